// Round 3
// baseline (1112.442 us; speedup 1.0000x reference)
//
#include <hip/hip_runtime.h>

typedef unsigned short u16;
typedef unsigned int   u32;
typedef __attribute__((ext_vector_type(8))) short short8;
typedef __attribute__((ext_vector_type(4))) float f32x4;

__device__ __forceinline__ float u2f(u32 u){
  union { u32 i; float f; } v; v.i = u << 16; return v.f;
}
__device__ __forceinline__ u16 f2bu(float f){
  union { float f; u32 i; } v; v.f = f;
  u32 i = v.i;
  i += 0x7fffu + ((i >> 16) & 1u);   // round-to-nearest-even
  return (u16)(i >> 16);
}
__device__ __forceinline__ float sigm(float x){ return 1.0f/(1.0f + expf(-x)); }
__device__ __forceinline__ float ldf(const void* p, size_t i, int bf){
  return bf ? u2f(((const u16*)p)[i]) : ((const float*)p)[i];
}
__device__ __forceinline__ float wsum(float v){
  #pragma unroll
  for (int off = 32; off > 0; off >>= 1) v += __shfl_xor(v, off, 64);
  return v;
}
// 8x f32 -> short8 bf16 (RNE), via packed HW cvt (matches f2bu for normals)
__device__ __forceinline__ short8 cvt8(float4 lo, float4 hi){
  union { u32 u[4]; short8 s; } r;
  asm("v_cvt_pk_bf16_f32 %0, %1, %2" : "=v"(r.u[0]) : "v"(lo.x), "v"(lo.y));
  asm("v_cvt_pk_bf16_f32 %0, %1, %2" : "=v"(r.u[1]) : "v"(lo.z), "v"(lo.w));
  asm("v_cvt_pk_bf16_f32 %0, %1, %2" : "=v"(r.u[2]) : "v"(hi.x), "v"(hi.y));
  asm("v_cvt_pk_bf16_f32 %0, %1, %2" : "=v"(r.u[3]) : "v"(hi.z), "v"(hi.w));
  return r.s;
}

// ---------------------------------------------------------------------------
// Kernel 0: dtype detector (bf16 vs f32 device buffers).
// ---------------------------------------------------------------------------
__global__ __launch_bounds__(64) void k_detect(const u32* __restrict__ nv,
                                               int* __restrict__ flag)
{
  int i = threadIdx.x;
  u32 w = nv[i];
  u32 e = (w >> 7) & 0xffu;
  bool sane = (e >= 100u && e <= 140u);
  unsigned long long m = __ballot(sane);
  if (i == 0) *flag = (__popcll(m) >= 40) ? 1 : 0;
}

// ---------------------------------------------------------------------------
// Kernel P: pack weights -> bf16, [Rp rows][Kp cols]; zero for k>=K or r>=R.
// ---------------------------------------------------------------------------
__global__ __launch_bounds__(256) void k_pack(
    const void* __restrict__ src, u16* __restrict__ dst,
    int K, int Kp, int R, int Rp, const int* __restrict__ flag)
{
  const int bf = *flag;
  int total = Rp*Kp;
  int idx = blockIdx.x*256 + threadIdx.x;
  if (idx >= total) return;
  int r = idx / Kp, k = idx - r*Kp;
  u16 v = 0;
  if (k < K && r < R){
    size_t si = (size_t)r*K + k;
    v = bf ? ((const u16*)src)[si] : f2bu(((const float*)src)[si]);
  }
  dst[idx] = v;
}

// ---------------------------------------------------------------------------
// Kernel 1: neighbor encoder. Barrier-free MFMA K-loop: A fragments read
// directly from emb (gathered rows, 32 B/frag, boundary window cb==96 split),
// B fragments read directly from pre-packed bf16 Wg [112][224] (L1/L2-hot).
// logit/oa computed from accumulators via shfl reductions (no out_s in LDS).
// ---------------------------------------------------------------------------
__global__ __launch_bounds__(256) void k_gcn(
    const int* __restrict__ left, const int* __restrict__ right,
    const void* __restrict__ emb, const u16* __restrict__ Wg,
    const void* __restrict__ gcnwb, const void* __restrict__ gcnb,
    const void* __restrict__ attnw, const void* __restrict__ attnwb,
    const void* __restrict__ gatew, const void* __restrict__ gatewb,
    const void* __restrict__ gateb,
    const int* __restrict__ flag,
    u16* __restrict__ X0bf)
{
  __shared__ int c1_s[200], c2_s[200];
  __shared__ float logit_s[208];
  __shared__ float red_s[256];
  __shared__ float attnw_s[112], bias_s[112], gatew_s[112], oa_s[112];

  const int bf  = *flag;
  const int tid = threadIdx.x;
  const int n   = blockIdx.x;
  const int b   = n & 255;
  const int fs  = n >> 8;
  const int s   = fs & 1;
  const int f   = fs >> 1;
  const int* conn = (s == 0 ? left : right) + (size_t)(f*256 + b)*600;

  const u16*   e16 = (const u16*)emb;
  const float* e32 = (const float*)emb;

  if (tid < 200){ c1_s[tid] = conn[tid*3+1]; c2_s[tid] = conn[tid*3+2]; }
  if (tid < 112){
    attnw_s[tid] = (tid < 100) ? ldf(attnw, tid, bf) : 0.0f;
    bias_s[tid]  = (tid < 100) ? (ldf(gcnwb, tid, bf) + ldf(gcnb, tid, bf)) : 0.0f;
    gatew_s[tid] = (tid < 100) ? ldf(gatew, tid, bf) : 0.0f;
    oa_s[tid] = 0.0f;
  }
  __syncthreads();

  const int wid  = tid >> 6, lane = tid & 63, ln = lane & 15, quad = lane >> 4;
  const int mt0 = (wid == 0) ? 0 : (4 + 3*(wid-1));
  const int nmt = (wid == 0) ? 4 : 3;

  f32x4 acc[4][7];
  #pragma unroll
  for (int i = 0; i < 4; ++i)
    #pragma unroll
    for (int j = 0; j < 7; ++j) acc[i][j] = (f32x4)0.0f;

  // ---- barrier-free MFMA main loop ----
  #pragma unroll 1
  for (int kc = 0; kc < 7; ++kc){
    short8 bfr[7];
    #pragma unroll
    for (int nt = 0; nt < 7; ++nt)
      bfr[nt] = *(const short8*)(Wg + (size_t)(nt*16 + ln)*224 + kc*32 + quad*8);

    #pragma unroll
    for (int mi = 0; mi < 4; ++mi){
      if (mi < nmt){
        const int r  = (mt0+mi)*16 + ln;
        const int cb = kc*32 + quad*8;
        short8 afr = (short8)0;
        if (r < 200 && cb < 200){
          const int c1 = c1_s[r], c2 = c2_s[r];
          if (bf){
            union { uint2 u2[2]; short8 s; } av;
            if (cb <= 88){
              const u16* p = e16 + (size_t)c1*100 + cb;
              av.u2[0] = *(const uint2*)p; av.u2[1] = *(const uint2*)(p+4);
            } else if (cb >= 104){
              const u16* p = e16 + (size_t)c2*100 + (cb-100);
              av.u2[0] = *(const uint2*)p; av.u2[1] = *(const uint2*)(p+4);
            } else { // cb == 96
              av.u2[0] = *(const uint2*)(e16 + (size_t)c1*100 + 96);
              av.u2[1] = *(const uint2*)(e16 + (size_t)c2*100);
            }
            afr = av.s;
          } else {
            float4 lo, hi;
            if (cb <= 88){
              const float* p = e32 + (size_t)c1*100 + cb;
              lo = *(const float4*)p; hi = *(const float4*)(p+4);
            } else if (cb >= 104){
              const float* p = e32 + (size_t)c2*100 + (cb-100);
              lo = *(const float4*)p; hi = *(const float4*)(p+4);
            } else { // cb == 96
              lo = *(const float4*)(e32 + (size_t)c1*100 + 96);
              hi = *(const float4*)(e32 + (size_t)c2*100);
            }
            afr = cvt8(lo, hi);
          }
        }
        #pragma unroll
        for (int nt = 0; nt < 7; ++nt)
          acc[mi][nt] = __builtin_amdgcn_mfma_f32_16x16x32_bf16(afr, bfr[nt], acc[mi][nt], 0, 0, 0);
      }
    }
  }

  // ---- logits from accumulators (out = lrelu(acc+bias), logit = out.attnw) ----
  const float awb = ldf(attnwb, 0, bf);
  #pragma unroll
  for (int mi = 0; mi < 4; ++mi){
    if (mi < nmt){
      #pragma unroll
      for (int rg = 0; rg < 4; ++rg){
        float p = 0.0f;
        #pragma unroll
        for (int nt = 0; nt < 7; ++nt){
          float x = acc[mi][nt][rg] + bias_s[nt*16 + ln];
          x = x > 0.0f ? x : 0.01f*x;
          p += x * attnw_s[nt*16 + ln];
        }
        p += __shfl_xor(p, 1, 64); p += __shfl_xor(p, 2, 64);
        p += __shfl_xor(p, 4, 64); p += __shfl_xor(p, 8, 64);
        int m = (mt0+mi)*16 + quad*4 + rg;
        if (ln == 0 && m < 200) logit_s[m] = p + awb;
      }
    }
  }
  __syncthreads();

  // ---- softmax over 200 ----
  red_s[tid] = (tid < 200) ? logit_s[tid] : -3.0e38f;
  __syncthreads();
  for (int off = 128; off > 0; off >>= 1){
    if (tid < off) red_s[tid] = fmaxf(red_s[tid], red_s[tid+off]);
    __syncthreads();
  }
  float mx = red_s[0];
  __syncthreads();
  float ev = 0.0f;
  if (tid < 200) ev = expf(logit_s[tid] - mx);
  red_s[tid] = ev;
  __syncthreads();
  for (int off = 128; off > 0; off >>= 1){
    if (tid < off) red_s[tid] += red_s[tid+off];
    __syncthreads();
  }
  float S = red_s[0];
  __syncthreads();
  if (tid < 208) logit_s[tid] = (tid < 200) ? ev*(1.0f/S) : 0.0f;  // attn
  __syncthreads();

  // ---- oa[d] = sum_m out[m][d]*attn[m] from accumulators ----
  float at[4][4];
  #pragma unroll
  for (int mi = 0; mi < 4; ++mi)
    #pragma unroll
    for (int rg = 0; rg < 4; ++rg)
      at[mi][rg] = (mi < nmt) ? logit_s[(mt0+mi)*16 + quad*4 + rg] : 0.0f;

  #pragma unroll
  for (int nt = 0; nt < 7; ++nt){
    float p = 0.0f;
    #pragma unroll
    for (int mi = 0; mi < 4; ++mi){
      if (mi < nmt){
        #pragma unroll
        for (int rg = 0; rg < 4; ++rg){
          float x = acc[mi][nt][rg] + bias_s[nt*16 + ln];
          x = x > 0.0f ? x : 0.01f*x;
          p += x * at[mi][rg];
        }
      }
    }
    p += __shfl_xor(p, 16, 64); p += __shfl_xor(p, 32, 64);
    if (quad == 0) atomicAdd(&oa_s[nt*16 + ln], p);
  }
  __syncthreads();

  // ---- gate + output ----
  red_s[tid] = (tid < 100) ? oa_s[tid]*gatew_s[tid] : 0.0f;
  __syncthreads();
  for (int off = 128; off > 0; off >>= 1){
    if (tid < off) red_s[tid] += red_s[tid+off];
    __syncthreads();
  }
  float gate = sigm(red_s[0] + ldf(gatewb, 0, bf) + ldf(gateb, 0, bf));
  if (tid < 100){
    int c0 = conn[0];
    float self = ldf(emb, (size_t)c0*100 + tid, bf);
    X0bf[((size_t)f*256 + b)*224 + s*100 + tid] = f2bu(oa_s[tid]*gate + self*(1.0f - gate));
  }
}

// ---------------------------------------------------------------------------
// Kernel M: MFMA GEMM. out[z][row][col] = sum_k A[z][row][k]*B[z][col][k]
//           (+ bias1/bias2[z*biasStride+col]) (+ addend_z[row*N+col], bf16).
// A,B bf16, lda/ldb multiples of 32, zero-padded. M multiple of 128.
// Block 256 thr = 4 waves (2x2), each wave 64x64 via 4x4 MFMA 16x16x32.
// Staging: 2 threads/row, each stages 16 contiguous bf16 (two short8) per
// operand so the FULL 32-element K-window is written (quads 0..3 all valid).
// ---------------------------------------------------------------------------
__global__ __launch_bounds__(256) void k_mgemm(
    const u16* __restrict__ A, int lda, size_t Astride,
    const u16* __restrict__ B, int ldb, size_t Bstride,
    const void* __restrict__ b1, const void* __restrict__ b2, int biasStride,
    const int* __restrict__ flag,
    const u16* __restrict__ add0, const u16* __restrict__ add1,
    void* __restrict__ out, int outBf, size_t Ostride,
    int N, int KC)
{
  __shared__ __align__(16) u16 As[128*40];
  __shared__ __align__(16) u16 Bs[128*40];
  const int tid = threadIdx.x;
  const int z  = blockIdx.z;
  const int nb = blockIdx.x, mb = blockIdx.y;
  const u16* Az = A + (size_t)z*Astride;
  const u16* Bz = B + (size_t)z*Bstride;
  const int bf = *flag;

  const int wid = tid >> 6, lane = tid & 63, ln = lane & 15, quad = lane >> 4;
  const int wm = wid >> 1, wn = wid & 1;

  f32x4 acc[4][4];
  #pragma unroll
  for (int i = 0; i < 4; ++i)
    #pragma unroll
    for (int j = 0; j < 4; ++j) acc[i][j] = (f32x4)0.0f;

  const int srow = tid >> 1;
  const int koff = (tid & 1)*16;
  const int rowA = mb*128 + srow;
  const int rowB = nb*128 + srow;
  const bool bok = (rowB < N);

  for (int kc = 0; kc < KC; ++kc){
    const int k0 = kc*32 + koff;
    const u16* ap = Az + (size_t)rowA*lda + k0;
    short8 av0 = *(const short8*)(ap);
    short8 av1 = *(const short8*)(ap + 8);
    short8 bv0 = (short8)0, bv1 = (short8)0;
    if (bok){
      const u16* bp = Bz + (size_t)rowB*ldb + k0;
      bv0 = *(const short8*)(bp);
      bv1 = *(const short8*)(bp + 8);
    }
    *(short8*)(As + srow*40 + koff)     = av0;
    *(short8*)(As + srow*40 + koff + 8) = av1;
    *(short8*)(Bs + srow*40 + koff)     = bv0;
    *(short8*)(Bs + srow*40 + koff + 8) = bv1;
    __syncthreads();
    short8 af[4], bfr[4];
    #pragma unroll
    for (int i = 0; i < 4; ++i)
      af[i] = *(const short8*)(As + (wm*64 + i*16 + ln)*40 + quad*8);
    #pragma unroll
    for (int j = 0; j < 4; ++j)
      bfr[j] = *(const short8*)(Bs + (wn*64 + j*16 + ln)*40 + quad*8);
    #pragma unroll
    for (int i = 0; i < 4; ++i)
      #pragma unroll
      for (int j = 0; j < 4; ++j)
        acc[i][j] = __builtin_amdgcn_mfma_f32_16x16x32_bf16(af[i], bfr[j], acc[i][j], 0, 0, 0);
    __syncthreads();
  }

  const u16* addz = (z == 0) ? add0 : add1;
  #pragma unroll
  for (int j = 0; j < 4; ++j){
    int col = nb*128 + wn*64 + j*16 + ln;
    if (col < N){
      float bias = 0.0f;
      if (b1) bias += ldf(b1, (size_t)z*biasStride + col, bf);
      if (b2) bias += ldf(b2, (size_t)z*biasStride + col, bf);
      #pragma unroll
      for (int i = 0; i < 4; ++i){
        #pragma unroll
        for (int rg = 0; rg < 4; ++rg){
          int row = mb*128 + wm*64 + i*16 + quad*4 + rg;
          float v = acc[i][j][rg] + bias;
          if (addz) v += u2f(addz[(size_t)row*N + col]);
          size_t oi = (size_t)z*Ostride + (size_t)row*N + col;
          if (outBf) ((u16*)out)[oi] = f2bu(v);
          else       ((float*)out)[oi] = v;
        }
      }
    }
  }
}

// ---------------------------------------------------------------------------
// Kernel 4: LSTM cell pointwise update. Writes h -> Hbf (bf16, stride 480),
// y -> Y0bf (bf16, stride 928) or Y1 (f32, stride 900), finals -> HF.
// ---------------------------------------------------------------------------
__global__ __launch_bounds__(256) void k_cell(
    const float* __restrict__ GT, float* __restrict__ HC,
    u16* __restrict__ Hbf, u16* __restrict__ Ybf, float* __restrict__ Yf,
    float* __restrict__ HF, int s, int layer)
{
  int idx = blockIdx.x*256 + threadIdx.x;
  if (idx >= 2*256*450) return;
  int k = idx % 450;
  int rb = idx / 450;
  int b = rb % 256;
  int dir = rb / 256;
  int t_eff = dir ? (4 - s) : s;
  const float* g = GT + ((size_t)dir*256 + b)*1800;
  float gi = g[k], gf = g[450+k], gg = g[900+k], go = g[1350+k];
  float* cp = HC + ((size_t)(2+dir)*256 + b)*450 + k;
  float c = sigm(gf)*(*cp) + sigm(gi)*tanhf(gg);
  float hv = sigm(go)*tanhf(c);
  *cp = c;
  Hbf[((size_t)dir*256 + b)*480 + k] = f2bu(hv);
  if (Ybf) Ybf[((size_t)t_eff*256 + b)*928 + dir*450 + k] = f2bu(hv);
  else     Yf [((size_t)t_eff*256 + b)*900 + dir*450 + k] = hv;
  HF[((size_t)(layer*2+dir)*256 + b)*450 + k] = hv;
}

// ---------------------------------------------------------------------------
// Kernel 5: attention over timesteps + context.
// hidden[b][h][l] = HF_flat[b*1800 + h*2 + l]  (reference reshape quirk)
// ---------------------------------------------------------------------------
__global__ __launch_bounds__(256) void k_attn(
    const float* __restrict__ Y1, const float* __restrict__ HF,
    float* __restrict__ CTX)
{
  __shared__ float red[256];
  __shared__ float sc[10];
  __shared__ float aw[10];
  int b = blockIdx.x, tid = threadIdx.x;
  for (int p = 0; p < 10; ++p){
    int t = p >> 1, l = p & 1;
    float a = 0.0f;
    for (int h = tid; h < 900; h += 256)
      a += Y1[((size_t)t*256 + b)*900 + h] * HF[(size_t)b*1800 + h*2 + l];
    red[tid] = a; __syncthreads();
    for (int off = 128; off > 0; off >>= 1){
      if (tid < off) red[tid] += red[tid+off];
      __syncthreads();
    }
    if (tid == 0) sc[p] = red[0];
    __syncthreads();
  }
  if (tid < 2){
    int l = tid;
    float mxv = -3.0e38f;
    for (int t = 0; t < 5; ++t) mxv = fmaxf(mxv, sc[t*2+l]);
    float e[5], sum = 0.0f;
    for (int t = 0; t < 5; ++t){ e[t] = expf(sc[t*2+l]-mxv); sum += e[t]; }
    for (int t = 0; t < 5; ++t) aw[t*2+l] = e[t]/sum;
  }
  __syncthreads();
  for (int h = tid; h < 900; h += 256){
    float v0 = 0.0f, v1 = 0.0f;
    for (int t = 0; t < 5; ++t){
      float y = Y1[((size_t)t*256 + b)*900 + h];
      v0 += y*aw[t*2+0]; v1 += y*aw[t*2+1];
    }
    CTX[(size_t)b*1800 + h*2 + 0] = v0;
    CTX[(size_t)b*1800 + h*2 + 1] = v1;
  }
}

// ---------------------------------------------------------------------------
// Kernel 2s: scalar GEMM (kept only for CTX @ out_w, C=100).
// ---------------------------------------------------------------------------
__global__ __launch_bounds__(256) void k_gemm(
    const float* __restrict__ A, const void* __restrict__ W, size_t wEl,
    const void* __restrict__ b1, const void* __restrict__ b2, size_t bEl,
    const int* __restrict__ flag,
    float* __restrict__ out, int K, int C)
{
  extern __shared__ float a_s[];
  const int bf = *flag;
  const int tid = threadIdx.x;
  const int r = blockIdx.y;
  const float* a = A + (size_t)r*K;
  for (int k = tid; k < K; k += 256) a_s[k] = a[k];
  __syncthreads();
  const int j = blockIdx.x*256 + tid;
  if (j >= C) return;
  float acc = 0.0f;
  if (b1) acc += ldf(b1, bEl + j, bf);
  if (b2) acc += ldf(b2, bEl + j, bf);
  if (bf){
    const u16* w = (const u16*)W + wEl + (size_t)j*K;
    for (int k = 0; k < K; k += 4){
      uint2 wv = *(const uint2*)(w + k);
      acc += a_s[k]   * u2f(wv.x & 0xffffu);
      acc += a_s[k+1] * u2f(wv.x >> 16);
      acc += a_s[k+2] * u2f(wv.y & 0xffffu);
      acc += a_s[k+3] * u2f(wv.y >> 16);
    }
  } else {
    const float* w = (const float*)W + wEl + (size_t)j*K;
    for (int k = 0; k < K; k += 4){
      float4 wv = *(const float4*)(w + k);
      acc += a_s[k]*wv.x + a_s[k+1]*wv.y + a_s[k+2]*wv.z + a_s[k+3]*wv.w;
    }
  }
  out[(size_t)r*C + j] = acc;
}

__device__ __forceinline__ float bred128(float v, float* red, int tid){
  red[tid] = v; __syncthreads();
  for (int off = 64; off > 0; off >>= 1){
    if (tid < off) red[tid] += red[tid+off];
    __syncthreads();
  }
  float r = red[0]; __syncthreads();
  return r;
}

// ---------------------------------------------------------------------------
// Kernel 6: analytic meta-gradient -> rel_q, norm_q. One block per b.
// ---------------------------------------------------------------------------
__global__ __launch_bounds__(128) void k_grad(
    const void* __restrict__ sup, const void* __restrict__ supn,
    const void* __restrict__ normv, const float* __restrict__ REL,
    const int* __restrict__ flag,
    float* __restrict__ RELQ, float* __restrict__ NORMQ)
{
  __shared__ float red[128];
  __shared__ float nv[100], rl[100], acc[100];
  const int bf = *flag;
  int b = blockIdx.x, tid = threadIdx.x;
  if (tid < 100){
    nv[tid] = ldf(normv, b*100+tid, bf);
    rl[tid] = REL[b*100+tid];
    acc[tid] = 0.0f;
  }
  __syncthreads();
  float nvd = (tid < 100) ? nv[tid] : 0.0f;
  float rld = (tid < 100) ? rl[tid] : 0.0f;
  for (int j = 0; j < 5; ++j){
    float h1=0.f,t1=0.f,h2=0.f,t2=0.f;
    if (tid < 100){
      size_t base = (size_t)(b*5+j)*200;
      h1 = ldf(sup,  base + tid, bf);  t1 = ldf(sup,  base + 100 + tid, bf);
      h2 = ldf(supn, base + tid, bf);  t2 = ldf(supn, base + 100 + tid, bf);
    }
    float hd1 = bred128(h1*nvd, red, tid);
    float td1 = bred128(t1*nvd, red, tid);
    float hd2 = bred128(h2*nvd, red, tid);
    float td2 = bred128(t2*nvd, red, tid);
    float upd = (h1 - hd1*nvd) + rld - (t1 - td1*nvd);
    float und = (h2 - hd2*nvd) + rld - (t2 - td2*nvd);
    if (tid >= 100){ upd = 0.0f; und = 0.0f; }
    float np2 = bred128(upd*upd, red, tid);
    float nn2 = bred128(und*und, red, tid);
    float p = -sqrtf(np2), nsc = -sqrtf(nn2);
    if ((1.0f - (p - nsc) > 0.0f) && tid < 100)
      acc[tid] += upd/sqrtf(np2) - und/sqrtf(nn2);
  }
  __syncthreads();
  if (tid < 100){
    float g = acc[tid] * (1.0f/1280.0f);
    RELQ[b*100+tid]  = rl[tid] - 5.0f*g;
    NORMQ[b*100+tid] = nv[tid] - 5.0f*g;
  }
}

// ---------------------------------------------------------------------------
// Kernel 7: final scores (10 query + 512 negative per b).
// One WAVE per row: lanes 0..49 hold the row's 200 elems as float4 in regs
// (800 B contiguous per wave -> fully coalesced, each byte fetched once).
// hd/td/s2 via 64-lane shfl_xor reductions; t-values reach h-lanes via shfl.
// ---------------------------------------------------------------------------
__global__ __launch_bounds__(256) void k_score(
    const void* __restrict__ query, const void* __restrict__ neg,
    const float* __restrict__ RELQ, const float* __restrict__ NORMQ,
    const int* __restrict__ flag, void* __restrict__ out)
{
  __shared__ __align__(16) float nq[104], rq[104];
  const int bf = *flag;
  const int b = blockIdx.x, tid = threadIdx.x;
  if (tid < 100){ nq[tid] = NORMQ[b*100+tid]; rq[tid] = RELQ[b*100+tid]; }
  __syncthreads();
  const int wid = tid >> 6, lane = tid & 63;
  const int d0 = lane*4;
  const int nidx = (lane < 25) ? d0 : (d0 - 100);
  float4 w4 = make_float4(0.0f,0.0f,0.0f,0.0f);
  float4 r4 = make_float4(0.0f,0.0f,0.0f,0.0f);
  if (lane < 50) w4 = *(const float4*)(nq + nidx);
  if (lane < 25) r4 = *(const float4*)(rq + d0);

  for (int qi = blockIdx.y*4 + wid; qi < 522; qi += 32){
    const void* src = (qi < 10) ? query : neg;
    size_t row = (qi < 10) ? ((size_t)b*10 + qi) : ((size_t)b*512 + qi - 10);
    size_t base = row*200;
    float4 v = make_float4(0.0f,0.0f,0.0f,0.0f);
    if (lane < 50){
      if (bf){
        uint2 u = *(const uint2*)((const u16*)src + base + d0);
        v.x = u2f(u.x & 0xffffu); v.y = u2f(u.x >> 16);
        v.z = u2f(u.y & 0xffffu); v.w = u2f(u.y >> 16);
      } else {
        v = *(const float4*)((const float*)src + base + d0);
      }
    }
    float p = v.x*w4.x + v.y*w4.y + v.z*w4.z + v.w*w4.w;
    float hd = wsum(lane < 25 ? p : 0.0f);
    float td = wsum((lane >= 25 && lane < 50) ? p : 0.0f);
    int sl = (lane < 25) ? (lane + 25) : lane;
    float4 t4;
    t4.x = __shfl(v.x, sl, 64);
    t4.y = __shfl(v.y, sl, 64);
    t4.z = __shfl(v.z, sl, 64);
    t4.w = __shfl(v.w, sl, 64);
    float s2p = 0.0f;
    if (lane < 25){
      float ux = (v.x - hd*w4.x) + r4.x - (t4.x - td*w4.x);
      float uy = (v.y - hd*w4.y) + r4.y - (t4.y - td*w4.y);
      float uz = (v.z - hd*w4.z) + r4.z - (t4.z - td*w4.z);
      float uw = (v.w - hd*w4.w) + r4.w - (t4.w - td*w4.w);
      s2p = ux*ux + uy*uy + uz*uz + uw*uw;
    }
    float s2 = wsum(s2p);
    if (lane == 0){
      float sc = -sqrtf(s2);
      size_t oi = (qi < 10) ? ((size_t)b*10 + qi) : (2560 + (size_t)b*512 + (qi - 10));
      if (bf) ((u16*)out)[oi] = f2bu(sc);
      else    ((float*)out)[oi] = sc;
    }
  }
}

// ---------------------------------------------------------------------------
extern "C" void kernel_launch(void* const* d_in, const int* in_sizes, int n_in,
                              void* d_out, int out_size, void* d_ws, size_t ws_size,
                              hipStream_t stream)
{
  const void* support = d_in[0];
  const void* supneg  = d_in[1];
  const void* query   = d_in[2];
  const void* negat   = d_in[3];
  const void* normv   = d_in[4];
  const int* left     = (const int*)d_in[5];
  const int* right    = (const int*)d_in[6];
  const void* emb     = d_in[7];
  const void* gcnw    = d_in[8];
  const void* gcnwb   = d_in[9];
  const void* gcnb    = d_in[10];
  const void* attnw   = d_in[11];
  const void* attnwb  = d_in[12];
  const void* gatew   = d_in[13];
  const void* gatewb  = d_in[14];
  const void* gateb   = d_in[15];
  const void* Wih0    = d_in[16];
  const void* Whh0    = d_in[17];
  const void* bih0    = d_in[18];
  const void* bhh0    = d_in[19];
  const void* Wih1    = d_in[20];
  const void* Whh1    = d_in[21];
  const void* bih1    = d_in[22];
  const void* bhh1    = d_in[23];
  const void* outw    = d_in[24];
  const void* outb    = d_in[25];

  int*   dflag = (int*)d_ws;
  float* fws   = (float*)d_ws + 16;
  // f32 region
  float* Y1   = fws;                 // 5*256*900  = 1,152,000
  float* HF   = Y1 + 1152000;        // 4*256*450  =   460,800
  float* HC   = HF + 460800;         //               460,800 (c-state in [2..4))
  float* CTX  = HC + 460800;         //               460,800
  float* RELb = CTX + 460800;        //    25,600
  float* RELQ = RELb + 25600;        //    25,600
  float* NORMQ= RELQ + 25600;        //    25,600
  float* GT   = NORMQ + 25600;       // 2*256*1800 =   921,600
  float* fend = GT + 921600;
  // u16 region (16B-aligned: fend offset is a multiple of 16 floats)
  u16* Gb   = (u16*)fend;            // 2*5*256*1800 = 4,608,000
  u16* X0bf = Gb + 4608000;          // 1280*224     =   286,720
  u16* Y0bf = X0bf + 286720;         // 1280*928     = 1,187,840
  u16* Hbf  = Y0bf + 1187840;        // 2*256*480    =   245,760
  u16* Wp   = Hbf + 245760;          // 3600*928 max = 3,340,800
  u16* Whp  = Wp + 3340800;          // 3600*480     = 1,728,000
  u16* Wg   = Whp + 1728000;         // 112*224      =    25,088
  // total ≈ 37.0 MB

  k_detect<<<1, 64, 0, stream>>>((const u32*)normv, dflag);

  // neighbor encoder -> X0bf (memset for zero pad first)
  hipMemsetAsync(X0bf, 0, 286720*sizeof(u16), stream);
  k_pack<<<(112*224+255)/256, 256, 0, stream>>>(gcnw, Wg, 200, 224, 100, 112, dflag);
  k_gcn<<<2560, 256, 0, stream>>>(left, right, emb, Wg, gcnwb, gcnb,
                                  attnw, attnwb, gatew, gatewb, gateb,
                                  dflag, X0bf);

  // ---- layer 0 ----
  hipMemsetAsync(Y0bf, 0, 1187840*sizeof(u16), stream);
  hipMemsetAsync(Hbf, 0, 245760*sizeof(u16), stream);
  hipMemsetAsync(HC, 0, 460800*sizeof(float), stream);
  k_pack<<<(3600*224+255)/256, 256, 0, stream>>>(Wih0, Wp,  200, 224, 3600, 3600, dflag);
  k_pack<<<(3600*480+255)/256, 256, 0, stream>>>(Whh0, Whp, 450, 480, 3600, 3600, dflag);
  // input projection: G[z][t][b][:] (bf16 out)
  k_mgemm<<<dim3(15,10,2), 256, 0, stream>>>(
      X0bf, 224, 0, Wp, 224, (size_t)1800*224,
      bih0, bhh0, 1800, dflag, nullptr, nullptr,
      Gb, 1, 2304000, 1800, 7);
  for (int s = 0; s < 5; ++s){
    k_mgemm<<<dim3(15,2,2), 256, 0, stream>>>(
        Hbf, 480, (size_t)256*480, Whp, 480, (size_t)1800*480,
        nullptr, nullptr, 0, dflag,
        Gb + (size_t)s*460800, Gb + (size_t)(9-s)*460800,
        GT, 0, 460800, 1800, 15);
    k_cell<<<900, 256, 0, stream>>>(GT, HC, Hbf, Y0bf, nullptr, HF, s, 0);
  }

  // ---- layer 1 ----
  hipMemsetAsync(Hbf, 0, 245760*sizeof(u16), stream);
  hipMemsetAsync(HC, 0, 460800*sizeof(float), stream);
  k_pack<<<(3600*928+255)/256, 256, 0, stream>>>(Wih1, Wp,  900, 928, 3600, 3600, dflag);
  k_pack<<<(3600*480+255)/256, 256, 0, stream>>>(Whh1, Whp, 450, 480, 3600, 3600, dflag);
  k_mgemm<<<dim3(15,10,2), 256, 0, stream>>>(
      Y0bf, 928, 0, Wp, 928, (size_t)1800*928,
      bih1, bhh1, 1800, dflag, nullptr, nullptr,
      Gb, 1, 2304000, 1800, 29);
  for (int s = 0; s < 5; ++s){
    k_mgemm<<<dim3(15,2,2), 256, 0, stream>>>(
        Hbf, 480, (size_t)256*480, Whp, 480, (size_t)1800*480,
        nullptr, nullptr, 0, dflag,
        Gb + (size_t)s*460800, Gb + (size_t)(9-s)*460800,
        GT, 0, 460800, 1800, 15);
    k_cell<<<900, 256, 0, stream>>>(GT, HC, Hbf, nullptr, Y1, HF, s, 1);
  }

  k_attn<<<256, 256, 0, stream>>>(Y1, HF, CTX);
  k_gemm<<<dim3(1,256), 256, 1800*4, stream>>>(CTX, outw, 0, outb, nullptr, 0,
                                               dflag, RELb, 1800, 100);
  k_grad<<<256, 128, 0, stream>>>(support, supneg, normv, RELb, dflag, RELQ, NORMQ);
  k_score<<<dim3(256,8), 256, 0, stream>>>(query, negat, RELQ, NORMQ, dflag, d_out);
}

// Round 4
// 960.100 us; speedup vs baseline: 1.1587x; 1.1587x over previous
//
#include <hip/hip_runtime.h>

typedef unsigned short u16;
typedef unsigned int   u32;
typedef __attribute__((ext_vector_type(8))) short short8;
typedef __attribute__((ext_vector_type(4))) float f32x4;

__device__ __forceinline__ float u2f(u32 u){
  union { u32 i; float f; } v; v.i = u << 16; return v.f;
}
__device__ __forceinline__ u16 f2bu(float f){
  union { float f; u32 i; } v; v.f = f;
  u32 i = v.i;
  i += 0x7fffu + ((i >> 16) & 1u);   // round-to-nearest-even
  return (u16)(i >> 16);
}
__device__ __forceinline__ float sigm(float x){ return 1.0f/(1.0f + expf(-x)); }
__device__ __forceinline__ float ldf(const void* p, size_t i, int bf){
  return bf ? u2f(((const u16*)p)[i]) : ((const float*)p)[i];
}
__device__ __forceinline__ float wsum(float v){
  #pragma unroll
  for (int off = 32; off > 0; off >>= 1) v += __shfl_xor(v, off, 64);
  return v;
}

// ---------------------------------------------------------------------------
// Kernel 0: dtype detector (bf16 vs f32 device buffers).
// ---------------------------------------------------------------------------
__global__ __launch_bounds__(64) void k_detect(const u32* __restrict__ nv,
                                               int* __restrict__ flag)
{
  int i = threadIdx.x;
  u32 w = nv[i];
  u32 e = (w >> 7) & 0xffu;
  bool sane = (e >= 100u && e <= 140u);
  unsigned long long m = __ballot(sane);
  if (i == 0) *flag = (__popcll(m) >= 40) ? 1 : 0;
}

// ---------------------------------------------------------------------------
// Kernel P: pack weights -> bf16, [Rp rows][Kp cols]; zero for k>=K or r>=R.
// ---------------------------------------------------------------------------
__global__ __launch_bounds__(256) void k_pack(
    const void* __restrict__ src, u16* __restrict__ dst,
    int K, int Kp, int R, int Rp, const int* __restrict__ flag)
{
  const int bf = *flag;
  int total = Rp*Kp;
  int idx = blockIdx.x*256 + threadIdx.x;
  if (idx >= total) return;
  int r = idx / Kp, k = idx - r*Kp;
  u16 v = 0;
  if (k < K && r < R){
    size_t si = (size_t)r*K + k;
    v = bf ? ((const u16*)src)[si] : f2bu(((const float*)src)[si]);
  }
  dst[idx] = v;
}

// ---------------------------------------------------------------------------
// Kernel 1: neighbor encoder. 512 threads (8 waves): waves 0-4 own 2 row-
// tiles, waves 5-7 own 1 (13 tiles = 208 rows). acc[2][7] = 56 regs/thread,
// __launch_bounds__(512,4) -> <=128 VGPR -> 2 blocks/CU (16 waves).
// A staged to LDS per kc (flat high-MLP gather, round-2 verified pattern);
// B (gcn_w bf16, pre-packed Wg) staged to LDS ONCE (row stride 232: 2-way
// bank aliasing only). Tail = accumulator shfl reductions (no out_s).
// ---------------------------------------------------------------------------
__global__ __launch_bounds__(512, 4) void k_gcn(
    const int* __restrict__ left, const int* __restrict__ right,
    const void* __restrict__ emb, const u16* __restrict__ Wg,
    const void* __restrict__ gcnwb, const void* __restrict__ gcnb,
    const void* __restrict__ attnw, const void* __restrict__ attnwb,
    const void* __restrict__ gatew, const void* __restrict__ gatewb,
    const void* __restrict__ gateb,
    const int* __restrict__ flag,
    u16* __restrict__ X0bf)
{
  __shared__ __align__(16) u16 As[208*40];    // 16640 B
  __shared__ __align__(16) u16 Bs[112*232];   // 51968 B
  __shared__ int c1_s[200], c2_s[200];
  __shared__ float logit_s[208];
  __shared__ float red_s[512];
  __shared__ float attnw_s[112], bias_s[112], gatew_s[112], oa_s[112];

  const int bf  = *flag;
  const int tid = threadIdx.x;
  const int n   = blockIdx.x;
  const int b   = n & 255;
  const int fs  = n >> 8;
  const int s   = fs & 1;
  const int f   = fs >> 1;
  const int* conn = (s == 0 ? left : right) + (size_t)(f*256 + b)*600;

  const u16*   e16 = (const u16*)emb;
  const float* e32 = (const float*)emb;

  if (tid < 200){ c1_s[tid] = conn[tid*3+1]; c2_s[tid] = conn[tid*3+2]; }
  if (tid < 112){
    attnw_s[tid] = (tid < 100) ? ldf(attnw, tid, bf) : 0.0f;
    bias_s[tid]  = (tid < 100) ? (ldf(gcnwb, tid, bf) + ldf(gcnb, tid, bf)) : 0.0f;
    gatew_s[tid] = (tid < 100) ? ldf(gatew, tid, bf) : 0.0f;
    oa_s[tid] = 0.0f;
  }
  // stage B once: Wg[112][224] -> Bs[112][232]
  for (int g = tid; g < 112*28; g += 512){
    int r = g / 28, cc = g - r*28;
    *(short8*)(Bs + r*232 + cc*8) = *(const short8*)(Wg + (size_t)r*224 + cc*8);
  }
  __syncthreads();

  const int wid  = tid >> 6, lane = tid & 63, ln = lane & 15, quad = lane >> 4;
  const int mt0 = (wid < 5) ? 2*wid : (10 + (wid - 5));
  const int nmt = (wid < 5) ? 2 : 1;

  f32x4 acc[2][7];
  #pragma unroll
  for (int i = 0; i < 2; ++i)
    #pragma unroll
    for (int j = 0; j < 7; ++j) acc[i][j] = (f32x4)0.0f;

  for (int kc = 0; kc < 7; ++kc){
    const int k0 = kc*32;
    for (int g = tid; g < 208*8; g += 512){
      int r = g >> 3, gi = g & 7, k = k0 + gi*4;
      uint2 v; v.x = 0u; v.y = 0u;
      if (r < 200 && k < 200){
        int c  = (k < 100) ? c1_s[r] : c2_s[r];
        int kk = (k < 100) ? k : (k - 100);
        size_t idx = (size_t)c*100 + kk;
        if (bf) v = *(const uint2*)(e16 + idx);
        else {
          float4 t = *(const float4*)(e32 + idx);
          v.x = (u32)f2bu(t.x) | ((u32)f2bu(t.y) << 16);
          v.y = (u32)f2bu(t.z) | ((u32)f2bu(t.w) << 16);
        }
      }
      *(uint2*)(As + r*40 + gi*4) = v;
    }
    __syncthreads();

    #pragma unroll
    for (int mi = 0; mi < 2; ++mi){
      if (mi < nmt){
        short8 afr = *(const short8*)(As + ((mt0+mi)*16 + ln)*40 + quad*8);
        #pragma unroll
        for (int nt = 0; nt < 7; ++nt){
          short8 bfr = *(const short8*)(Bs + (size_t)(nt*16 + ln)*232 + k0 + quad*8);
          acc[mi][nt] = __builtin_amdgcn_mfma_f32_16x16x32_bf16(afr, bfr, acc[mi][nt], 0, 0, 0);
        }
      }
    }
    __syncthreads();
  }

  // ---- logits from accumulators (out = lrelu(acc+bias), logit = out.attnw) ----
  const float awb = ldf(attnwb, 0, bf);
  #pragma unroll
  for (int mi = 0; mi < 2; ++mi){
    if (mi < nmt){
      #pragma unroll
      for (int rg = 0; rg < 4; ++rg){
        float p = 0.0f;
        #pragma unroll
        for (int nt = 0; nt < 7; ++nt){
          float x = acc[mi][nt][rg] + bias_s[nt*16 + ln];
          x = x > 0.0f ? x : 0.01f*x;
          p += x * attnw_s[nt*16 + ln];
        }
        p += __shfl_xor(p, 1, 64); p += __shfl_xor(p, 2, 64);
        p += __shfl_xor(p, 4, 64); p += __shfl_xor(p, 8, 64);
        int m = (mt0+mi)*16 + quad*4 + rg;
        if (ln == 0 && m < 200) logit_s[m] = p + awb;
      }
    }
  }
  __syncthreads();

  // ---- softmax over 200 (512-thread trees) ----
  red_s[tid] = (tid < 200) ? logit_s[tid] : -3.0e38f;
  __syncthreads();
  for (int off = 256; off > 0; off >>= 1){
    if (tid < off) red_s[tid] = fmaxf(red_s[tid], red_s[tid+off]);
    __syncthreads();
  }
  float mx = red_s[0];
  __syncthreads();
  float ev = 0.0f;
  if (tid < 200) ev = expf(logit_s[tid] - mx);
  red_s[tid] = ev;
  __syncthreads();
  for (int off = 256; off > 0; off >>= 1){
    if (tid < off) red_s[tid] += red_s[tid+off];
    __syncthreads();
  }
  float S = red_s[0];
  __syncthreads();
  if (tid < 208) logit_s[tid] = (tid < 200) ? ev*(1.0f/S) : 0.0f;  // attn
  __syncthreads();

  // ---- oa[d] = sum_m out[m][d]*attn[m] from accumulators ----
  float at[2][4];
  #pragma unroll
  for (int mi = 0; mi < 2; ++mi)
    #pragma unroll
    for (int rg = 0; rg < 4; ++rg)
      at[mi][rg] = (mi < nmt) ? logit_s[(mt0+mi)*16 + quad*4 + rg] : 0.0f;

  #pragma unroll
  for (int nt = 0; nt < 7; ++nt){
    float p = 0.0f;
    #pragma unroll
    for (int mi = 0; mi < 2; ++mi){
      if (mi < nmt){
        #pragma unroll
        for (int rg = 0; rg < 4; ++rg){
          float x = acc[mi][nt][rg] + bias_s[nt*16 + ln];
          x = x > 0.0f ? x : 0.01f*x;
          p += x * at[mi][rg];
        }
      }
    }
    p += __shfl_xor(p, 16, 64); p += __shfl_xor(p, 32, 64);
    if (quad == 0) atomicAdd(&oa_s[nt*16 + ln], p);
  }
  __syncthreads();

  // ---- gate + output ----
  red_s[tid] = (tid < 100) ? oa_s[tid]*gatew_s[tid] : 0.0f;
  __syncthreads();
  for (int off = 256; off > 0; off >>= 1){
    if (tid < off) red_s[tid] += red_s[tid+off];
    __syncthreads();
  }
  float gate = sigm(red_s[0] + ldf(gatewb, 0, bf) + ldf(gateb, 0, bf));
  if (tid < 100){
    int c0 = conn[0];
    float self = ldf(emb, (size_t)c0*100 + tid, bf);
    X0bf[((size_t)f*256 + b)*224 + s*100 + tid] = f2bu(oa_s[tid]*gate + self*(1.0f - gate));
  }
}

// ---------------------------------------------------------------------------
// Kernel M: MFMA GEMM. out[z][row][col] = sum_k A[z][row][k]*B[z][col][k]
//           (+ bias1/bias2[z*biasStride+col]) (+ addend_z[row*N+col], bf16).
// A,B bf16, lda/ldb multiples of 32, zero-padded. M multiple of 128.
// Block 256 thr = 4 waves (2x2), each wave 64x64 via 4x4 MFMA 16x16x32.
// Staging: 2 threads/row, each stages 16 contiguous bf16 (two short8) per
// operand so the FULL 32-element K-window is written (quads 0..3 all valid).
// ---------------------------------------------------------------------------
__global__ __launch_bounds__(256) void k_mgemm(
    const u16* __restrict__ A, int lda, size_t Astride,
    const u16* __restrict__ B, int ldb, size_t Bstride,
    const void* __restrict__ b1, const void* __restrict__ b2, int biasStride,
    const int* __restrict__ flag,
    const u16* __restrict__ add0, const u16* __restrict__ add1,
    void* __restrict__ out, int outBf, size_t Ostride,
    int N, int KC)
{
  __shared__ __align__(16) u16 As[128*40];
  __shared__ __align__(16) u16 Bs[128*40];
  const int tid = threadIdx.x;
  const int z  = blockIdx.z;
  const int nb = blockIdx.x, mb = blockIdx.y;
  const u16* Az = A + (size_t)z*Astride;
  const u16* Bz = B + (size_t)z*Bstride;
  const int bf = *flag;

  const int wid = tid >> 6, lane = tid & 63, ln = lane & 15, quad = lane >> 4;
  const int wm = wid >> 1, wn = wid & 1;

  f32x4 acc[4][4];
  #pragma unroll
  for (int i = 0; i < 4; ++i)
    #pragma unroll
    for (int j = 0; j < 4; ++j) acc[i][j] = (f32x4)0.0f;

  const int srow = tid >> 1;
  const int koff = (tid & 1)*16;
  const int rowA = mb*128 + srow;
  const int rowB = nb*128 + srow;
  const bool bok = (rowB < N);

  for (int kc = 0; kc < KC; ++kc){
    const int k0 = kc*32 + koff;
    const u16* ap = Az + (size_t)rowA*lda + k0;
    short8 av0 = *(const short8*)(ap);
    short8 av1 = *(const short8*)(ap + 8);
    short8 bv0 = (short8)0, bv1 = (short8)0;
    if (bok){
      const u16* bp = Bz + (size_t)rowB*ldb + k0;
      bv0 = *(const short8*)(bp);
      bv1 = *(const short8*)(bp + 8);
    }
    *(short8*)(As + srow*40 + koff)     = av0;
    *(short8*)(As + srow*40 + koff + 8) = av1;
    *(short8*)(Bs + srow*40 + koff)     = bv0;
    *(short8*)(Bs + srow*40 + koff + 8) = bv1;
    __syncthreads();
    short8 af[4], bfr[4];
    #pragma unroll
    for (int i = 0; i < 4; ++i)
      af[i] = *(const short8*)(As + (wm*64 + i*16 + ln)*40 + quad*8);
    #pragma unroll
    for (int j = 0; j < 4; ++j)
      bfr[j] = *(const short8*)(Bs + (wn*64 + j*16 + ln)*40 + quad*8);
    #pragma unroll
    for (int i = 0; i < 4; ++i)
      #pragma unroll
      for (int j = 0; j < 4; ++j)
        acc[i][j] = __builtin_amdgcn_mfma_f32_16x16x32_bf16(af[i], bfr[j], acc[i][j], 0, 0, 0);
    __syncthreads();
  }

  const u16* addz = (z == 0) ? add0 : add1;
  #pragma unroll
  for (int j = 0; j < 4; ++j){
    int col = nb*128 + wn*64 + j*16 + ln;
    if (col < N){
      float bias = 0.0f;
      if (b1) bias += ldf(b1, (size_t)z*biasStride + col, bf);
      if (b2) bias += ldf(b2, (size_t)z*biasStride + col, bf);
      #pragma unroll
      for (int i = 0; i < 4; ++i){
        #pragma unroll
        for (int rg = 0; rg < 4; ++rg){
          int row = mb*128 + wm*64 + i*16 + quad*4 + rg;
          float v = acc[i][j][rg] + bias;
          if (addz) v += u2f(addz[(size_t)row*N + col]);
          size_t oi = (size_t)z*Ostride + (size_t)row*N + col;
          if (outBf) ((u16*)out)[oi] = f2bu(v);
          else       ((float*)out)[oi] = v;
        }
      }
    }
  }
}

// ---------------------------------------------------------------------------
// Kernel 4: LSTM cell pointwise update. Writes h -> Hbf (bf16, stride 480),
// y -> Y0bf (bf16, stride 928) or Y1 (f32, stride 900), finals -> HF.
// ---------------------------------------------------------------------------
__global__ __launch_bounds__(256) void k_cell(
    const float* __restrict__ GT, float* __restrict__ HC,
    u16* __restrict__ Hbf, u16* __restrict__ Ybf, float* __restrict__ Yf,
    float* __restrict__ HF, int s, int layer)
{
  int idx = blockIdx.x*256 + threadIdx.x;
  if (idx >= 2*256*450) return;
  int k = idx % 450;
  int rb = idx / 450;
  int b = rb % 256;
  int dir = rb / 256;
  int t_eff = dir ? (4 - s) : s;
  const float* g = GT + ((size_t)dir*256 + b)*1800;
  float gi = g[k], gf = g[450+k], gg = g[900+k], go = g[1350+k];
  float* cp = HC + ((size_t)(2+dir)*256 + b)*450 + k;
  float c = sigm(gf)*(*cp) + sigm(gi)*tanhf(gg);
  float hv = sigm(go)*tanhf(c);
  *cp = c;
  Hbf[((size_t)dir*256 + b)*480 + k] = f2bu(hv);
  if (Ybf) Ybf[((size_t)t_eff*256 + b)*928 + dir*450 + k] = f2bu(hv);
  else     Yf [((size_t)t_eff*256 + b)*900 + dir*450 + k] = hv;
  HF[((size_t)(layer*2+dir)*256 + b)*450 + k] = hv;
}

// ---------------------------------------------------------------------------
// Kernel 5: attention over timesteps + context.
// hidden[b][h][l] = HF_flat[b*1800 + h*2 + l]  (reference reshape quirk)
// ---------------------------------------------------------------------------
__global__ __launch_bounds__(256) void k_attn(
    const float* __restrict__ Y1, const float* __restrict__ HF,
    float* __restrict__ CTX)
{
  __shared__ float red[256];
  __shared__ float sc[10];
  __shared__ float aw[10];
  int b = blockIdx.x, tid = threadIdx.x;
  for (int p = 0; p < 10; ++p){
    int t = p >> 1, l = p & 1;
    float a = 0.0f;
    for (int h = tid; h < 900; h += 256)
      a += Y1[((size_t)t*256 + b)*900 + h] * HF[(size_t)b*1800 + h*2 + l];
    red[tid] = a; __syncthreads();
    for (int off = 128; off > 0; off >>= 1){
      if (tid < off) red[tid] += red[tid+off];
      __syncthreads();
    }
    if (tid == 0) sc[p] = red[0];
    __syncthreads();
  }
  if (tid < 2){
    int l = tid;
    float mxv = -3.0e38f;
    for (int t = 0; t < 5; ++t) mxv = fmaxf(mxv, sc[t*2+l]);
    float e[5], sum = 0.0f;
    for (int t = 0; t < 5; ++t){ e[t] = expf(sc[t*2+l]-mxv); sum += e[t]; }
    for (int t = 0; t < 5; ++t) aw[t*2+l] = e[t]/sum;
  }
  __syncthreads();
  for (int h = tid; h < 900; h += 256){
    float v0 = 0.0f, v1 = 0.0f;
    for (int t = 0; t < 5; ++t){
      float y = Y1[((size_t)t*256 + b)*900 + h];
      v0 += y*aw[t*2+0]; v1 += y*aw[t*2+1];
    }
    CTX[(size_t)b*1800 + h*2 + 0] = v0;
    CTX[(size_t)b*1800 + h*2 + 1] = v1;
  }
}

// ---------------------------------------------------------------------------
// Kernel 2s: scalar GEMM (kept only for CTX @ out_w, C=100).
// ---------------------------------------------------------------------------
__global__ __launch_bounds__(256) void k_gemm(
    const float* __restrict__ A, const void* __restrict__ W, size_t wEl,
    const void* __restrict__ b1, const void* __restrict__ b2, size_t bEl,
    const int* __restrict__ flag,
    float* __restrict__ out, int K, int C)
{
  extern __shared__ float a_s[];
  const int bf = *flag;
  const int tid = threadIdx.x;
  const int r = blockIdx.y;
  const float* a = A + (size_t)r*K;
  for (int k = tid; k < K; k += 256) a_s[k] = a[k];
  __syncthreads();
  const int j = blockIdx.x*256 + tid;
  if (j >= C) return;
  float acc = 0.0f;
  if (b1) acc += ldf(b1, bEl + j, bf);
  if (b2) acc += ldf(b2, bEl + j, bf);
  if (bf){
    const u16* w = (const u16*)W + wEl + (size_t)j*K;
    for (int k = 0; k < K; k += 4){
      uint2 wv = *(const uint2*)(w + k);
      acc += a_s[k]   * u2f(wv.x & 0xffffu);
      acc += a_s[k+1] * u2f(wv.x >> 16);
      acc += a_s[k+2] * u2f(wv.y & 0xffffu);
      acc += a_s[k+3] * u2f(wv.y >> 16);
    }
  } else {
    const float* w = (const float*)W + wEl + (size_t)j*K;
    for (int k = 0; k < K; k += 4){
      float4 wv = *(const float4*)(w + k);
      acc += a_s[k]*wv.x + a_s[k+1]*wv.y + a_s[k+2]*wv.z + a_s[k+3]*wv.w;
    }
  }
  out[(size_t)r*C + j] = acc;
}

__device__ __forceinline__ float bred128(float v, float* red, int tid){
  red[tid] = v; __syncthreads();
  for (int off = 64; off > 0; off >>= 1){
    if (tid < off) red[tid] += red[tid+off];
    __syncthreads();
  }
  float r = red[0]; __syncthreads();
  return r;
}

// ---------------------------------------------------------------------------
// Kernel 6: analytic meta-gradient -> rel_q, norm_q. One block per b.
// ---------------------------------------------------------------------------
__global__ __launch_bounds__(128) void k_grad(
    const void* __restrict__ sup, const void* __restrict__ supn,
    const void* __restrict__ normv, const float* __restrict__ REL,
    const int* __restrict__ flag,
    float* __restrict__ RELQ, float* __restrict__ NORMQ)
{
  __shared__ float red[128];
  __shared__ float nv[100], rl[100], acc[100];
  const int bf = *flag;
  int b = blockIdx.x, tid = threadIdx.x;
  if (tid < 100){
    nv[tid] = ldf(normv, b*100+tid, bf);
    rl[tid] = REL[b*100+tid];
    acc[tid] = 0.0f;
  }
  __syncthreads();
  float nvd = (tid < 100) ? nv[tid] : 0.0f;
  float rld = (tid < 100) ? rl[tid] : 0.0f;
  for (int j = 0; j < 5; ++j){
    float h1=0.f,t1=0.f,h2=0.f,t2=0.f;
    if (tid < 100){
      size_t base = (size_t)(b*5+j)*200;
      h1 = ldf(sup,  base + tid, bf);  t1 = ldf(sup,  base + 100 + tid, bf);
      h2 = ldf(supn, base + tid, bf);  t2 = ldf(supn, base + 100 + tid, bf);
    }
    float hd1 = bred128(h1*nvd, red, tid);
    float td1 = bred128(t1*nvd, red, tid);
    float hd2 = bred128(h2*nvd, red, tid);
    float td2 = bred128(t2*nvd, red, tid);
    float upd = (h1 - hd1*nvd) + rld - (t1 - td1*nvd);
    float und = (h2 - hd2*nvd) + rld - (t2 - td2*nvd);
    if (tid >= 100){ upd = 0.0f; und = 0.0f; }
    float np2 = bred128(upd*upd, red, tid);
    float nn2 = bred128(und*und, red, tid);
    float p = -sqrtf(np2), nsc = -sqrtf(nn2);
    if ((1.0f - (p - nsc) > 0.0f) && tid < 100)
      acc[tid] += upd/sqrtf(np2) - und/sqrtf(nn2);
  }
  __syncthreads();
  if (tid < 100){
    float g = acc[tid] * (1.0f/1280.0f);
    RELQ[b*100+tid]  = rl[tid] - 5.0f*g;
    NORMQ[b*100+tid] = nv[tid] - 5.0f*g;
  }
}

// ---------------------------------------------------------------------------
// Kernel 7: final scores (10 query + 512 negative per b).
// One WAVE per row: lanes 0..49 hold the row's 200 elems as float4 in regs
// (800 B contiguous per wave -> fully coalesced, each byte fetched once).
// hd/td/s2 via 64-lane shfl_xor reductions; t-values reach h-lanes via shfl.
// ---------------------------------------------------------------------------
__global__ __launch_bounds__(256) void k_score(
    const void* __restrict__ query, const void* __restrict__ neg,
    const float* __restrict__ RELQ, const float* __restrict__ NORMQ,
    const int* __restrict__ flag, void* __restrict__ out)
{
  __shared__ __align__(16) float nq[104], rq[104];
  const int bf = *flag;
  const int b = blockIdx.x, tid = threadIdx.x;
  if (tid < 100){ nq[tid] = NORMQ[b*100+tid]; rq[tid] = RELQ[b*100+tid]; }
  __syncthreads();
  const int wid = tid >> 6, lane = tid & 63;
  const int d0 = lane*4;
  const int nidx = (lane < 25) ? d0 : (d0 - 100);
  float4 w4 = make_float4(0.0f,0.0f,0.0f,0.0f);
  float4 r4 = make_float4(0.0f,0.0f,0.0f,0.0f);
  if (lane < 50) w4 = *(const float4*)(nq + nidx);
  if (lane < 25) r4 = *(const float4*)(rq + d0);

  for (int qi = blockIdx.y*4 + wid; qi < 522; qi += 32){
    const void* src = (qi < 10) ? query : neg;
    size_t row = (qi < 10) ? ((size_t)b*10 + qi) : ((size_t)b*512 + qi - 10);
    size_t base = row*200;
    float4 v = make_float4(0.0f,0.0f,0.0f,0.0f);
    if (lane < 50){
      if (bf){
        uint2 u = *(const uint2*)((const u16*)src + base + d0);
        v.x = u2f(u.x & 0xffffu); v.y = u2f(u.x >> 16);
        v.z = u2f(u.y & 0xffffu); v.w = u2f(u.y >> 16);
      } else {
        v = *(const float4*)((const float*)src + base + d0);
      }
    }
    float p = v.x*w4.x + v.y*w4.y + v.z*w4.z + v.w*w4.w;
    float hd = wsum(lane < 25 ? p : 0.0f);
    float td = wsum((lane >= 25 && lane < 50) ? p : 0.0f);
    int sl = (lane < 25) ? (lane + 25) : lane;
    float4 t4;
    t4.x = __shfl(v.x, sl, 64);
    t4.y = __shfl(v.y, sl, 64);
    t4.z = __shfl(v.z, sl, 64);
    t4.w = __shfl(v.w, sl, 64);
    float s2p = 0.0f;
    if (lane < 25){
      float ux = (v.x - hd*w4.x) + r4.x - (t4.x - td*w4.x);
      float uy = (v.y - hd*w4.y) + r4.y - (t4.y - td*w4.y);
      float uz = (v.z - hd*w4.z) + r4.z - (t4.z - td*w4.z);
      float uw = (v.w - hd*w4.w) + r4.w - (t4.w - td*w4.w);
      s2p = ux*ux + uy*uy + uz*uz + uw*uw;
    }
    float s2 = wsum(s2p);
    if (lane == 0){
      float sc = -sqrtf(s2);
      size_t oi = (qi < 10) ? ((size_t)b*10 + qi) : (2560 + (size_t)b*512 + (qi - 10));
      if (bf) ((u16*)out)[oi] = f2bu(sc);
      else    ((float*)out)[oi] = sc;
    }
  }
}

// ---------------------------------------------------------------------------
extern "C" void kernel_launch(void* const* d_in, const int* in_sizes, int n_in,
                              void* d_out, int out_size, void* d_ws, size_t ws_size,
                              hipStream_t stream)
{
  const void* support = d_in[0];
  const void* supneg  = d_in[1];
  const void* query   = d_in[2];
  const void* negat   = d_in[3];
  const void* normv   = d_in[4];
  const int* left     = (const int*)d_in[5];
  const int* right    = (const int*)d_in[6];
  const void* emb     = d_in[7];
  const void* gcnw    = d_in[8];
  const void* gcnwb   = d_in[9];
  const void* gcnb    = d_in[10];
  const void* attnw   = d_in[11];
  const void* attnwb  = d_in[12];
  const void* gatew   = d_in[13];
  const void* gatewb  = d_in[14];
  const void* gateb   = d_in[15];
  const void* Wih0    = d_in[16];
  const void* Whh0    = d_in[17];
  const void* bih0    = d_in[18];
  const void* bhh0    = d_in[19];
  const void* Wih1    = d_in[20];
  const void* Whh1    = d_in[21];
  const void* bih1    = d_in[22];
  const void* bhh1    = d_in[23];
  const void* outw    = d_in[24];
  const void* outb    = d_in[25];

  int*   dflag = (int*)d_ws;
  float* fws   = (float*)d_ws + 16;
  // f32 region
  float* Y1   = fws;                 // 5*256*900  = 1,152,000
  float* HF   = Y1 + 1152000;        // 4*256*450  =   460,800
  float* HC   = HF + 460800;         //               460,800 (c-state in [2..4))
  float* CTX  = HC + 460800;         //               460,800
  float* RELb = CTX + 460800;        //    25,600
  float* RELQ = RELb + 25600;        //    25,600
  float* NORMQ= RELQ + 25600;        //    25,600
  float* GT   = NORMQ + 25600;       // 2*256*1800 =   921,600
  float* fend = GT + 921600;
  // u16 region (16B-aligned: fend offset is a multiple of 16 floats)
  u16* Gb   = (u16*)fend;            // 2*5*256*1800 = 4,608,000
  u16* X0bf = Gb + 4608000;          // 1280*224     =   286,720
  u16* Y0bf = X0bf + 286720;         // 1280*928     = 1,187,840
  u16* Hbf  = Y0bf + 1187840;        // 2*256*480    =   245,760
  u16* Wp   = Hbf + 245760;          // 3600*928 max = 3,340,800
  u16* Whp  = Wp + 3340800;          // 3600*480     = 1,728,000
  u16* Wg   = Whp + 1728000;         // 112*224      =    25,088
  // total ≈ 37.0 MB

  k_detect<<<1, 64, 0, stream>>>((const u32*)normv, dflag);

  // neighbor encoder -> X0bf (memset for zero pad first)
  hipMemsetAsync(X0bf, 0, 286720*sizeof(u16), stream);
  k_pack<<<(112*224+255)/256, 256, 0, stream>>>(gcnw, Wg, 200, 224, 100, 112, dflag);
  k_gcn<<<2560, 512, 0, stream>>>(left, right, emb, Wg, gcnwb, gcnb,
                                  attnw, attnwb, gatew, gatewb, gateb,
                                  dflag, X0bf);

  // ---- layer 0 ----
  hipMemsetAsync(Y0bf, 0, 1187840*sizeof(u16), stream);
  hipMemsetAsync(Hbf, 0, 245760*sizeof(u16), stream);
  hipMemsetAsync(HC, 0, 460800*sizeof(float), stream);
  k_pack<<<(3600*224+255)/256, 256, 0, stream>>>(Wih0, Wp,  200, 224, 3600, 3600, dflag);
  k_pack<<<(3600*480+255)/256, 256, 0, stream>>>(Whh0, Whp, 450, 480, 3600, 3600, dflag);
  // input projection: G[z][t][b][:] (bf16 out)
  k_mgemm<<<dim3(15,10,2), 256, 0, stream>>>(
      X0bf, 224, 0, Wp, 224, (size_t)1800*224,
      bih0, bhh0, 1800, dflag, nullptr, nullptr,
      Gb, 1, 2304000, 1800, 7);
  for (int s = 0; s < 5; ++s){
    k_mgemm<<<dim3(15,2,2), 256, 0, stream>>>(
        Hbf, 480, (size_t)256*480, Whp, 480, (size_t)1800*480,
        nullptr, nullptr, 0, dflag,
        Gb + (size_t)s*460800, Gb + (size_t)(9-s)*460800,
        GT, 0, 460800, 1800, 15);
    k_cell<<<900, 256, 0, stream>>>(GT, HC, Hbf, Y0bf, nullptr, HF, s, 0);
  }

  // ---- layer 1 ----
  hipMemsetAsync(Hbf, 0, 245760*sizeof(u16), stream);
  hipMemsetAsync(HC, 0, 460800*sizeof(float), stream);
  k_pack<<<(3600*928+255)/256, 256, 0, stream>>>(Wih1, Wp,  900, 928, 3600, 3600, dflag);
  k_pack<<<(3600*480+255)/256, 256, 0, stream>>>(Whh1, Whp, 450, 480, 3600, 3600, dflag);
  k_mgemm<<<dim3(15,10,2), 256, 0, stream>>>(
      Y0bf, 928, 0, Wp, 928, (size_t)1800*928,
      bih1, bhh1, 1800, dflag, nullptr, nullptr,
      Gb, 1, 2304000, 1800, 29);
  for (int s = 0; s < 5; ++s){
    k_mgemm<<<dim3(15,2,2), 256, 0, stream>>>(
        Hbf, 480, (size_t)256*480, Whp, 480, (size_t)1800*480,
        nullptr, nullptr, 0, dflag,
        Gb + (size_t)s*460800, Gb + (size_t)(9-s)*460800,
        GT, 0, 460800, 1800, 15);
    k_cell<<<900, 256, 0, stream>>>(GT, HC, Hbf, nullptr, Y1, HF, s, 1);
  }

  k_attn<<<256, 256, 0, stream>>>(Y1, HF, CTX);
  k_gemm<<<dim3(1,256), 256, 1800*4, stream>>>(CTX, outw, 0, outb, nullptr, 0,
                                               dflag, RELb, 1800, 100);
  k_grad<<<256, 128, 0, stream>>>(support, supneg, normv, RELb, dflag, RELQ, NORMQ);
  k_score<<<dim3(256,8), 256, 0, stream>>>(query, negat, RELQ, NORMQ, dflag, d_out);
}

// Round 5
// 780.944 us; speedup vs baseline: 1.4245x; 1.2294x over previous
//
#include <hip/hip_runtime.h>

typedef unsigned short u16;
typedef unsigned int   u32;
typedef __attribute__((ext_vector_type(8))) short short8;
typedef __attribute__((ext_vector_type(4))) float f32x4;

__device__ __forceinline__ float u2f(u32 u){
  union { u32 i; float f; } v; v.i = u << 16; return v.f;
}
__device__ __forceinline__ u16 f2bu(float f){
  union { float f; u32 i; } v; v.f = f;
  u32 i = v.i;
  i += 0x7fffu + ((i >> 16) & 1u);   // round-to-nearest-even
  return (u16)(i >> 16);
}
__device__ __forceinline__ float sigm(float x){ return 1.0f/(1.0f + expf(-x)); }
__device__ __forceinline__ float ldf(const void* p, size_t i, int bf){
  return bf ? u2f(((const u16*)p)[i]) : ((const float*)p)[i];
}
__device__ __forceinline__ float wsum(float v){
  #pragma unroll
  for (int off = 32; off > 0; off >>= 1) v += __shfl_xor(v, off, 64);
  return v;
}

// ---------------------------------------------------------------------------
// Kernel 0: dtype detector (bf16 vs f32 device buffers).
// ---------------------------------------------------------------------------
__global__ __launch_bounds__(64) void k_detect(const u32* __restrict__ nv,
                                               int* __restrict__ flag)
{
  int i = threadIdx.x;
  u32 w = nv[i];
  u32 e = (w >> 7) & 0xffu;
  bool sane = (e >= 100u && e <= 140u);
  unsigned long long m = __ballot(sane);
  if (i == 0) *flag = (__popcll(m) >= 40) ? 1 : 0;
}

// ---------------------------------------------------------------------------
// Kernel P: pack weights -> bf16, [Rp rows][Kp cols]; zero for k>=K or r>=R.
// (kept for gcn_w only)
// ---------------------------------------------------------------------------
__global__ __launch_bounds__(256) void k_pack(
    const void* __restrict__ src, u16* __restrict__ dst,
    int K, int Kp, int R, int Rp, const int* __restrict__ flag)
{
  const int bf = *flag;
  int total = Rp*Kp;
  int idx = blockIdx.x*256 + threadIdx.x;
  if (idx >= total) return;
  int r = idx / Kp, k = idx - r*Kp;
  u16 v = 0;
  if (k < K && r < R){
    size_t si = (size_t)r*K + k;
    v = bf ? ((const u16*)src)[si] : f2bu(((const float*)src)[si]);
  }
  dst[idx] = v;
}

// ---------------------------------------------------------------------------
// Kernel Pg: gate-interleaved LSTM weight pack. src [2][1800=gate*450+k][K]
// -> dst [2][1920][Kp], row' = (k/16)*64 + gate*16 + (k%16). Zero pad.
// With this layout a 64-col' MFMA group holds {gate j at col j*16+ln, k =
// kblk*16+ln} -> all 4 gates of one k live in ONE lane's acc[j].
// ---------------------------------------------------------------------------
__global__ __launch_bounds__(256) void k_packg(
    const void* __restrict__ src, u16* __restrict__ dst,
    int K, int Kp, const int* __restrict__ flag)
{
  const int bf = *flag;
  int per = 1920*Kp;
  int idx = blockIdx.x*256 + threadIdx.x;
  if (idx >= 2*per) return;
  int z = idx / per, r = idx - z*per;
  int rp = r / Kp, c = r - rp*Kp;
  int kblk = rp >> 6, rem = rp & 63, gate = rem >> 4, klo = rem & 15;
  int k = kblk*16 + klo;
  u16 v = 0;
  if (k < 450 && c < K){
    size_t si = ((size_t)z*1800 + (size_t)gate*450 + k)*K + c;
    v = bf ? ((const u16*)src)[si] : f2bu(((const float*)src)[si]);
  }
  dst[idx] = v;
}

// ---------------------------------------------------------------------------
// Kernel Pb: permuted bias pack: Bp[z][1920] f32 = bih+bhh at (gate,k).
// ---------------------------------------------------------------------------
__global__ __launch_bounds__(256) void k_packb(
    const void* __restrict__ bih, const void* __restrict__ bhh,
    float* __restrict__ Bp, const int* __restrict__ flag)
{
  const int bf = *flag;
  int idx = blockIdx.x*256 + threadIdx.x;
  if (idx >= 2*1920) return;
  int z = idx / 1920, rp = idx - z*1920;
  int kblk = rp >> 6, rem = rp & 63, gate = rem >> 4, klo = rem & 15;
  int k = kblk*16 + klo;
  float v = 0.0f;
  if (k < 450){
    size_t si = (size_t)z*1800 + (size_t)gate*450 + k;
    v = ldf(bih, si, bf) + ldf(bhh, si, bf);
  }
  Bp[idx] = v;
}

// ---------------------------------------------------------------------------
// Kernel 1: neighbor encoder (round-4 verified, unchanged).
// ---------------------------------------------------------------------------
__global__ __launch_bounds__(512, 4) void k_gcn(
    const int* __restrict__ left, const int* __restrict__ right,
    const void* __restrict__ emb, const u16* __restrict__ Wg,
    const void* __restrict__ gcnwb, const void* __restrict__ gcnb,
    const void* __restrict__ attnw, const void* __restrict__ attnwb,
    const void* __restrict__ gatew, const void* __restrict__ gatewb,
    const void* __restrict__ gateb,
    const int* __restrict__ flag,
    u16* __restrict__ X0bf)
{
  __shared__ __align__(16) u16 As[208*40];    // 16640 B
  __shared__ __align__(16) u16 Bs[112*232];   // 51968 B
  __shared__ int c1_s[200], c2_s[200];
  __shared__ float logit_s[208];
  __shared__ float red_s[512];
  __shared__ float attnw_s[112], bias_s[112], gatew_s[112], oa_s[112];

  const int bf  = *flag;
  const int tid = threadIdx.x;
  const int n   = blockIdx.x;
  const int b   = n & 255;
  const int fs  = n >> 8;
  const int s   = fs & 1;
  const int f   = fs >> 1;
  const int* conn = (s == 0 ? left : right) + (size_t)(f*256 + b)*600;

  const u16*   e16 = (const u16*)emb;
  const float* e32 = (const float*)emb;

  if (tid < 200){ c1_s[tid] = conn[tid*3+1]; c2_s[tid] = conn[tid*3+2]; }
  if (tid < 112){
    attnw_s[tid] = (tid < 100) ? ldf(attnw, tid, bf) : 0.0f;
    bias_s[tid]  = (tid < 100) ? (ldf(gcnwb, tid, bf) + ldf(gcnb, tid, bf)) : 0.0f;
    gatew_s[tid] = (tid < 100) ? ldf(gatew, tid, bf) : 0.0f;
    oa_s[tid] = 0.0f;
  }
  for (int g = tid; g < 112*28; g += 512){
    int r = g / 28, cc = g - r*28;
    *(short8*)(Bs + r*232 + cc*8) = *(const short8*)(Wg + (size_t)r*224 + cc*8);
  }
  __syncthreads();

  const int wid  = tid >> 6, lane = tid & 63, ln = lane & 15, quad = lane >> 4;
  const int mt0 = (wid < 5) ? 2*wid : (10 + (wid - 5));
  const int nmt = (wid < 5) ? 2 : 1;

  f32x4 acc[2][7];
  #pragma unroll
  for (int i = 0; i < 2; ++i)
    #pragma unroll
    for (int j = 0; j < 7; ++j) acc[i][j] = (f32x4)0.0f;

  for (int kc = 0; kc < 7; ++kc){
    const int k0 = kc*32;
    for (int g = tid; g < 208*8; g += 512){
      int r = g >> 3, gi = g & 7, k = k0 + gi*4;
      uint2 v; v.x = 0u; v.y = 0u;
      if (r < 200 && k < 200){
        int c  = (k < 100) ? c1_s[r] : c2_s[r];
        int kk = (k < 100) ? k : (k - 100);
        size_t idx = (size_t)c*100 + kk;
        if (bf) v = *(const uint2*)(e16 + idx);
        else {
          float4 t = *(const float4*)(e32 + idx);
          v.x = (u32)f2bu(t.x) | ((u32)f2bu(t.y) << 16);
          v.y = (u32)f2bu(t.z) | ((u32)f2bu(t.w) << 16);
        }
      }
      *(uint2*)(As + r*40 + gi*4) = v;
    }
    __syncthreads();

    #pragma unroll
    for (int mi = 0; mi < 2; ++mi){
      if (mi < nmt){
        short8 afr = *(const short8*)(As + ((mt0+mi)*16 + ln)*40 + quad*8);
        #pragma unroll
        for (int nt = 0; nt < 7; ++nt){
          short8 bfr = *(const short8*)(Bs + (size_t)(nt*16 + ln)*232 + k0 + quad*8);
          acc[mi][nt] = __builtin_amdgcn_mfma_f32_16x16x32_bf16(afr, bfr, acc[mi][nt], 0, 0, 0);
        }
      }
    }
    __syncthreads();
  }

  const float awb = ldf(attnwb, 0, bf);
  #pragma unroll
  for (int mi = 0; mi < 2; ++mi){
    if (mi < nmt){
      #pragma unroll
      for (int rg = 0; rg < 4; ++rg){
        float p = 0.0f;
        #pragma unroll
        for (int nt = 0; nt < 7; ++nt){
          float x = acc[mi][nt][rg] + bias_s[nt*16 + ln];
          x = x > 0.0f ? x : 0.01f*x;
          p += x * attnw_s[nt*16 + ln];
        }
        p += __shfl_xor(p, 1, 64); p += __shfl_xor(p, 2, 64);
        p += __shfl_xor(p, 4, 64); p += __shfl_xor(p, 8, 64);
        int m = (mt0+mi)*16 + quad*4 + rg;
        if (ln == 0 && m < 200) logit_s[m] = p + awb;
      }
    }
  }
  __syncthreads();

  red_s[tid] = (tid < 200) ? logit_s[tid] : -3.0e38f;
  __syncthreads();
  for (int off = 256; off > 0; off >>= 1){
    if (tid < off) red_s[tid] = fmaxf(red_s[tid], red_s[tid+off]);
    __syncthreads();
  }
  float mx = red_s[0];
  __syncthreads();
  float ev = 0.0f;
  if (tid < 200) ev = expf(logit_s[tid] - mx);
  red_s[tid] = ev;
  __syncthreads();
  for (int off = 256; off > 0; off >>= 1){
    if (tid < off) red_s[tid] += red_s[tid+off];
    __syncthreads();
  }
  float S = red_s[0];
  __syncthreads();
  if (tid < 208) logit_s[tid] = (tid < 200) ? ev*(1.0f/S) : 0.0f;
  __syncthreads();

  float at[2][4];
  #pragma unroll
  for (int mi = 0; mi < 2; ++mi)
    #pragma unroll
    for (int rg = 0; rg < 4; ++rg)
      at[mi][rg] = (mi < nmt) ? logit_s[(mt0+mi)*16 + quad*4 + rg] : 0.0f;

  #pragma unroll
  for (int nt = 0; nt < 7; ++nt){
    float p = 0.0f;
    #pragma unroll
    for (int mi = 0; mi < 2; ++mi){
      if (mi < nmt){
        #pragma unroll
        for (int rg = 0; rg < 4; ++rg){
          float x = acc[mi][nt][rg] + bias_s[nt*16 + ln];
          x = x > 0.0f ? x : 0.01f*x;
          p += x * at[mi][rg];
        }
      }
    }
    p += __shfl_xor(p, 16, 64); p += __shfl_xor(p, 32, 64);
    if (quad == 0) atomicAdd(&oa_s[nt*16 + ln], p);
  }
  __syncthreads();

  red_s[tid] = (tid < 100) ? oa_s[tid]*gatew_s[tid] : 0.0f;
  __syncthreads();
  for (int off = 256; off > 0; off >>= 1){
    if (tid < off) red_s[tid] += red_s[tid+off];
    __syncthreads();
  }
  float gate = sigm(red_s[0] + ldf(gatewb, 0, bf) + ldf(gateb, 0, bf));
  if (tid < 100){
    int c0 = conn[0];
    float self = ldf(emb, (size_t)c0*100 + tid, bf);
    X0bf[((size_t)f*256 + b)*224 + s*100 + tid] = f2bu(oa_s[tid]*gate + self*(1.0f - gate));
  }
}

// ---------------------------------------------------------------------------
// Kernel M: MFMA GEMM (input projections only). out[z][row][col'] bf16 =
// A[row]·B'[col'] + Bp[z][col']. N=1920 exact (15x128 tiles), M mult of 128.
// ---------------------------------------------------------------------------
__global__ __launch_bounds__(256) void k_mgemm(
    const u16* __restrict__ A, int lda, size_t Astride,
    const u16* __restrict__ B, int ldb, size_t Bstride,
    const float* __restrict__ bsum,
    u16* __restrict__ out, size_t Ostride,
    int N, int KC)
{
  __shared__ __align__(16) u16 As[128*40];
  __shared__ __align__(16) u16 Bs[128*40];
  const int tid = threadIdx.x;
  const int z  = blockIdx.z;
  const int nb = blockIdx.x, mb = blockIdx.y;
  const u16* Az = A + (size_t)z*Astride;
  const u16* Bz = B + (size_t)z*Bstride;

  const int wid = tid >> 6, lane = tid & 63, ln = lane & 15, quad = lane >> 4;
  const int wm = wid >> 1, wn = wid & 1;

  f32x4 acc[4][4];
  #pragma unroll
  for (int i = 0; i < 4; ++i)
    #pragma unroll
    for (int j = 0; j < 4; ++j) acc[i][j] = (f32x4)0.0f;

  const int srow = tid >> 1;
  const int koff = (tid & 1)*16;
  const int rowA = mb*128 + srow;
  const int rowB = nb*128 + srow;

  for (int kc = 0; kc < KC; ++kc){
    const int k0 = kc*32 + koff;
    const u16* ap = Az + (size_t)rowA*lda + k0;
    const u16* bp = Bz + (size_t)rowB*ldb + k0;
    short8 av0 = *(const short8*)(ap);
    short8 av1 = *(const short8*)(ap + 8);
    short8 bv0 = *(const short8*)(bp);
    short8 bv1 = *(const short8*)(bp + 8);
    *(short8*)(As + srow*40 + koff)     = av0;
    *(short8*)(As + srow*40 + koff + 8) = av1;
    *(short8*)(Bs + srow*40 + koff)     = bv0;
    *(short8*)(Bs + srow*40 + koff + 8) = bv1;
    __syncthreads();
    short8 af[4], bfr[4];
    #pragma unroll
    for (int i = 0; i < 4; ++i)
      af[i] = *(const short8*)(As + (wm*64 + i*16 + ln)*40 + quad*8);
    #pragma unroll
    for (int j = 0; j < 4; ++j)
      bfr[j] = *(const short8*)(Bs + (wn*64 + j*16 + ln)*40 + quad*8);
    #pragma unroll
    for (int i = 0; i < 4; ++i)
      #pragma unroll
      for (int j = 0; j < 4; ++j)
        acc[i][j] = __builtin_amdgcn_mfma_f32_16x16x32_bf16(af[i], bfr[j], acc[i][j], 0, 0, 0);
    __syncthreads();
  }

  #pragma unroll
  for (int j = 0; j < 4; ++j){
    int col = nb*128 + wn*64 + j*16 + ln;
    float bias = bsum ? bsum[(size_t)z*1920 + col] : 0.0f;
    #pragma unroll
    for (int i = 0; i < 4; ++i){
      #pragma unroll
      for (int rg = 0; rg < 4; ++rg){
        int row = mb*128 + wm*64 + i*16 + quad*4 + rg;
        out[(size_t)z*Ostride + (size_t)row*N + col] = f2bu(acc[i][j][rg] + bias);
      }
    }
  }
}

// ---------------------------------------------------------------------------
// Kernel H: fused hidden GEMM + LSTM cell. Grid (15,8,2)=240 blocks.
// Tile 32 rows x 128 cols'; 4 waves = 2 wm x 2 wn, wave tile 16x64,
// acc[4] (j = gate). B = gate-interleaved Whp' [2][1920][480].
// Epilogue: lane owns (b = mb*32+wm*16+quad*4+rg, k = (nb*2+wn)*16+ln) with
// all 4 gate pre-acts in acc[0..3][rg] + Gb addend -> cell update in-place.
// Hbf parity double-buffered (read Hin, write Hout) to avoid RW race.
// ---------------------------------------------------------------------------
__global__ __launch_bounds__(256) void k_hstep(
    const u16* __restrict__ Hin, const u16* __restrict__ Whp,
    const u16* __restrict__ Gb, float* __restrict__ HC,
    u16* __restrict__ Hout, u16* __restrict__ Ybf, float* __restrict__ Yf,
    float* __restrict__ HF, int s, int layer)
{
  __shared__ __align__(16) u16 As[32*40];
  __shared__ __align__(16) u16 Bs[128*40];
  const int tid = threadIdx.x;
  const int nb = blockIdx.x, mb = blockIdx.y, z = blockIdx.z;
  const int wid = tid >> 6, lane = tid & 63, ln = lane & 15, quad = lane >> 4;
  const int wm = wid >> 1, wn = wid & 1;

  const u16* Az = Hin + ((size_t)z*256 + mb*32)*480;
  const u16* Bz = Whp + (size_t)z*1920*480 + (size_t)nb*128*480;

  f32x4 acc[4];
  #pragma unroll
  for (int j = 0; j < 4; ++j) acc[j] = (f32x4)0.0f;

  const int ar = tid >> 2, ap = tid & 3;   // A: first 128 threads
  const int br = tid >> 1, bp = tid & 1;   // B: all 256 threads
  for (int kc = 0; kc < 15; ++kc){
    const int k0 = kc*32;
    if (tid < 128)
      *(short8*)(As + ar*40 + ap*8) = *(const short8*)(Az + (size_t)ar*480 + k0 + ap*8);
    *(short8*)(Bs + br*40 + bp*16)     = *(const short8*)(Bz + (size_t)br*480 + k0 + bp*16);
    *(short8*)(Bs + br*40 + bp*16 + 8) = *(const short8*)(Bz + (size_t)br*480 + k0 + bp*16 + 8);
    __syncthreads();
    short8 afr = *(const short8*)(As + (wm*16 + ln)*40 + quad*8);
    #pragma unroll
    for (int j = 0; j < 4; ++j){
      short8 bfr = *(const short8*)(Bs + (wn*64 + j*16 + ln)*40 + quad*8);
      acc[j] = __builtin_amdgcn_mfma_f32_16x16x32_bf16(afr, bfr, acc[j], 0, 0, 0);
    }
    __syncthreads();
  }

  const int kblk = nb*2 + wn;
  const int k = kblk*16 + ln;
  const int t = z ? (4 - s) : s;
  if (k < 450){
    const u16* Gz = Gb + (size_t)z*2457600 + (size_t)t*256*1920;
    #pragma unroll
    for (int rg = 0; rg < 4; ++rg){
      int b = mb*32 + wm*16 + quad*4 + rg;
      const u16* grow = Gz + (size_t)b*1920 + nb*128 + wn*64 + ln;
      float gi = acc[0][rg] + u2f(grow[0]);
      float gf = acc[1][rg] + u2f(grow[16]);
      float gg = acc[2][rg] + u2f(grow[32]);
      float go = acc[3][rg] + u2f(grow[48]);
      float* cp = HC + ((size_t)(2+z)*256 + b)*450 + k;
      float c = sigm(gf)*(*cp) + sigm(gi)*tanhf(gg);
      float h = sigm(go)*tanhf(c);
      *cp = c;
      Hout[((size_t)z*256 + b)*480 + k] = f2bu(h);
      if (Ybf) Ybf[((size_t)t*256 + b)*928 + z*450 + k] = f2bu(h);
      else     Yf [((size_t)t*256 + b)*900 + z*450 + k] = h;
      HF[((size_t)(layer*2+z)*256 + b)*450 + k] = h;
    }
  }
}

// ---------------------------------------------------------------------------
// Kernel 5: attention over timesteps + context (unchanged).
// ---------------------------------------------------------------------------
__global__ __launch_bounds__(256) void k_attn(
    const float* __restrict__ Y1, const float* __restrict__ HF,
    float* __restrict__ CTX)
{
  __shared__ float red[256];
  __shared__ float sc[10];
  __shared__ float aw[10];
  int b = blockIdx.x, tid = threadIdx.x;
  for (int p = 0; p < 10; ++p){
    int t = p >> 1, l = p & 1;
    float a = 0.0f;
    for (int h = tid; h < 900; h += 256)
      a += Y1[((size_t)t*256 + b)*900 + h] * HF[(size_t)b*1800 + h*2 + l];
    red[tid] = a; __syncthreads();
    for (int off = 128; off > 0; off >>= 1){
      if (tid < off) red[tid] += red[tid+off];
      __syncthreads();
    }
    if (tid == 0) sc[p] = red[0];
    __syncthreads();
  }
  if (tid < 2){
    int l = tid;
    float mxv = -3.0e38f;
    for (int t = 0; t < 5; ++t) mxv = fmaxf(mxv, sc[t*2+l]);
    float e[5], sum = 0.0f;
    for (int t = 0; t < 5; ++t){ e[t] = expf(sc[t*2+l]-mxv); sum += e[t]; }
    for (int t = 0; t < 5; ++t) aw[t*2+l] = e[t]/sum;
  }
  __syncthreads();
  for (int h = tid; h < 900; h += 256){
    float v0 = 0.0f, v1 = 0.0f;
    for (int t = 0; t < 5; ++t){
      float y = Y1[((size_t)t*256 + b)*900 + h];
      v0 += y*aw[t*2+0]; v1 += y*aw[t*2+1];
    }
    CTX[(size_t)b*1800 + h*2 + 0] = v0;
    CTX[(size_t)b*1800 + h*2 + 1] = v1;
  }
}

// ---------------------------------------------------------------------------
// Kernel 2s: scalar GEMM (kept only for CTX @ out_w, C=100).
// ---------------------------------------------------------------------------
__global__ __launch_bounds__(256) void k_gemm(
    const float* __restrict__ A, const void* __restrict__ W, size_t wEl,
    const void* __restrict__ b1, const void* __restrict__ b2, size_t bEl,
    const int* __restrict__ flag,
    float* __restrict__ out, int K, int C)
{
  extern __shared__ float a_s[];
  const int bf = *flag;
  const int tid = threadIdx.x;
  const int r = blockIdx.y;
  const float* a = A + (size_t)r*K;
  for (int k = tid; k < K; k += 256) a_s[k] = a[k];
  __syncthreads();
  const int j = blockIdx.x*256 + tid;
  if (j >= C) return;
  float acc = 0.0f;
  if (b1) acc += ldf(b1, bEl + j, bf);
  if (b2) acc += ldf(b2, bEl + j, bf);
  if (bf){
    const u16* w = (const u16*)W + wEl + (size_t)j*K;
    for (int k = 0; k < K; k += 4){
      uint2 wv = *(const uint2*)(w + k);
      acc += a_s[k]   * u2f(wv.x & 0xffffu);
      acc += a_s[k+1] * u2f(wv.x >> 16);
      acc += a_s[k+2] * u2f(wv.y & 0xffffu);
      acc += a_s[k+3] * u2f(wv.y >> 16);
    }
  } else {
    const float* w = (const float*)W + wEl + (size_t)j*K;
    for (int k = 0; k < K; k += 4){
      float4 wv = *(const float4*)(w + k);
      acc += a_s[k]*wv.x + a_s[k+1]*wv.y + a_s[k+2]*wv.z + a_s[k+3]*wv.w;
    }
  }
  out[(size_t)r*C + j] = acc;
}

__device__ __forceinline__ float bred128(float v, float* red, int tid){
  red[tid] = v; __syncthreads();
  for (int off = 64; off > 0; off >>= 1){
    if (tid < off) red[tid] += red[tid+off];
    __syncthreads();
  }
  float r = red[0]; __syncthreads();
  return r;
}

// ---------------------------------------------------------------------------
// Kernel 6: analytic meta-gradient -> rel_q, norm_q. One block per b.
// ---------------------------------------------------------------------------
__global__ __launch_bounds__(128) void k_grad(
    const void* __restrict__ sup, const void* __restrict__ supn,
    const void* __restrict__ normv, const float* __restrict__ REL,
    const int* __restrict__ flag,
    float* __restrict__ RELQ, float* __restrict__ NORMQ)
{
  __shared__ float red[128];
  __shared__ float nv[100], rl[100], acc[100];
  const int bf = *flag;
  int b = blockIdx.x, tid = threadIdx.x;
  if (tid < 100){
    nv[tid] = ldf(normv, b*100+tid, bf);
    rl[tid] = REL[b*100+tid];
    acc[tid] = 0.0f;
  }
  __syncthreads();
  float nvd = (tid < 100) ? nv[tid] : 0.0f;
  float rld = (tid < 100) ? rl[tid] : 0.0f;
  for (int j = 0; j < 5; ++j){
    float h1=0.f,t1=0.f,h2=0.f,t2=0.f;
    if (tid < 100){
      size_t base = (size_t)(b*5+j)*200;
      h1 = ldf(sup,  base + tid, bf);  t1 = ldf(sup,  base + 100 + tid, bf);
      h2 = ldf(supn, base + tid, bf);  t2 = ldf(supn, base + 100 + tid, bf);
    }
    float hd1 = bred128(h1*nvd, red, tid);
    float td1 = bred128(t1*nvd, red, tid);
    float hd2 = bred128(h2*nvd, red, tid);
    float td2 = bred128(t2*nvd, red, tid);
    float upd = (h1 - hd1*nvd) + rld - (t1 - td1*nvd);
    float und = (h2 - hd2*nvd) + rld - (t2 - td2*nvd);
    if (tid >= 100){ upd = 0.0f; und = 0.0f; }
    float np2 = bred128(upd*upd, red, tid);
    float nn2 = bred128(und*und, red, tid);
    float p = -sqrtf(np2), nsc = -sqrtf(nn2);
    if ((1.0f - (p - nsc) > 0.0f) && tid < 100)
      acc[tid] += upd/sqrtf(np2) - und/sqrtf(nn2);
  }
  __syncthreads();
  if (tid < 100){
    float g = acc[tid] * (1.0f/1280.0f);
    RELQ[b*100+tid]  = rl[tid] - 5.0f*g;
    NORMQ[b*100+tid] = nv[tid] - 5.0f*g;
  }
}

// ---------------------------------------------------------------------------
// Kernel 7: final scores (unchanged, round-2 verified).
// ---------------------------------------------------------------------------
__global__ __launch_bounds__(256) void k_score(
    const void* __restrict__ query, const void* __restrict__ neg,
    const float* __restrict__ RELQ, const float* __restrict__ NORMQ,
    const int* __restrict__ flag, void* __restrict__ out)
{
  __shared__ __align__(16) float nq[104], rq[104];
  const int bf = *flag;
  const int b = blockIdx.x, tid = threadIdx.x;
  if (tid < 100){ nq[tid] = NORMQ[b*100+tid]; rq[tid] = RELQ[b*100+tid]; }
  __syncthreads();
  const int wid = tid >> 6, lane = tid & 63;
  const int d0 = lane*4;
  const int nidx = (lane < 25) ? d0 : (d0 - 100);
  float4 w4 = make_float4(0.0f,0.0f,0.0f,0.0f);
  float4 r4 = make_float4(0.0f,0.0f,0.0f,0.0f);
  if (lane < 50) w4 = *(const float4*)(nq + nidx);
  if (lane < 25) r4 = *(const float4*)(rq + d0);

  for (int qi = blockIdx.y*4 + wid; qi < 522; qi += 32){
    const void* src = (qi < 10) ? query : neg;
    size_t row = (qi < 10) ? ((size_t)b*10 + qi) : ((size_t)b*512 + qi - 10);
    size_t base = row*200;
    float4 v = make_float4(0.0f,0.0f,0.0f,0.0f);
    if (lane < 50){
      if (bf){
        uint2 u = *(const uint2*)((const u16*)src + base + d0);
        v.x = u2f(u.x & 0xffffu); v.y = u2f(u.x >> 16);
        v.z = u2f(u.y & 0xffffu); v.w = u2f(u.y >> 16);
      } else {
        v = *(const float4*)((const float*)src + base + d0);
      }
    }
    float p = v.x*w4.x + v.y*w4.y + v.z*w4.z + v.w*w4.w;
    float hd = wsum(lane < 25 ? p : 0.0f);
    float td = wsum((lane >= 25 && lane < 50) ? p : 0.0f);
    int sl = (lane < 25) ? (lane + 25) : lane;
    float4 t4;
    t4.x = __shfl(v.x, sl, 64);
    t4.y = __shfl(v.y, sl, 64);
    t4.z = __shfl(v.z, sl, 64);
    t4.w = __shfl(v.w, sl, 64);
    float s2p = 0.0f;
    if (lane < 25){
      float ux = (v.x - hd*w4.x) + r4.x - (t4.x - td*w4.x);
      float uy = (v.y - hd*w4.y) + r4.y - (t4.y - td*w4.y);
      float uz = (v.z - hd*w4.z) + r4.z - (t4.z - td*w4.z);
      float uw = (v.w - hd*w4.w) + r4.w - (t4.w - td*w4.w);
      s2p = ux*ux + uy*uy + uz*uz + uw*uw;
    }
    float s2 = wsum(s2p);
    if (lane == 0){
      float sc = -sqrtf(s2);
      size_t oi = (qi < 10) ? ((size_t)b*10 + qi) : (2560 + (size_t)b*512 + (qi - 10));
      if (bf) ((u16*)out)[oi] = f2bu(sc);
      else    ((float*)out)[oi] = sc;
    }
  }
}

// ---------------------------------------------------------------------------
extern "C" void kernel_launch(void* const* d_in, const int* in_sizes, int n_in,
                              void* d_out, int out_size, void* d_ws, size_t ws_size,
                              hipStream_t stream)
{
  const void* support = d_in[0];
  const void* supneg  = d_in[1];
  const void* query   = d_in[2];
  const void* negat   = d_in[3];
  const void* normv   = d_in[4];
  const int* left     = (const int*)d_in[5];
  const int* right    = (const int*)d_in[6];
  const void* emb     = d_in[7];
  const void* gcnw    = d_in[8];
  const void* gcnwb   = d_in[9];
  const void* gcnb    = d_in[10];
  const void* attnw   = d_in[11];
  const void* attnwb  = d_in[12];
  const void* gatew   = d_in[13];
  const void* gatewb  = d_in[14];
  const void* gateb   = d_in[15];
  const void* Wih0    = d_in[16];
  const void* Whh0    = d_in[17];
  const void* bih0    = d_in[18];
  const void* bhh0    = d_in[19];
  const void* Wih1    = d_in[20];
  const void* Whh1    = d_in[21];
  const void* bih1    = d_in[22];
  const void* bhh1    = d_in[23];
  const void* outw    = d_in[24];
  const void* outb    = d_in[25];

  int*   dflag = (int*)d_ws;
  float* fws   = (float*)d_ws + 16;
  // f32 region
  float* Y1   = fws;                 // 5*256*900  = 1,152,000
  float* HF   = Y1 + 1152000;        // 4*256*450  =   460,800
  float* HC   = HF + 460800;         //               460,800 (c in slots 2,3)
  float* CTX  = HC + 460800;         //               460,800
  float* RELb = CTX + 460800;        //    25,600
  float* RELQ = RELb + 25600;        //    25,600
  float* NORMQ= RELQ + 25600;        //    25,600
  float* Bp   = NORMQ + 25600;       //     3,840  (2x1920 permuted bias)
  float* fend = Bp + 3840;           // total f32 = 2,615,040 (16B aligned)
  // u16 region
  u16* Gb   = (u16*)fend;            // 2*1280*1920 = 4,915,200
  u16* X0bf = Gb + 4915200;          // 1280*224    =   286,720
  u16* Y0bf = X0bf + 286720;         // 1280*928    = 1,187,840
  u16* Hbf  = Y0bf + 1187840;        // 2 par * 2*256*480 = 491,520
  u16* Wp   = Hbf + 491520;          // 2*1920*928 max = 3,563,520
  u16* Whp  = Wp + 3563520;          // 2*1920*480  = 1,843,200
  u16* Wg   = Whp + 1843200;         // 112*224     =    25,088
  // total ~= 35.1 MB

  k_detect<<<1, 64, 0, stream>>>((const u32*)normv, dflag);

  // neighbor encoder -> X0bf
  hipMemsetAsync(X0bf, 0, 286720*sizeof(u16), stream);
  k_pack<<<(112*224+255)/256, 256, 0, stream>>>(gcnw, Wg, 200, 224, 100, 112, dflag);
  k_gcn<<<2560, 512, 0, stream>>>(left, right, emb, Wg, gcnwb, gcnb,
                                  attnw, attnwb, gatew, gatewb, gateb,
                                  dflag, X0bf);

  u16* Hpar0 = Hbf;
  u16* Hpar1 = Hbf + 245760;

  // ---- layer 0 ----
  hipMemsetAsync(Y0bf, 0, 1187840*sizeof(u16), stream);
  hipMemsetAsync(Hbf, 0, 491520*sizeof(u16), stream);
  hipMemsetAsync(HC, 0, 460800*sizeof(float), stream);
  k_packg<<<(2*1920*224+255)/256, 256, 0, stream>>>(Wih0, Wp, 200, 224, dflag);
  k_packg<<<(2*1920*480+255)/256, 256, 0, stream>>>(Whh0, Whp, 450, 480, dflag);
  k_packb<<<15, 256, 0, stream>>>(bih0, bhh0, Bp, dflag);
  k_mgemm<<<dim3(15,10,2), 256, 0, stream>>>(
      X0bf, 224, 0, Wp, 224, (size_t)1920*224,
      Bp, Gb, 2457600, 1920, 7);
  {
    u16* hc = Hpar0; u16* hn = Hpar1;
    for (int s = 0; s < 5; ++s){
      k_hstep<<<dim3(15,8,2), 256, 0, stream>>>(hc, Whp, Gb, HC, hn,
                                                Y0bf, nullptr, HF, s, 0);
      u16* tmp = hc; hc = hn; hn = tmp;
    }
  }

  // ---- layer 1 ----
  hipMemsetAsync(Hbf, 0, 491520*sizeof(u16), stream);
  hipMemsetAsync(HC, 0, 460800*sizeof(float), stream);
  k_packg<<<(2*1920*928+255)/256, 256, 0, stream>>>(Wih1, Wp, 900, 928, dflag);
  k_packg<<<(2*1920*480+255)/256, 256, 0, stream>>>(Whh1, Whp, 450, 480, dflag);
  k_packb<<<15, 256, 0, stream>>>(bih1, bhh1, Bp, dflag);
  k_mgemm<<<dim3(15,10,2), 256, 0, stream>>>(
      Y0bf, 928, 0, Wp, 928, (size_t)1920*928,
      Bp, Gb, 2457600, 1920, 29);
  {
    u16* hc = Hpar0; u16* hn = Hpar1;
    for (int s = 0; s < 5; ++s){
      k_hstep<<<dim3(15,8,2), 256, 0, stream>>>(hc, Whp, Gb, HC, hn,
                                                nullptr, Y1, HF, s, 1);
      u16* tmp = hc; hc = hn; hn = tmp;
    }
  }

  k_attn<<<256, 256, 0, stream>>>(Y1, HF, CTX);
  k_gemm<<<dim3(1,256), 256, 1800*4, stream>>>(CTX, outw, 0, outb, nullptr, 0,
                                               dflag, RELb, 1800, 100);
  k_grad<<<256, 128, 0, stream>>>(support, supneg, normv, RELb, dflag, RELQ, NORMQ);
  k_score<<<dim3(256,8), 256, 0, stream>>>(query, negat, RELQ, NORMQ, dflag, d_out);
}

// Round 6
// 761.588 us; speedup vs baseline: 1.4607x; 1.0254x over previous
//
#include <hip/hip_runtime.h>

typedef unsigned short u16;
typedef unsigned int   u32;
typedef __attribute__((ext_vector_type(8))) short short8;
typedef __attribute__((ext_vector_type(4))) float f32x4;

__device__ __forceinline__ float u2f(u32 u){
  union { u32 i; float f; } v; v.i = u << 16; return v.f;
}
__device__ __forceinline__ u16 f2bu(float f){
  union { float f; u32 i; } v; v.f = f;
  u32 i = v.i;
  i += 0x7fffu + ((i >> 16) & 1u);   // round-to-nearest-even
  return (u16)(i >> 16);
}
__device__ __forceinline__ float sigm(float x){ return 1.0f/(1.0f + expf(-x)); }
__device__ __forceinline__ float ldf(const void* p, size_t i, int bf){
  return bf ? u2f(((const u16*)p)[i]) : ((const float*)p)[i];
}
__device__ __forceinline__ float wsum(float v){
  #pragma unroll
  for (int off = 32; off > 0; off >>= 1) v += __shfl_xor(v, off, 64);
  return v;
}

// ---------------------------------------------------------------------------
// Kernel 0: dtype detector (bf16 vs f32 device buffers).
// ---------------------------------------------------------------------------
__global__ __launch_bounds__(64) void k_detect(const u32* __restrict__ nv,
                                               int* __restrict__ flag)
{
  int i = threadIdx.x;
  u32 w = nv[i];
  u32 e = (w >> 7) & 0xffu;
  bool sane = (e >= 100u && e <= 140u);
  unsigned long long m = __ballot(sane);
  if (i == 0) *flag = (__popcll(m) >= 40) ? 1 : 0;
}

// ---------------------------------------------------------------------------
// Kernel P: pack weights -> bf16, [Rp rows][Kp cols]; zero for k>=K or r>=R.
// (kept for gcn_w only)
// ---------------------------------------------------------------------------
__global__ __launch_bounds__(256) void k_pack(
    const void* __restrict__ src, u16* __restrict__ dst,
    int K, int Kp, int R, int Rp, const int* __restrict__ flag)
{
  const int bf = *flag;
  int total = Rp*Kp;
  int idx = blockIdx.x*256 + threadIdx.x;
  if (idx >= total) return;
  int r = idx / Kp, k = idx - r*Kp;
  u16 v = 0;
  if (k < K && r < R){
    size_t si = (size_t)r*K + k;
    v = bf ? ((const u16*)src)[si] : f2bu(((const float*)src)[si]);
  }
  dst[idx] = v;
}

// ---------------------------------------------------------------------------
// Kernel Pg: gate-interleaved LSTM weight pack, 4 elems/thread along K.
// src [2][1800=gate*450+k][K] -> dst [2][1920][Kp],
// row' = (k/16)*64 + gate*16 + (k%16). Zero pad. Kp % 4 == 0.
// ---------------------------------------------------------------------------
__global__ __launch_bounds__(256) void k_packg(
    const void* __restrict__ src, u16* __restrict__ dst,
    int K, int Kp, const int* __restrict__ flag)
{
  const int bf = *flag;
  const int Kq = Kp >> 2;
  const int per = 1920*Kq;
  int idx = blockIdx.x*256 + threadIdx.x;
  if (idx >= 2*per) return;
  int z = idx / per, r = idx - z*per;
  int rp = r / Kq, cq = r - rp*Kq;
  int c0 = cq*4;
  int kblk = rp >> 6, rem = rp & 63, gate = rem >> 4, klo = rem & 15;
  int k = kblk*16 + klo;
  union { u16 q[4]; uint2 d; } o;
  o.q[0] = 0; o.q[1] = 0; o.q[2] = 0; o.q[3] = 0;
  if (k < 450){
    size_t base = ((size_t)z*1800 + (size_t)gate*450 + k)*K;
    #pragma unroll
    for (int e = 0; e < 4; ++e){
      int c = c0 + e;
      if (c < K)
        o.q[e] = bf ? ((const u16*)src)[base+c] : f2bu(((const float*)src)[base+c]);
    }
  }
  *(uint2*)(dst + (size_t)idx*4) = o.d;
}

// ---------------------------------------------------------------------------
// Kernel Pb: permuted bias pack: Bp[z][1920] f32 = bih+bhh at (gate,k).
// ---------------------------------------------------------------------------
__global__ __launch_bounds__(256) void k_packb(
    const void* __restrict__ bih, const void* __restrict__ bhh,
    float* __restrict__ Bp, const int* __restrict__ flag)
{
  const int bf = *flag;
  int idx = blockIdx.x*256 + threadIdx.x;
  if (idx >= 2*1920) return;
  int z = idx / 1920, rp = idx - z*1920;
  int kblk = rp >> 6, rem = rp & 63, gate = rem >> 4, klo = rem & 15;
  int k = kblk*16 + klo;
  float v = 0.0f;
  if (k < 450){
    size_t si = (size_t)z*1800 + (size_t)gate*450 + k;
    v = ldf(bih, si, bf) + ldf(bhh, si, bf);
  }
  Bp[idx] = v;
}

// ---------------------------------------------------------------------------
// Kernel 1: neighbor encoder. Round-4 structure + T14 register prefetch:
// each thread owns 4 gather slots (pv, 8 VGPR); kc+1's gathers are issued
// right after the staging barrier so they fly under the MFMA phase.
// ---------------------------------------------------------------------------
__global__ __launch_bounds__(512, 4) void k_gcn(
    const int* __restrict__ left, const int* __restrict__ right,
    const void* __restrict__ emb, const u16* __restrict__ Wg,
    const void* __restrict__ gcnwb, const void* __restrict__ gcnb,
    const void* __restrict__ attnw, const void* __restrict__ attnwb,
    const void* __restrict__ gatew, const void* __restrict__ gatewb,
    const void* __restrict__ gateb,
    const int* __restrict__ flag,
    u16* __restrict__ X0bf)
{
  __shared__ __align__(16) u16 As[208*40];    // 16640 B
  __shared__ __align__(16) u16 Bs[112*232];   // 51968 B
  __shared__ int c1_s[200], c2_s[200];
  __shared__ float logit_s[208];
  __shared__ float red_s[512];
  __shared__ float attnw_s[112], bias_s[112], gatew_s[112], oa_s[112];

  const int bf  = *flag;
  const int tid = threadIdx.x;
  const int n   = blockIdx.x;
  const int b   = n & 255;
  const int fs  = n >> 8;
  const int s   = fs & 1;
  const int f   = fs >> 1;
  const int* conn = (s == 0 ? left : right) + (size_t)(f*256 + b)*600;

  const u16*   e16 = (const u16*)emb;
  const float* e32 = (const float*)emb;

  if (tid < 200){ c1_s[tid] = conn[tid*3+1]; c2_s[tid] = conn[tid*3+2]; }
  if (tid < 112){
    attnw_s[tid] = (tid < 100) ? ldf(attnw, tid, bf) : 0.0f;
    bias_s[tid]  = (tid < 100) ? (ldf(gcnwb, tid, bf) + ldf(gcnb, tid, bf)) : 0.0f;
    gatew_s[tid] = (tid < 100) ? ldf(gatew, tid, bf) : 0.0f;
    oa_s[tid] = 0.0f;
  }
  for (int g = tid; g < 112*28; g += 512){
    int r = g / 28, cc = g - r*28;
    *(short8*)(Bs + r*232 + cc*8) = *(const short8*)(Wg + (size_t)r*224 + cc*8);
  }
  __syncthreads();

  const int wid  = tid >> 6, lane = tid & 63, ln = lane & 15, quad = lane >> 4;
  const int mt0 = (wid < 5) ? 2*wid : (10 + (wid - 5));
  const int nmt = (wid < 5) ? 2 : 1;

  // gather kc's A-slots into registers (4 slots/thread, 208*8=1664 total)
  auto loadA = [&](int kc, uint2* pv){
    #pragma unroll
    for (int it = 0; it < 4; ++it){
      int g = tid + it*512;
      uint2 v; v.x = 0u; v.y = 0u;
      if (g < 1664){
        int r = g >> 3, gi = g & 7, k = kc*32 + gi*4;
        if (r < 200 && k < 200){
          int c  = (k < 100) ? c1_s[r] : c2_s[r];
          int kk = (k < 100) ? k : (k - 100);
          size_t idx = (size_t)c*100 + kk;
          if (bf) v = *(const uint2*)(e16 + idx);
          else {
            float4 t = *(const float4*)(e32 + idx);
            v.x = (u32)f2bu(t.x) | ((u32)f2bu(t.y) << 16);
            v.y = (u32)f2bu(t.z) | ((u32)f2bu(t.w) << 16);
          }
        }
      }
      pv[it] = v;
    }
  };

  f32x4 acc[2][7];
  #pragma unroll
  for (int i = 0; i < 2; ++i)
    #pragma unroll
    for (int j = 0; j < 7; ++j) acc[i][j] = (f32x4)0.0f;

  uint2 pv[4];
  loadA(0, pv);

  for (int kc = 0; kc < 7; ++kc){
    const int k0 = kc*32;
    #pragma unroll
    for (int it = 0; it < 4; ++it){
      int g = tid + it*512;
      if (g < 1664){
        int r = g >> 3, gi = g & 7;
        *(uint2*)(As + r*40 + gi*4) = pv[it];
      }
    }
    __syncthreads();
    if (kc < 6) loadA(kc+1, pv);   // in flight under MFMA phase

    #pragma unroll
    for (int mi = 0; mi < 2; ++mi){
      if (mi < nmt){
        short8 afr = *(const short8*)(As + ((mt0+mi)*16 + ln)*40 + quad*8);
        #pragma unroll
        for (int nt = 0; nt < 7; ++nt){
          short8 bfr = *(const short8*)(Bs + (size_t)(nt*16 + ln)*232 + k0 + quad*8);
          acc[mi][nt] = __builtin_amdgcn_mfma_f32_16x16x32_bf16(afr, bfr, acc[mi][nt], 0, 0, 0);
        }
      }
    }
    __syncthreads();
  }

  const float awb = ldf(attnwb, 0, bf);
  #pragma unroll
  for (int mi = 0; mi < 2; ++mi){
    if (mi < nmt){
      #pragma unroll
      for (int rg = 0; rg < 4; ++rg){
        float p = 0.0f;
        #pragma unroll
        for (int nt = 0; nt < 7; ++nt){
          float x = acc[mi][nt][rg] + bias_s[nt*16 + ln];
          x = x > 0.0f ? x : 0.01f*x;
          p += x * attnw_s[nt*16 + ln];
        }
        p += __shfl_xor(p, 1, 64); p += __shfl_xor(p, 2, 64);
        p += __shfl_xor(p, 4, 64); p += __shfl_xor(p, 8, 64);
        int m = (mt0+mi)*16 + quad*4 + rg;
        if (ln == 0 && m < 200) logit_s[m] = p + awb;
      }
    }
  }
  __syncthreads();

  red_s[tid] = (tid < 200) ? logit_s[tid] : -3.0e38f;
  __syncthreads();
  for (int off = 256; off > 0; off >>= 1){
    if (tid < off) red_s[tid] = fmaxf(red_s[tid], red_s[tid+off]);
    __syncthreads();
  }
  float mx = red_s[0];
  __syncthreads();
  float ev = 0.0f;
  if (tid < 200) ev = expf(logit_s[tid] - mx);
  red_s[tid] = ev;
  __syncthreads();
  for (int off = 256; off > 0; off >>= 1){
    if (tid < off) red_s[tid] += red_s[tid+off];
    __syncthreads();
  }
  float S = red_s[0];
  __syncthreads();
  if (tid < 208) logit_s[tid] = (tid < 200) ? ev*(1.0f/S) : 0.0f;
  __syncthreads();

  float at[2][4];
  #pragma unroll
  for (int mi = 0; mi < 2; ++mi)
    #pragma unroll
    for (int rg = 0; rg < 4; ++rg)
      at[mi][rg] = (mi < nmt) ? logit_s[(mt0+mi)*16 + quad*4 + rg] : 0.0f;

  #pragma unroll
  for (int nt = 0; nt < 7; ++nt){
    float p = 0.0f;
    #pragma unroll
    for (int mi = 0; mi < 2; ++mi){
      if (mi < nmt){
        #pragma unroll
        for (int rg = 0; rg < 4; ++rg){
          float x = acc[mi][nt][rg] + bias_s[nt*16 + ln];
          x = x > 0.0f ? x : 0.01f*x;
          p += x * at[mi][rg];
        }
      }
    }
    p += __shfl_xor(p, 16, 64); p += __shfl_xor(p, 32, 64);
    if (quad == 0) atomicAdd(&oa_s[nt*16 + ln], p);
  }
  __syncthreads();

  red_s[tid] = (tid < 100) ? oa_s[tid]*gatew_s[tid] : 0.0f;
  __syncthreads();
  for (int off = 256; off > 0; off >>= 1){
    if (tid < off) red_s[tid] += red_s[tid+off];
    __syncthreads();
  }
  float gate = sigm(red_s[0] + ldf(gatewb, 0, bf) + ldf(gateb, 0, bf));
  if (tid < 100){
    int c0 = conn[0];
    float self = ldf(emb, (size_t)c0*100 + tid, bf);
    X0bf[((size_t)f*256 + b)*224 + s*100 + tid] = f2bu(oa_s[tid]*gate + self*(1.0f - gate));
  }
}

// ---------------------------------------------------------------------------
// Kernel M: MFMA GEMM (input projections only). out[z][row][col'] bf16 =
// A[row]·B'[col'] + Bp[z][col']. N=1920 exact (15x128 tiles), M mult of 128.
// ---------------------------------------------------------------------------
__global__ __launch_bounds__(256) void k_mgemm(
    const u16* __restrict__ A, int lda, size_t Astride,
    const u16* __restrict__ B, int ldb, size_t Bstride,
    const float* __restrict__ bsum,
    u16* __restrict__ out, size_t Ostride,
    int N, int KC)
{
  __shared__ __align__(16) u16 As[128*40];
  __shared__ __align__(16) u16 Bs[128*40];
  const int tid = threadIdx.x;
  const int z  = blockIdx.z;
  const int nb = blockIdx.x, mb = blockIdx.y;
  const u16* Az = A + (size_t)z*Astride;
  const u16* Bz = B + (size_t)z*Bstride;

  const int wid = tid >> 6, lane = tid & 63, ln = lane & 15, quad = lane >> 4;
  const int wm = wid >> 1, wn = wid & 1;

  f32x4 acc[4][4];
  #pragma unroll
  for (int i = 0; i < 4; ++i)
    #pragma unroll
    for (int j = 0; j < 4; ++j) acc[i][j] = (f32x4)0.0f;

  const int srow = tid >> 1;
  const int koff = (tid & 1)*16;
  const int rowA = mb*128 + srow;
  const int rowB = nb*128 + srow;

  for (int kc = 0; kc < KC; ++kc){
    const int k0 = kc*32 + koff;
    const u16* ap = Az + (size_t)rowA*lda + k0;
    const u16* bp = Bz + (size_t)rowB*ldb + k0;
    short8 av0 = *(const short8*)(ap);
    short8 av1 = *(const short8*)(ap + 8);
    short8 bv0 = *(const short8*)(bp);
    short8 bv1 = *(const short8*)(bp + 8);
    *(short8*)(As + srow*40 + koff)     = av0;
    *(short8*)(As + srow*40 + koff + 8) = av1;
    *(short8*)(Bs + srow*40 + koff)     = bv0;
    *(short8*)(Bs + srow*40 + koff + 8) = bv1;
    __syncthreads();
    short8 af[4], bfr[4];
    #pragma unroll
    for (int i = 0; i < 4; ++i)
      af[i] = *(const short8*)(As + (wm*64 + i*16 + ln)*40 + quad*8);
    #pragma unroll
    for (int j = 0; j < 4; ++j)
      bfr[j] = *(const short8*)(Bs + (wn*64 + j*16 + ln)*40 + quad*8);
    #pragma unroll
    for (int i = 0; i < 4; ++i)
      #pragma unroll
      for (int j = 0; j < 4; ++j)
        acc[i][j] = __builtin_amdgcn_mfma_f32_16x16x32_bf16(af[i], bfr[j], acc[i][j], 0, 0, 0);
    __syncthreads();
  }

  #pragma unroll
  for (int j = 0; j < 4; ++j){
    int col = nb*128 + wn*64 + j*16 + ln;
    float bias = bsum ? bsum[(size_t)z*1920 + col] : 0.0f;
    #pragma unroll
    for (int i = 0; i < 4; ++i){
      #pragma unroll
      for (int rg = 0; rg < 4; ++rg){
        int row = mb*128 + wm*64 + i*16 + quad*4 + rg;
        out[(size_t)z*Ostride + (size_t)row*N + col] = f2bu(acc[i][j][rg] + bias);
      }
    }
  }
}

// ---------------------------------------------------------------------------
// Kernel H: fused hidden GEMM + LSTM cell (round-5 verified, unchanged).
// ---------------------------------------------------------------------------
__global__ __launch_bounds__(256) void k_hstep(
    const u16* __restrict__ Hin, const u16* __restrict__ Whp,
    const u16* __restrict__ Gb, float* __restrict__ HC,
    u16* __restrict__ Hout, u16* __restrict__ Ybf, float* __restrict__ Yf,
    float* __restrict__ HF, int s, int layer)
{
  __shared__ __align__(16) u16 As[32*40];
  __shared__ __align__(16) u16 Bs[128*40];
  const int tid = threadIdx.x;
  const int nb = blockIdx.x, mb = blockIdx.y, z = blockIdx.z;
  const int wid = tid >> 6, lane = tid & 63, ln = lane & 15, quad = lane >> 4;
  const int wm = wid >> 1, wn = wid & 1;

  const u16* Az = Hin + ((size_t)z*256 + mb*32)*480;
  const u16* Bz = Whp + (size_t)z*1920*480 + (size_t)nb*128*480;

  f32x4 acc[4];
  #pragma unroll
  for (int j = 0; j < 4; ++j) acc[j] = (f32x4)0.0f;

  const int ar = tid >> 2, ap = tid & 3;   // A: first 128 threads
  const int br = tid >> 1, bp = tid & 1;   // B: all 256 threads
  for (int kc = 0; kc < 15; ++kc){
    const int k0 = kc*32;
    if (tid < 128)
      *(short8*)(As + ar*40 + ap*8) = *(const short8*)(Az + (size_t)ar*480 + k0 + ap*8);
    *(short8*)(Bs + br*40 + bp*16)     = *(const short8*)(Bz + (size_t)br*480 + k0 + bp*16);
    *(short8*)(Bs + br*40 + bp*16 + 8) = *(const short8*)(Bz + (size_t)br*480 + k0 + bp*16 + 8);
    __syncthreads();
    short8 afr = *(const short8*)(As + (wm*16 + ln)*40 + quad*8);
    #pragma unroll
    for (int j = 0; j < 4; ++j){
      short8 bfr = *(const short8*)(Bs + (wn*64 + j*16 + ln)*40 + quad*8);
      acc[j] = __builtin_amdgcn_mfma_f32_16x16x32_bf16(afr, bfr, acc[j], 0, 0, 0);
    }
    __syncthreads();
  }

  const int kblk = nb*2 + wn;
  const int k = kblk*16 + ln;
  const int t = z ? (4 - s) : s;
  if (k < 450){
    const u16* Gz = Gb + (size_t)z*2457600 + (size_t)t*256*1920;
    #pragma unroll
    for (int rg = 0; rg < 4; ++rg){
      int b = mb*32 + wm*16 + quad*4 + rg;
      const u16* grow = Gz + (size_t)b*1920 + nb*128 + wn*64 + ln;
      float gi = acc[0][rg] + u2f(grow[0]);
      float gf = acc[1][rg] + u2f(grow[16]);
      float gg = acc[2][rg] + u2f(grow[32]);
      float go = acc[3][rg] + u2f(grow[48]);
      float* cp = HC + ((size_t)(2+z)*256 + b)*450 + k;
      float c = sigm(gf)*(*cp) + sigm(gi)*tanhf(gg);
      float h = sigm(go)*tanhf(c);
      *cp = c;
      Hout[((size_t)z*256 + b)*480 + k] = f2bu(h);
      if (Ybf) Ybf[((size_t)t*256 + b)*928 + z*450 + k] = f2bu(h);
      else     Yf [((size_t)t*256 + b)*900 + z*450 + k] = h;
      HF[((size_t)(layer*2+z)*256 + b)*450 + k] = h;
    }
  }
}

// ---------------------------------------------------------------------------
// Kernel 5: attention over timesteps + context (unchanged).
// ---------------------------------------------------------------------------
__global__ __launch_bounds__(256) void k_attn(
    const float* __restrict__ Y1, const float* __restrict__ HF,
    float* __restrict__ CTX)
{
  __shared__ float red[256];
  __shared__ float sc[10];
  __shared__ float aw[10];
  int b = blockIdx.x, tid = threadIdx.x;
  for (int p = 0; p < 10; ++p){
    int t = p >> 1, l = p & 1;
    float a = 0.0f;
    for (int h = tid; h < 900; h += 256)
      a += Y1[((size_t)t*256 + b)*900 + h] * HF[(size_t)b*1800 + h*2 + l];
    red[tid] = a; __syncthreads();
    for (int off = 128; off > 0; off >>= 1){
      if (tid < off) red[tid] += red[tid+off];
      __syncthreads();
    }
    if (tid == 0) sc[p] = red[0];
    __syncthreads();
  }
  if (tid < 2){
    int l = tid;
    float mxv = -3.0e38f;
    for (int t = 0; t < 5; ++t) mxv = fmaxf(mxv, sc[t*2+l]);
    float e[5], sum = 0.0f;
    for (int t = 0; t < 5; ++t){ e[t] = expf(sc[t*2+l]-mxv); sum += e[t]; }
    for (int t = 0; t < 5; ++t) aw[t*2+l] = e[t]/sum;
  }
  __syncthreads();
  for (int h = tid; h < 900; h += 256){
    float v0 = 0.0f, v1 = 0.0f;
    for (int t = 0; t < 5; ++t){
      float y = Y1[((size_t)t*256 + b)*900 + h];
      v0 += y*aw[t*2+0]; v1 += y*aw[t*2+1];
    }
    CTX[(size_t)b*1800 + h*2 + 0] = v0;
    CTX[(size_t)b*1800 + h*2 + 1] = v1;
  }
}

// ---------------------------------------------------------------------------
// Kernel 2s: scalar GEMM (kept only for CTX @ out_w, C=100).
// ---------------------------------------------------------------------------
__global__ __launch_bounds__(256) void k_gemm(
    const float* __restrict__ A, const void* __restrict__ W, size_t wEl,
    const void* __restrict__ b1, const void* __restrict__ b2, size_t bEl,
    const int* __restrict__ flag,
    float* __restrict__ out, int K, int C)
{
  extern __shared__ float a_s[];
  const int bf = *flag;
  const int tid = threadIdx.x;
  const int r = blockIdx.y;
  const float* a = A + (size_t)r*K;
  for (int k = tid; k < K; k += 256) a_s[k] = a[k];
  __syncthreads();
  const int j = blockIdx.x*256 + tid;
  if (j >= C) return;
  float acc = 0.0f;
  if (b1) acc += ldf(b1, bEl + j, bf);
  if (b2) acc += ldf(b2, bEl + j, bf);
  if (bf){
    const u16* w = (const u16*)W + wEl + (size_t)j*K;
    for (int k = 0; k < K; k += 4){
      uint2 wv = *(const uint2*)(w + k);
      acc += a_s[k]   * u2f(wv.x & 0xffffu);
      acc += a_s[k+1] * u2f(wv.x >> 16);
      acc += a_s[k+2] * u2f(wv.y & 0xffffu);
      acc += a_s[k+3] * u2f(wv.y >> 16);
    }
  } else {
    const float* w = (const float*)W + wEl + (size_t)j*K;
    for (int k = 0; k < K; k += 4){
      float4 wv = *(const float4*)(w + k);
      acc += a_s[k]*wv.x + a_s[k+1]*wv.y + a_s[k+2]*wv.z + a_s[k+3]*wv.w;
    }
  }
  out[(size_t)r*C + j] = acc;
}

__device__ __forceinline__ float bred128(float v, float* red, int tid){
  red[tid] = v; __syncthreads();
  for (int off = 64; off > 0; off >>= 1){
    if (tid < off) red[tid] += red[tid+off];
    __syncthreads();
  }
  float r = red[0]; __syncthreads();
  return r;
}

// ---------------------------------------------------------------------------
// Kernel 6: analytic meta-gradient -> rel_q, norm_q. One block per b.
// ---------------------------------------------------------------------------
__global__ __launch_bounds__(128) void k_grad(
    const void* __restrict__ sup, const void* __restrict__ supn,
    const void* __restrict__ normv, const float* __restrict__ REL,
    const int* __restrict__ flag,
    float* __restrict__ RELQ, float* __restrict__ NORMQ)
{
  __shared__ float red[128];
  __shared__ float nv[100], rl[100], acc[100];
  const int bf = *flag;
  int b = blockIdx.x, tid = threadIdx.x;
  if (tid < 100){
    nv[tid] = ldf(normv, b*100+tid, bf);
    rl[tid] = REL[b*100+tid];
    acc[tid] = 0.0f;
  }
  __syncthreads();
  float nvd = (tid < 100) ? nv[tid] : 0.0f;
  float rld = (tid < 100) ? rl[tid] : 0.0f;
  for (int j = 0; j < 5; ++j){
    float h1=0.f,t1=0.f,h2=0.f,t2=0.f;
    if (tid < 100){
      size_t base = (size_t)(b*5+j)*200;
      h1 = ldf(sup,  base + tid, bf);  t1 = ldf(sup,  base + 100 + tid, bf);
      h2 = ldf(supn, base + tid, bf);  t2 = ldf(supn, base + 100 + tid, bf);
    }
    float hd1 = bred128(h1*nvd, red, tid);
    float td1 = bred128(t1*nvd, red, tid);
    float hd2 = bred128(h2*nvd, red, tid);
    float td2 = bred128(t2*nvd, red, tid);
    float upd = (h1 - hd1*nvd) + rld - (t1 - td1*nvd);
    float und = (h2 - hd2*nvd) + rld - (t2 - td2*nvd);
    if (tid >= 100){ upd = 0.0f; und = 0.0f; }
    float np2 = bred128(upd*upd, red, tid);
    float nn2 = bred128(und*und, red, tid);
    float p = -sqrtf(np2), nsc = -sqrtf(nn2);
    if ((1.0f - (p - nsc) > 0.0f) && tid < 100)
      acc[tid] += upd/sqrtf(np2) - und/sqrtf(nn2);
  }
  __syncthreads();
  if (tid < 100){
    float g = acc[tid] * (1.0f/1280.0f);
    RELQ[b*100+tid]  = rl[tid] - 5.0f*g;
    NORMQ[b*100+tid] = nv[tid] - 5.0f*g;
  }
}

// ---------------------------------------------------------------------------
// Kernel 7: final scores (unchanged, round-2 verified).
// ---------------------------------------------------------------------------
__global__ __launch_bounds__(256) void k_score(
    const void* __restrict__ query, const void* __restrict__ neg,
    const float* __restrict__ RELQ, const float* __restrict__ NORMQ,
    const int* __restrict__ flag, void* __restrict__ out)
{
  __shared__ __align__(16) float nq[104], rq[104];
  const int bf = *flag;
  const int b = blockIdx.x, tid = threadIdx.x;
  if (tid < 100){ nq[tid] = NORMQ[b*100+tid]; rq[tid] = RELQ[b*100+tid]; }
  __syncthreads();
  const int wid = tid >> 6, lane = tid & 63;
  const int d0 = lane*4;
  const int nidx = (lane < 25) ? d0 : (d0 - 100);
  float4 w4 = make_float4(0.0f,0.0f,0.0f,0.0f);
  float4 r4 = make_float4(0.0f,0.0f,0.0f,0.0f);
  if (lane < 50) w4 = *(const float4*)(nq + nidx);
  if (lane < 25) r4 = *(const float4*)(rq + d0);

  for (int qi = blockIdx.y*4 + wid; qi < 522; qi += 32){
    const void* src = (qi < 10) ? query : neg;
    size_t row = (qi < 10) ? ((size_t)b*10 + qi) : ((size_t)b*512 + qi - 10);
    size_t base = row*200;
    float4 v = make_float4(0.0f,0.0f,0.0f,0.0f);
    if (lane < 50){
      if (bf){
        uint2 u = *(const uint2*)((const u16*)src + base + d0);
        v.x = u2f(u.x & 0xffffu); v.y = u2f(u.x >> 16);
        v.z = u2f(u.y & 0xffffu); v.w = u2f(u.y >> 16);
      } else {
        v = *(const float4*)((const float*)src + base + d0);
      }
    }
    float p = v.x*w4.x + v.y*w4.y + v.z*w4.z + v.w*w4.w;
    float hd = wsum(lane < 25 ? p : 0.0f);
    float td = wsum((lane >= 25 && lane < 50) ? p : 0.0f);
    int sl = (lane < 25) ? (lane + 25) : lane;
    float4 t4;
    t4.x = __shfl(v.x, sl, 64);
    t4.y = __shfl(v.y, sl, 64);
    t4.z = __shfl(v.z, sl, 64);
    t4.w = __shfl(v.w, sl, 64);
    float s2p = 0.0f;
    if (lane < 25){
      float ux = (v.x - hd*w4.x) + r4.x - (t4.x - td*w4.x);
      float uy = (v.y - hd*w4.y) + r4.y - (t4.y - td*w4.y);
      float uz = (v.z - hd*w4.z) + r4.z - (t4.z - td*w4.z);
      float uw = (v.w - hd*w4.w) + r4.w - (t4.w - td*w4.w);
      s2p = ux*ux + uy*uy + uz*uz + uw*uw;
    }
    float s2 = wsum(s2p);
    if (lane == 0){
      float sc = -sqrtf(s2);
      size_t oi = (qi < 10) ? ((size_t)b*10 + qi) : (2560 + (size_t)b*512 + (qi - 10));
      if (bf) ((u16*)out)[oi] = f2bu(sc);
      else    ((float*)out)[oi] = sc;
    }
  }
}

// ---------------------------------------------------------------------------
extern "C" void kernel_launch(void* const* d_in, const int* in_sizes, int n_in,
                              void* d_out, int out_size, void* d_ws, size_t ws_size,
                              hipStream_t stream)
{
  const void* support = d_in[0];
  const void* supneg  = d_in[1];
  const void* query   = d_in[2];
  const void* negat   = d_in[3];
  const void* normv   = d_in[4];
  const int* left     = (const int*)d_in[5];
  const int* right    = (const int*)d_in[6];
  const void* emb     = d_in[7];
  const void* gcnw    = d_in[8];
  const void* gcnwb   = d_in[9];
  const void* gcnb    = d_in[10];
  const void* attnw   = d_in[11];
  const void* attnwb  = d_in[12];
  const void* gatew   = d_in[13];
  const void* gatewb  = d_in[14];
  const void* gateb   = d_in[15];
  const void* Wih0    = d_in[16];
  const void* Whh0    = d_in[17];
  const void* bih0    = d_in[18];
  const void* bhh0    = d_in[19];
  const void* Wih1    = d_in[20];
  const void* Whh1    = d_in[21];
  const void* bih1    = d_in[22];
  const void* bhh1    = d_in[23];
  const void* outw    = d_in[24];
  const void* outb    = d_in[25];

  int*   dflag = (int*)d_ws;
  float* fws   = (float*)d_ws + 16;
  // f32 region
  float* Y1   = fws;                 // 5*256*900  = 1,152,000
  float* HF   = Y1 + 1152000;        // 4*256*450  =   460,800
  float* HC   = HF + 460800;         //               460,800 (c in slots 2,3)
  float* CTX  = HC + 460800;         //               460,800
  float* RELb = CTX + 460800;        //    25,600
  float* RELQ = RELb + 25600;        //    25,600
  float* NORMQ= RELQ + 25600;        //    25,600
  float* Bp   = NORMQ + 25600;       //     3,840  (2x1920 permuted bias)
  float* fend = Bp + 3840;           // total f32 = 2,615,040 (16B aligned)
  // u16 region
  u16* Gb   = (u16*)fend;            // 2*1280*1920 = 4,915,200
  u16* X0bf = Gb + 4915200;          // 1280*224    =   286,720
  u16* Y0bf = X0bf + 286720;         // 1280*928    = 1,187,840
  u16* Hbf  = Y0bf + 1187840;        // 2 par * 2*256*480 = 491,520
  u16* Wp   = Hbf + 491520;          // 2*1920*928 max = 3,563,520
  u16* Whp  = Wp + 3563520;          // 2*1920*480  = 1,843,200
  u16* Wg   = Whp + 1843200;         // 112*224     =    25,088
  // total ~= 35.1 MB

  k_detect<<<1, 64, 0, stream>>>((const u32*)normv, dflag);

  // neighbor encoder -> X0bf
  hipMemsetAsync(X0bf, 0, 286720*sizeof(u16), stream);
  k_pack<<<(112*224+255)/256, 256, 0, stream>>>(gcnw, Wg, 200, 224, 100, 112, dflag);
  k_gcn<<<2560, 512, 0, stream>>>(left, right, emb, Wg, gcnwb, gcnb,
                                  attnw, attnwb, gatew, gatewb, gateb,
                                  dflag, X0bf);

  u16* Hpar0 = Hbf;
  u16* Hpar1 = Hbf + 245760;

  // ---- layer 0 ----
  hipMemsetAsync(Y0bf, 0, 1187840*sizeof(u16), stream);
  hipMemsetAsync(Hbf, 0, 491520*sizeof(u16), stream);
  hipMemsetAsync(HC, 0, 460800*sizeof(float), stream);
  k_packg<<<(2*1920*224/4+255)/256, 256, 0, stream>>>(Wih0, Wp, 200, 224, dflag);
  k_packg<<<(2*1920*480/4+255)/256, 256, 0, stream>>>(Whh0, Whp, 450, 480, dflag);
  k_packb<<<15, 256, 0, stream>>>(bih0, bhh0, Bp, dflag);
  k_mgemm<<<dim3(15,10,2), 256, 0, stream>>>(
      X0bf, 224, 0, Wp, 224, (size_t)1920*224,
      Bp, Gb, 2457600, 1920, 7);
  {
    u16* hc = Hpar0; u16* hn = Hpar1;
    for (int s = 0; s < 5; ++s){
      k_hstep<<<dim3(15,8,2), 256, 0, stream>>>(hc, Whp, Gb, HC, hn,
                                                Y0bf, nullptr, HF, s, 0);
      u16* tmp = hc; hc = hn; hn = tmp;
    }
  }

  // ---- layer 1 ----
  hipMemsetAsync(Hbf, 0, 491520*sizeof(u16), stream);
  hipMemsetAsync(HC, 0, 460800*sizeof(float), stream);
  k_packg<<<(2*1920*928/4+255)/256, 256, 0, stream>>>(Wih1, Wp, 900, 928, dflag);
  k_packg<<<(2*1920*480/4+255)/256, 256, 0, stream>>>(Whh1, Whp, 450, 480, dflag);
  k_packb<<<15, 256, 0, stream>>>(bih1, bhh1, Bp, dflag);
  k_mgemm<<<dim3(15,10,2), 256, 0, stream>>>(
      Y0bf, 928, 0, Wp, 928, (size_t)1920*928,
      Bp, Gb, 2457600, 1920, 29);
  {
    u16* hc = Hpar0; u16* hn = Hpar1;
    for (int s = 0; s < 5; ++s){
      k_hstep<<<dim3(15,8,2), 256, 0, stream>>>(hc, Whp, Gb, HC, hn,
                                                nullptr, Y1, HF, s, 1);
      u16* tmp = hc; hc = hn; hn = tmp;
    }
  }

  k_attn<<<256, 256, 0, stream>>>(Y1, HF, CTX);
  k_gemm<<<dim3(1,256), 256, 1800*4, stream>>>(CTX, outw, 0, outb, nullptr, 0,
                                               dflag, RELb, 1800, 100);
  k_grad<<<256, 128, 0, stream>>>(support, supneg, normv, RELb, dflag, RELQ, NORMQ);
  k_score<<<dim3(256,8), 256, 0, stream>>>(query, negat, RELQ, NORMQ, dflag, d_out);
}

// Round 7
// 737.305 us; speedup vs baseline: 1.5088x; 1.0329x over previous
//
#include <hip/hip_runtime.h>

typedef unsigned short u16;
typedef unsigned int   u32;
typedef __attribute__((ext_vector_type(8))) short short8;
typedef __attribute__((ext_vector_type(4))) float f32x4;

__device__ __forceinline__ float u2f(u32 u){
  union { u32 i; float f; } v; v.i = u << 16; return v.f;
}
__device__ __forceinline__ u16 f2bu(float f){
  union { float f; u32 i; } v; v.f = f;
  u32 i = v.i;
  i += 0x7fffu + ((i >> 16) & 1u);   // round-to-nearest-even
  return (u16)(i >> 16);
}
__device__ __forceinline__ float sigm(float x){ return 1.0f/(1.0f + expf(-x)); }
__device__ __forceinline__ float ldf(const void* p, size_t i, int bf){
  return bf ? u2f(((const u16*)p)[i]) : ((const float*)p)[i];
}
__device__ __forceinline__ float wsum(float v){
  #pragma unroll
  for (int off = 32; off > 0; off >>= 1) v += __shfl_xor(v, off, 64);
  return v;
}

// ---------------------------------------------------------------------------
// Kernel 0: dtype detector (bf16 vs f32 device buffers).
// ---------------------------------------------------------------------------
__global__ __launch_bounds__(64) void k_detect(const u32* __restrict__ nv,
                                               int* __restrict__ flag)
{
  int i = threadIdx.x;
  u32 w = nv[i];
  u32 e = (w >> 7) & 0xffu;
  bool sane = (e >= 100u && e <= 140u);
  unsigned long long m = __ballot(sane);
  if (i == 0) *flag = (__popcll(m) >= 40) ? 1 : 0;
}

// ---------------------------------------------------------------------------
// Kernel P: pack weights -> bf16, [Rp rows][Kp cols]; zero for k>=K or r>=R.
// (kept for gcn_w only)
// ---------------------------------------------------------------------------
__global__ __launch_bounds__(256) void k_pack(
    const void* __restrict__ src, u16* __restrict__ dst,
    int K, int Kp, int R, int Rp, const int* __restrict__ flag)
{
  const int bf = *flag;
  int total = Rp*Kp;
  int idx = blockIdx.x*256 + threadIdx.x;
  if (idx >= total) return;
  int r = idx / Kp, k = idx - r*Kp;
  u16 v = 0;
  if (k < K && r < R){
    size_t si = (size_t)r*K + k;
    v = bf ? ((const u16*)src)[si] : f2bu(((const float*)src)[si]);
  }
  dst[idx] = v;
}

// ---------------------------------------------------------------------------
// Kernel Pe: emb table -> bf16, 4 elems/thread. total4 = 70001*100/4.
// ---------------------------------------------------------------------------
__global__ __launch_bounds__(256) void k_packe(
    const void* __restrict__ emb, u16* __restrict__ Eb,
    int total4, const int* __restrict__ flag)
{
  const int bf = *flag;
  int idx = blockIdx.x*256 + threadIdx.x;
  if (idx >= total4) return;
  size_t i = (size_t)idx*4;
  union { u16 q[4]; uint2 d; } o;
  if (bf){
    o.d = *(const uint2*)((const u16*)emb + i);
  } else {
    float4 t = *(const float4*)((const float*)emb + i);
    o.q[0] = f2bu(t.x); o.q[1] = f2bu(t.y);
    o.q[2] = f2bu(t.z); o.q[3] = f2bu(t.w);
  }
  *(uint2*)(Eb + i) = o.d;
}

// ---------------------------------------------------------------------------
// Kernel Pg: gate-interleaved LSTM weight pack, 4 elems/thread along K.
// src [2][1800=gate*450+k][K] -> dst [2][1920][Kp],
// row' = (k/16)*64 + gate*16 + (k%16). Zero pad. Kp % 4 == 0.
// ---------------------------------------------------------------------------
__global__ __launch_bounds__(256) void k_packg(
    const void* __restrict__ src, u16* __restrict__ dst,
    int K, int Kp, const int* __restrict__ flag)
{
  const int bf = *flag;
  const int Kq = Kp >> 2;
  const int per = 1920*Kq;
  int idx = blockIdx.x*256 + threadIdx.x;
  if (idx >= 2*per) return;
  int z = idx / per, r = idx - z*per;
  int rp = r / Kq, cq = r - rp*Kq;
  int c0 = cq*4;
  int kblk = rp >> 6, rem = rp & 63, gate = rem >> 4, klo = rem & 15;
  int k = kblk*16 + klo;
  union { u16 q[4]; uint2 d; } o;
  o.q[0] = 0; o.q[1] = 0; o.q[2] = 0; o.q[3] = 0;
  if (k < 450){
    size_t base = ((size_t)z*1800 + (size_t)gate*450 + k)*K;
    #pragma unroll
    for (int e = 0; e < 4; ++e){
      int c = c0 + e;
      if (c < K)
        o.q[e] = bf ? ((const u16*)src)[base+c] : f2bu(((const float*)src)[base+c]);
    }
  }
  *(uint2*)(dst + (size_t)idx*4) = o.d;
}

// ---------------------------------------------------------------------------
// Kernel Pb: permuted bias pack: Bp[z][1920] f32 = bih+bhh at (gate,k).
// ---------------------------------------------------------------------------
__global__ __launch_bounds__(256) void k_packb(
    const void* __restrict__ bih, const void* __restrict__ bhh,
    float* __restrict__ Bp, const int* __restrict__ flag)
{
  const int bf = *flag;
  int idx = blockIdx.x*256 + threadIdx.x;
  if (idx >= 2*1920) return;
  int z = idx / 1920, rp = idx - z*1920;
  int kblk = rp >> 6, rem = rp & 63, gate = rem >> 4, klo = rem & 15;
  int k = kblk*16 + klo;
  float v = 0.0f;
  if (k < 450){
    size_t si = (size_t)z*1800 + (size_t)gate*450 + k;
    v = ldf(bih, si, bf) + ldf(bhh, si, bf);
  }
  Bp[idx] = v;
}

// ---------------------------------------------------------------------------
// Kernel 1: neighbor encoder. Gathers read PRE-PACKED bf16 emb (Eb) -- half
// the fetch volume of the f32 path, no convert in the hot loop. Register
// prefetch (pv) kept. Tail = accumulator shfl reductions.
// ---------------------------------------------------------------------------
__global__ __launch_bounds__(512, 4) void k_gcn(
    const int* __restrict__ left, const int* __restrict__ right,
    const void* __restrict__ emb, const u16* __restrict__ Eb,
    const u16* __restrict__ Wg,
    const void* __restrict__ gcnwb, const void* __restrict__ gcnb,
    const void* __restrict__ attnw, const void* __restrict__ attnwb,
    const void* __restrict__ gatew, const void* __restrict__ gatewb,
    const void* __restrict__ gateb,
    const int* __restrict__ flag,
    u16* __restrict__ X0bf)
{
  __shared__ __align__(16) u16 As[208*40];    // 16640 B
  __shared__ __align__(16) u16 Bs[112*232];   // 51968 B
  __shared__ int c1_s[200], c2_s[200];
  __shared__ float logit_s[208];
  __shared__ float red_s[512];
  __shared__ float attnw_s[112], bias_s[112], gatew_s[112], oa_s[112];

  const int bf  = *flag;
  const int tid = threadIdx.x;
  const int n   = blockIdx.x;
  const int b   = n & 255;
  const int fs  = n >> 8;
  const int s   = fs & 1;
  const int f   = fs >> 1;
  const int* conn = (s == 0 ? left : right) + (size_t)(f*256 + b)*600;

  if (tid < 200){ c1_s[tid] = conn[tid*3+1]; c2_s[tid] = conn[tid*3+2]; }
  if (tid < 112){
    attnw_s[tid] = (tid < 100) ? ldf(attnw, tid, bf) : 0.0f;
    bias_s[tid]  = (tid < 100) ? (ldf(gcnwb, tid, bf) + ldf(gcnb, tid, bf)) : 0.0f;
    gatew_s[tid] = (tid < 100) ? ldf(gatew, tid, bf) : 0.0f;
    oa_s[tid] = 0.0f;
  }
  for (int g = tid; g < 112*28; g += 512){
    int r = g / 28, cc = g - r*28;
    *(short8*)(Bs + r*232 + cc*8) = *(const short8*)(Wg + (size_t)r*224 + cc*8);
  }
  __syncthreads();

  const int wid  = tid >> 6, lane = tid & 63, ln = lane & 15, quad = lane >> 4;
  const int mt0 = (wid < 5) ? 2*wid : (10 + (wid - 5));
  const int nmt = (wid < 5) ? 2 : 1;

  // gather kc's A-slots (bf16 table, 8 B/slot) into registers
  auto loadA = [&](int kc, uint2* pv){
    #pragma unroll
    for (int it = 0; it < 4; ++it){
      int g = tid + it*512;
      uint2 v; v.x = 0u; v.y = 0u;
      if (g < 1664){
        int r = g >> 3, gi = g & 7, k = kc*32 + gi*4;
        if (r < 200 && k < 200){
          int c  = (k < 100) ? c1_s[r] : c2_s[r];
          int kk = (k < 100) ? k : (k - 100);
          v = *(const uint2*)(Eb + (size_t)c*100 + kk);
        }
      }
      pv[it] = v;
    }
  };

  f32x4 acc[2][7];
  #pragma unroll
  for (int i = 0; i < 2; ++i)
    #pragma unroll
    for (int j = 0; j < 7; ++j) acc[i][j] = (f32x4)0.0f;

  uint2 pv[4];
  loadA(0, pv);

  for (int kc = 0; kc < 7; ++kc){
    const int k0 = kc*32;
    #pragma unroll
    for (int it = 0; it < 4; ++it){
      int g = tid + it*512;
      if (g < 1664){
        int r = g >> 3, gi = g & 7;
        *(uint2*)(As + r*40 + gi*4) = pv[it];
      }
    }
    __syncthreads();
    if (kc < 6) loadA(kc+1, pv);   // in flight under MFMA phase

    #pragma unroll
    for (int mi = 0; mi < 2; ++mi){
      if (mi < nmt){
        short8 afr = *(const short8*)(As + ((mt0+mi)*16 + ln)*40 + quad*8);
        #pragma unroll
        for (int nt = 0; nt < 7; ++nt){
          short8 bfr = *(const short8*)(Bs + (size_t)(nt*16 + ln)*232 + k0 + quad*8);
          acc[mi][nt] = __builtin_amdgcn_mfma_f32_16x16x32_bf16(afr, bfr, acc[mi][nt], 0, 0, 0);
        }
      }
    }
    __syncthreads();
  }

  const float awb = ldf(attnwb, 0, bf);
  #pragma unroll
  for (int mi = 0; mi < 2; ++mi){
    if (mi < nmt){
      #pragma unroll
      for (int rg = 0; rg < 4; ++rg){
        float p = 0.0f;
        #pragma unroll
        for (int nt = 0; nt < 7; ++nt){
          float x = acc[mi][nt][rg] + bias_s[nt*16 + ln];
          x = x > 0.0f ? x : 0.01f*x;
          p += x * attnw_s[nt*16 + ln];
        }
        p += __shfl_xor(p, 1, 64); p += __shfl_xor(p, 2, 64);
        p += __shfl_xor(p, 4, 64); p += __shfl_xor(p, 8, 64);
        int m = (mt0+mi)*16 + quad*4 + rg;
        if (ln == 0 && m < 200) logit_s[m] = p + awb;
      }
    }
  }
  __syncthreads();

  red_s[tid] = (tid < 200) ? logit_s[tid] : -3.0e38f;
  __syncthreads();
  for (int off = 256; off > 0; off >>= 1){
    if (tid < off) red_s[tid] = fmaxf(red_s[tid], red_s[tid+off]);
    __syncthreads();
  }
  float mx = red_s[0];
  __syncthreads();
  float ev = 0.0f;
  if (tid < 200) ev = expf(logit_s[tid] - mx);
  red_s[tid] = ev;
  __syncthreads();
  for (int off = 256; off > 0; off >>= 1){
    if (tid < off) red_s[tid] += red_s[tid+off];
    __syncthreads();
  }
  float S = red_s[0];
  __syncthreads();
  if (tid < 208) logit_s[tid] = (tid < 200) ? ev*(1.0f/S) : 0.0f;
  __syncthreads();

  float at[2][4];
  #pragma unroll
  for (int mi = 0; mi < 2; ++mi)
    #pragma unroll
    for (int rg = 0; rg < 4; ++rg)
      at[mi][rg] = (mi < nmt) ? logit_s[(mt0+mi)*16 + quad*4 + rg] : 0.0f;

  #pragma unroll
  for (int nt = 0; nt < 7; ++nt){
    float p = 0.0f;
    #pragma unroll
    for (int mi = 0; mi < 2; ++mi){
      if (mi < nmt){
        #pragma unroll
        for (int rg = 0; rg < 4; ++rg){
          float x = acc[mi][nt][rg] + bias_s[nt*16 + ln];
          x = x > 0.0f ? x : 0.01f*x;
          p += x * at[mi][rg];
        }
      }
    }
    p += __shfl_xor(p, 16, 64); p += __shfl_xor(p, 32, 64);
    if (quad == 0) atomicAdd(&oa_s[nt*16 + ln], p);
  }
  __syncthreads();

  red_s[tid] = (tid < 100) ? oa_s[tid]*gatew_s[tid] : 0.0f;
  __syncthreads();
  for (int off = 256; off > 0; off >>= 1){
    if (tid < off) red_s[tid] += red_s[tid+off];
    __syncthreads();
  }
  float gate = sigm(red_s[0] + ldf(gatewb, 0, bf) + ldf(gateb, 0, bf));
  if (tid < 100){
    int c0 = conn[0];
    float self = ldf(emb, (size_t)c0*100 + tid, bf);
    X0bf[((size_t)f*256 + b)*224 + s*100 + tid] = f2bu(oa_s[tid]*gate + self*(1.0f - gate));
  }
}

// ---------------------------------------------------------------------------
// Kernel M: MFMA GEMM (input projections only). out[z][row][col'] bf16 =
// A[row]·B'[col'] + Bp[z][col']. N=1920 exact (15x128 tiles), M mult of 128.
// ---------------------------------------------------------------------------
__global__ __launch_bounds__(256) void k_mgemm(
    const u16* __restrict__ A, int lda, size_t Astride,
    const u16* __restrict__ B, int ldb, size_t Bstride,
    const float* __restrict__ bsum,
    u16* __restrict__ out, size_t Ostride,
    int N, int KC)
{
  __shared__ __align__(16) u16 As[128*40];
  __shared__ __align__(16) u16 Bs[128*40];
  const int tid = threadIdx.x;
  const int z  = blockIdx.z;
  const int nb = blockIdx.x, mb = blockIdx.y;
  const u16* Az = A + (size_t)z*Astride;
  const u16* Bz = B + (size_t)z*Bstride;

  const int wid = tid >> 6, lane = tid & 63, ln = lane & 15, quad = lane >> 4;
  const int wm = wid >> 1, wn = wid & 1;

  f32x4 acc[4][4];
  #pragma unroll
  for (int i = 0; i < 4; ++i)
    #pragma unroll
    for (int j = 0; j < 4; ++j) acc[i][j] = (f32x4)0.0f;

  const int srow = tid >> 1;
  const int koff = (tid & 1)*16;
  const int rowA = mb*128 + srow;
  const int rowB = nb*128 + srow;

  for (int kc = 0; kc < KC; ++kc){
    const int k0 = kc*32 + koff;
    const u16* ap = Az + (size_t)rowA*lda + k0;
    const u16* bp = Bz + (size_t)rowB*ldb + k0;
    short8 av0 = *(const short8*)(ap);
    short8 av1 = *(const short8*)(ap + 8);
    short8 bv0 = *(const short8*)(bp);
    short8 bv1 = *(const short8*)(bp + 8);
    *(short8*)(As + srow*40 + koff)     = av0;
    *(short8*)(As + srow*40 + koff + 8) = av1;
    *(short8*)(Bs + srow*40 + koff)     = bv0;
    *(short8*)(Bs + srow*40 + koff + 8) = bv1;
    __syncthreads();
    short8 af[4], bfr[4];
    #pragma unroll
    for (int i = 0; i < 4; ++i)
      af[i] = *(const short8*)(As + (wm*64 + i*16 + ln)*40 + quad*8);
    #pragma unroll
    for (int j = 0; j < 4; ++j)
      bfr[j] = *(const short8*)(Bs + (wn*64 + j*16 + ln)*40 + quad*8);
    #pragma unroll
    for (int i = 0; i < 4; ++i)
      #pragma unroll
      for (int j = 0; j < 4; ++j)
        acc[i][j] = __builtin_amdgcn_mfma_f32_16x16x32_bf16(af[i], bfr[j], acc[i][j], 0, 0, 0);
    __syncthreads();
  }

  #pragma unroll
  for (int j = 0; j < 4; ++j){
    int col = nb*128 + wn*64 + j*16 + ln;
    float bias = bsum ? bsum[(size_t)z*1920 + col] : 0.0f;
    #pragma unroll
    for (int i = 0; i < 4; ++i){
      #pragma unroll
      for (int rg = 0; rg < 4; ++rg){
        int row = mb*128 + wm*64 + i*16 + quad*4 + rg;
        out[(size_t)z*Ostride + (size_t)row*N + col] = f2bu(acc[i][j][rg] + bias);
      }
    }
  }
}

// ---------------------------------------------------------------------------
// Kernel H: fused hidden GEMM + LSTM cell (round-5 verified, unchanged).
// ---------------------------------------------------------------------------
__global__ __launch_bounds__(256) void k_hstep(
    const u16* __restrict__ Hin, const u16* __restrict__ Whp,
    const u16* __restrict__ Gb, float* __restrict__ HC,
    u16* __restrict__ Hout, u16* __restrict__ Ybf, float* __restrict__ Yf,
    float* __restrict__ HF, int s, int layer)
{
  __shared__ __align__(16) u16 As[32*40];
  __shared__ __align__(16) u16 Bs[128*40];
  const int tid = threadIdx.x;
  const int nb = blockIdx.x, mb = blockIdx.y, z = blockIdx.z;
  const int wid = tid >> 6, lane = tid & 63, ln = lane & 15, quad = lane >> 4;
  const int wm = wid >> 1, wn = wid & 1;

  const u16* Az = Hin + ((size_t)z*256 + mb*32)*480;
  const u16* Bz = Whp + (size_t)z*1920*480 + (size_t)nb*128*480;

  f32x4 acc[4];
  #pragma unroll
  for (int j = 0; j < 4; ++j) acc[j] = (f32x4)0.0f;

  const int ar = tid >> 2, ap = tid & 3;   // A: first 128 threads
  const int br = tid >> 1, bp = tid & 1;   // B: all 256 threads
  for (int kc = 0; kc < 15; ++kc){
    const int k0 = kc*32;
    if (tid < 128)
      *(short8*)(As + ar*40 + ap*8) = *(const short8*)(Az + (size_t)ar*480 + k0 + ap*8);
    *(short8*)(Bs + br*40 + bp*16)     = *(const short8*)(Bz + (size_t)br*480 + k0 + bp*16);
    *(short8*)(Bs + br*40 + bp*16 + 8) = *(const short8*)(Bz + (size_t)br*480 + k0 + bp*16 + 8);
    __syncthreads();
    short8 afr = *(const short8*)(As + (wm*16 + ln)*40 + quad*8);
    #pragma unroll
    for (int j = 0; j < 4; ++j){
      short8 bfr = *(const short8*)(Bs + (wn*64 + j*16 + ln)*40 + quad*8);
      acc[j] = __builtin_amdgcn_mfma_f32_16x16x32_bf16(afr, bfr, acc[j], 0, 0, 0);
    }
    __syncthreads();
  }

  const int kblk = nb*2 + wn;
  const int k = kblk*16 + ln;
  const int t = z ? (4 - s) : s;
  if (k < 450){
    const u16* Gz = Gb + (size_t)z*2457600 + (size_t)t*256*1920;
    #pragma unroll
    for (int rg = 0; rg < 4; ++rg){
      int b = mb*32 + wm*16 + quad*4 + rg;
      const u16* grow = Gz + (size_t)b*1920 + nb*128 + wn*64 + ln;
      float gi = acc[0][rg] + u2f(grow[0]);
      float gf = acc[1][rg] + u2f(grow[16]);
      float gg = acc[2][rg] + u2f(grow[32]);
      float go = acc[3][rg] + u2f(grow[48]);
      float* cp = HC + ((size_t)(2+z)*256 + b)*450 + k;
      float c = sigm(gf)*(*cp) + sigm(gi)*tanhf(gg);
      float h = sigm(go)*tanhf(c);
      *cp = c;
      Hout[((size_t)z*256 + b)*480 + k] = f2bu(h);
      if (Ybf) Ybf[((size_t)t*256 + b)*928 + z*450 + k] = f2bu(h);
      else     Yf [((size_t)t*256 + b)*900 + z*450 + k] = h;
      HF[((size_t)(layer*2+z)*256 + b)*450 + k] = h;
    }
  }
}

// ---------------------------------------------------------------------------
// Kernel 5: attention over timesteps + context (unchanged).
// ---------------------------------------------------------------------------
__global__ __launch_bounds__(256) void k_attn(
    const float* __restrict__ Y1, const float* __restrict__ HF,
    float* __restrict__ CTX)
{
  __shared__ float red[256];
  __shared__ float sc[10];
  __shared__ float aw[10];
  int b = blockIdx.x, tid = threadIdx.x;
  for (int p = 0; p < 10; ++p){
    int t = p >> 1, l = p & 1;
    float a = 0.0f;
    for (int h = tid; h < 900; h += 256)
      a += Y1[((size_t)t*256 + b)*900 + h] * HF[(size_t)b*1800 + h*2 + l];
    red[tid] = a; __syncthreads();
    for (int off = 128; off > 0; off >>= 1){
      if (tid < off) red[tid] += red[tid+off];
      __syncthreads();
    }
    if (tid == 0) sc[p] = red[0];
    __syncthreads();
  }
  if (tid < 2){
    int l = tid;
    float mxv = -3.0e38f;
    for (int t = 0; t < 5; ++t) mxv = fmaxf(mxv, sc[t*2+l]);
    float e[5], sum = 0.0f;
    for (int t = 0; t < 5; ++t){ e[t] = expf(sc[t*2+l]-mxv); sum += e[t]; }
    for (int t = 0; t < 5; ++t) aw[t*2+l] = e[t]/sum;
  }
  __syncthreads();
  for (int h = tid; h < 900; h += 256){
    float v0 = 0.0f, v1 = 0.0f;
    for (int t = 0; t < 5; ++t){
      float y = Y1[((size_t)t*256 + b)*900 + h];
      v0 += y*aw[t*2+0]; v1 += y*aw[t*2+1];
    }
    CTX[(size_t)b*1800 + h*2 + 0] = v0;
    CTX[(size_t)b*1800 + h*2 + 1] = v1;
  }
}

// ---------------------------------------------------------------------------
// Kernel 2s: scalar GEMM (kept only for CTX @ out_w, C=100).
// ---------------------------------------------------------------------------
__global__ __launch_bounds__(256) void k_gemm(
    const float* __restrict__ A, const void* __restrict__ W, size_t wEl,
    const void* __restrict__ b1, const void* __restrict__ b2, size_t bEl,
    const int* __restrict__ flag,
    float* __restrict__ out, int K, int C)
{
  extern __shared__ float a_s[];
  const int bf = *flag;
  const int tid = threadIdx.x;
  const int r = blockIdx.y;
  const float* a = A + (size_t)r*K;
  for (int k = tid; k < K; k += 256) a_s[k] = a[k];
  __syncthreads();
  const int j = blockIdx.x*256 + tid;
  if (j >= C) return;
  float acc = 0.0f;
  if (b1) acc += ldf(b1, bEl + j, bf);
  if (b2) acc += ldf(b2, bEl + j, bf);
  if (bf){
    const u16* w = (const u16*)W + wEl + (size_t)j*K;
    for (int k = 0; k < K; k += 4){
      uint2 wv = *(const uint2*)(w + k);
      acc += a_s[k]   * u2f(wv.x & 0xffffu);
      acc += a_s[k+1] * u2f(wv.x >> 16);
      acc += a_s[k+2] * u2f(wv.y & 0xffffu);
      acc += a_s[k+3] * u2f(wv.y >> 16);
    }
  } else {
    const float* w = (const float*)W + wEl + (size_t)j*K;
    for (int k = 0; k < K; k += 4){
      float4 wv = *(const float4*)(w + k);
      acc += a_s[k]*wv.x + a_s[k+1]*wv.y + a_s[k+2]*wv.z + a_s[k+3]*wv.w;
    }
  }
  out[(size_t)r*C + j] = acc;
}

__device__ __forceinline__ float bred128(float v, float* red, int tid){
  red[tid] = v; __syncthreads();
  for (int off = 64; off > 0; off >>= 1){
    if (tid < off) red[tid] += red[tid+off];
    __syncthreads();
  }
  float r = red[0]; __syncthreads();
  return r;
}

// ---------------------------------------------------------------------------
// Kernel 6: analytic meta-gradient -> rel_q, norm_q. One block per b.
// ---------------------------------------------------------------------------
__global__ __launch_bounds__(128) void k_grad(
    const void* __restrict__ sup, const void* __restrict__ supn,
    const void* __restrict__ normv, const float* __restrict__ REL,
    const int* __restrict__ flag,
    float* __restrict__ RELQ, float* __restrict__ NORMQ)
{
  __shared__ float red[128];
  __shared__ float nv[100], rl[100], acc[100];
  const int bf = *flag;
  int b = blockIdx.x, tid = threadIdx.x;
  if (tid < 100){
    nv[tid] = ldf(normv, b*100+tid, bf);
    rl[tid] = REL[b*100+tid];
    acc[tid] = 0.0f;
  }
  __syncthreads();
  float nvd = (tid < 100) ? nv[tid] : 0.0f;
  float rld = (tid < 100) ? rl[tid] : 0.0f;
  for (int j = 0; j < 5; ++j){
    float h1=0.f,t1=0.f,h2=0.f,t2=0.f;
    if (tid < 100){
      size_t base = (size_t)(b*5+j)*200;
      h1 = ldf(sup,  base + tid, bf);  t1 = ldf(sup,  base + 100 + tid, bf);
      h2 = ldf(supn, base + tid, bf);  t2 = ldf(supn, base + 100 + tid, bf);
    }
    float hd1 = bred128(h1*nvd, red, tid);
    float td1 = bred128(t1*nvd, red, tid);
    float hd2 = bred128(h2*nvd, red, tid);
    float td2 = bred128(t2*nvd, red, tid);
    float upd = (h1 - hd1*nvd) + rld - (t1 - td1*nvd);
    float und = (h2 - hd2*nvd) + rld - (t2 - td2*nvd);
    if (tid >= 100){ upd = 0.0f; und = 0.0f; }
    float np2 = bred128(upd*upd, red, tid);
    float nn2 = bred128(und*und, red, tid);
    float p = -sqrtf(np2), nsc = -sqrtf(nn2);
    if ((1.0f - (p - nsc) > 0.0f) && tid < 100)
      acc[tid] += upd/sqrtf(np2) - und/sqrtf(nn2);
  }
  __syncthreads();
  if (tid < 100){
    float g = acc[tid] * (1.0f/1280.0f);
    RELQ[b*100+tid]  = rl[tid] - 5.0f*g;
    NORMQ[b*100+tid] = nv[tid] - 5.0f*g;
  }
}

// ---------------------------------------------------------------------------
// Kernel 7: final scores (unchanged, round-2 verified).
// ---------------------------------------------------------------------------
__global__ __launch_bounds__(256) void k_score(
    const void* __restrict__ query, const void* __restrict__ neg,
    const float* __restrict__ RELQ, const float* __restrict__ NORMQ,
    const int* __restrict__ flag, void* __restrict__ out)
{
  __shared__ __align__(16) float nq[104], rq[104];
  const int bf = *flag;
  const int b = blockIdx.x, tid = threadIdx.x;
  if (tid < 100){ nq[tid] = NORMQ[b*100+tid]; rq[tid] = RELQ[b*100+tid]; }
  __syncthreads();
  const int wid = tid >> 6, lane = tid & 63;
  const int d0 = lane*4;
  const int nidx = (lane < 25) ? d0 : (d0 - 100);
  float4 w4 = make_float4(0.0f,0.0f,0.0f,0.0f);
  float4 r4 = make_float4(0.0f,0.0f,0.0f,0.0f);
  if (lane < 50) w4 = *(const float4*)(nq + nidx);
  if (lane < 25) r4 = *(const float4*)(rq + d0);

  for (int qi = blockIdx.y*4 + wid; qi < 522; qi += 32){
    const void* src = (qi < 10) ? query : neg;
    size_t row = (qi < 10) ? ((size_t)b*10 + qi) : ((size_t)b*512 + qi - 10);
    size_t base = row*200;
    float4 v = make_float4(0.0f,0.0f,0.0f,0.0f);
    if (lane < 50){
      if (bf){
        uint2 u = *(const uint2*)((const u16*)src + base + d0);
        v.x = u2f(u.x & 0xffffu); v.y = u2f(u.x >> 16);
        v.z = u2f(u.y & 0xffffu); v.w = u2f(u.y >> 16);
      } else {
        v = *(const float4*)((const float*)src + base + d0);
      }
    }
    float p = v.x*w4.x + v.y*w4.y + v.z*w4.z + v.w*w4.w;
    float hd = wsum(lane < 25 ? p : 0.0f);
    float td = wsum((lane >= 25 && lane < 50) ? p : 0.0f);
    int sl = (lane < 25) ? (lane + 25) : lane;
    float4 t4;
    t4.x = __shfl(v.x, sl, 64);
    t4.y = __shfl(v.y, sl, 64);
    t4.z = __shfl(v.z, sl, 64);
    t4.w = __shfl(v.w, sl, 64);
    float s2p = 0.0f;
    if (lane < 25){
      float ux = (v.x - hd*w4.x) + r4.x - (t4.x - td*w4.x);
      float uy = (v.y - hd*w4.y) + r4.y - (t4.y - td*w4.y);
      float uz = (v.z - hd*w4.z) + r4.z - (t4.z - td*w4.z);
      float uw = (v.w - hd*w4.w) + r4.w - (t4.w - td*w4.w);
      s2p = ux*ux + uy*uy + uz*uz + uw*uw;
    }
    float s2 = wsum(s2p);
    if (lane == 0){
      float sc = -sqrtf(s2);
      size_t oi = (qi < 10) ? ((size_t)b*10 + qi) : (2560 + (size_t)b*512 + (qi - 10));
      if (bf) ((u16*)out)[oi] = f2bu(sc);
      else    ((float*)out)[oi] = sc;
    }
  }
}

// ---------------------------------------------------------------------------
extern "C" void kernel_launch(void* const* d_in, const int* in_sizes, int n_in,
                              void* d_out, int out_size, void* d_ws, size_t ws_size,
                              hipStream_t stream)
{
  const void* support = d_in[0];
  const void* supneg  = d_in[1];
  const void* query   = d_in[2];
  const void* negat   = d_in[3];
  const void* normv   = d_in[4];
  const int* left     = (const int*)d_in[5];
  const int* right    = (const int*)d_in[6];
  const void* emb     = d_in[7];
  const void* gcnw    = d_in[8];
  const void* gcnwb   = d_in[9];
  const void* gcnb    = d_in[10];
  const void* attnw   = d_in[11];
  const void* attnwb  = d_in[12];
  const void* gatew   = d_in[13];
  const void* gatewb  = d_in[14];
  const void* gateb   = d_in[15];
  const void* Wih0    = d_in[16];
  const void* Whh0    = d_in[17];
  const void* bih0    = d_in[18];
  const void* bhh0    = d_in[19];
  const void* Wih1    = d_in[20];
  const void* Whh1    = d_in[21];
  const void* bih1    = d_in[22];
  const void* bhh1    = d_in[23];
  const void* outw    = d_in[24];
  const void* outb    = d_in[25];

  int*   dflag = (int*)d_ws;
  float* fws   = (float*)d_ws + 16;
  // f32 region
  float* Y1   = fws;                 // 5*256*900  = 1,152,000
  float* HF   = Y1 + 1152000;        // 4*256*450  =   460,800
  float* HC   = HF + 460800;         //               460,800 (c in slots 2,3)
  float* CTX  = HC + 460800;         //               460,800
  float* RELb = CTX + 460800;        //    25,600
  float* RELQ = RELb + 25600;        //    25,600
  float* NORMQ= RELQ + 25600;        //    25,600
  float* Bp   = NORMQ + 25600;       //     3,840  (2x1920 permuted bias)
  float* fend = Bp + 3840;           // total f32 = 2,615,040 (16B aligned)
  // u16 region
  u16* Gb   = (u16*)fend;            // 2*1280*1920 = 4,915,200
  u16* X0bf = Gb + 4915200;          // 1280*224    =   286,720
  u16* Y0bf = X0bf + 286720;         // 1280*928    = 1,187,840
  u16* Hbf  = Y0bf + 1187840;        // 2 par * 2*256*480 = 491,520
  u16* Wg   = Hbf + 491520;          // 112*224     =    25,088
  u16* Eb   = Wg + 25088;            // 70001*100   = 7,000,100 (bf16 emb)
  // Wp/Whp ALIAS Eb: Eb dead after k_gcn; packs run after (stream-serial).
  u16* Wp   = Eb;                    // 2*1920*928 max = 3,563,520
  u16* Whp  = Eb + 3563520;          // 2*1920*480  = 1,843,200 (sum 5.4M < 7.0M)
  // total ~= 38.3 MB

  k_detect<<<1, 64, 0, stream>>>((const u32*)normv, dflag);

  // neighbor encoder -> X0bf
  hipMemsetAsync(X0bf, 0, 286720*sizeof(u16), stream);
  k_pack<<<(112*224+255)/256, 256, 0, stream>>>(gcnw, Wg, 200, 224, 100, 112, dflag);
  k_packe<<<(1750025+255)/256, 256, 0, stream>>>(emb, Eb, 1750025, dflag);
  k_gcn<<<2560, 512, 0, stream>>>(left, right, emb, Eb, Wg, gcnwb, gcnb,
                                  attnw, attnwb, gatew, gatewb, gateb,
                                  dflag, X0bf);

  u16* Hpar0 = Hbf;
  u16* Hpar1 = Hbf + 245760;

  // ---- layer 0 ----
  hipMemsetAsync(Y0bf, 0, 1187840*sizeof(u16), stream);
  hipMemsetAsync(Hbf, 0, 491520*sizeof(u16), stream);
  hipMemsetAsync(HC, 0, 460800*sizeof(float), stream);
  k_packg<<<(2*1920*224/4+255)/256, 256, 0, stream>>>(Wih0, Wp, 200, 224, dflag);
  k_packg<<<(2*1920*480/4+255)/256, 256, 0, stream>>>(Whh0, Whp, 450, 480, dflag);
  k_packb<<<15, 256, 0, stream>>>(bih0, bhh0, Bp, dflag);
  k_mgemm<<<dim3(15,10,2), 256, 0, stream>>>(
      X0bf, 224, 0, Wp, 224, (size_t)1920*224,
      Bp, Gb, 2457600, 1920, 7);
  {
    u16* hc = Hpar0; u16* hn = Hpar1;
    for (int s = 0; s < 5; ++s){
      k_hstep<<<dim3(15,8,2), 256, 0, stream>>>(hc, Whp, Gb, HC, hn,
                                                Y0bf, nullptr, HF, s, 0);
      u16* tmp = hc; hc = hn; hn = tmp;
    }
  }

  // ---- layer 1 ----
  hipMemsetAsync(Hbf, 0, 491520*sizeof(u16), stream);
  hipMemsetAsync(HC, 0, 460800*sizeof(float), stream);
  k_packg<<<(2*1920*928/4+255)/256, 256, 0, stream>>>(Wih1, Wp, 900, 928, dflag);
  k_packg<<<(2*1920*480/4+255)/256, 256, 0, stream>>>(Whh1, Whp, 450, 480, dflag);
  k_packb<<<15, 256, 0, stream>>>(bih1, bhh1, Bp, dflag);
  k_mgemm<<<dim3(15,10,2), 256, 0, stream>>>(
      Y0bf, 928, 0, Wp, 928, (size_t)1920*928,
      Bp, Gb, 2457600, 1920, 29);
  {
    u16* hc = Hpar0; u16* hn = Hpar1;
    for (int s = 0; s < 5; ++s){
      k_hstep<<<dim3(15,8,2), 256, 0, stream>>>(hc, Whp, Gb, HC, hn,
                                                nullptr, Y1, HF, s, 1);
      u16* tmp = hc; hc = hn; hn = tmp;
    }
  }

  k_attn<<<256, 256, 0, stream>>>(Y1, HF, CTX);
  k_gemm<<<dim3(1,256), 256, 1800*4, stream>>>(CTX, outw, 0, outb, nullptr, 0,
                                               dflag, RELb, 1800, 100);
  k_grad<<<256, 128, 0, stream>>>(support, supneg, normv, RELb, dflag, RELQ, NORMQ);
  k_score<<<dim3(256,8), 256, 0, stream>>>(query, negat, RELQ, NORMQ, dflag, d_out);
}

// Round 8
// 726.139 us; speedup vs baseline: 1.5320x; 1.0154x over previous
//
#include <hip/hip_runtime.h>

typedef unsigned short u16;
typedef unsigned int   u32;
typedef __attribute__((ext_vector_type(8))) short short8;
typedef __attribute__((ext_vector_type(4))) float f32x4;

__device__ __forceinline__ float u2f(u32 u){
  union { u32 i; float f; } v; v.i = u << 16; return v.f;
}
__device__ __forceinline__ u16 f2bu(float f){
  union { float f; u32 i; } v; v.f = f;
  u32 i = v.i;
  i += 0x7fffu + ((i >> 16) & 1u);   // round-to-nearest-even
  return (u16)(i >> 16);
}
__device__ __forceinline__ float sigm(float x){ return 1.0f/(1.0f + expf(-x)); }
__device__ __forceinline__ float ldf(const void* p, size_t i, int bf){
  return bf ? u2f(((const u16*)p)[i]) : ((const float*)p)[i];
}
__device__ __forceinline__ float wsum(float v){
  #pragma unroll
  for (int off = 32; off > 0; off >>= 1) v += __shfl_xor(v, off, 64);
  return v;
}

// ---------------------------------------------------------------------------
// Kernel 0: dtype detector (bf16 vs f32 device buffers).
// ---------------------------------------------------------------------------
__global__ __launch_bounds__(64) void k_detect(const u32* __restrict__ nv,
                                               int* __restrict__ flag)
{
  int i = threadIdx.x;
  u32 w = nv[i];
  u32 e = (w >> 7) & 0xffu;
  bool sane = (e >= 100u && e <= 140u);
  unsigned long long m = __ballot(sane);
  if (i == 0) *flag = (__popcll(m) >= 40) ? 1 : 0;
}

// ---------------------------------------------------------------------------
// Kernel P: pack weights -> bf16, [Rp rows][Kp cols]; zero for k>=K or r>=R.
// (kept for gcn_w only)
// ---------------------------------------------------------------------------
__global__ __launch_bounds__(256) void k_pack(
    const void* __restrict__ src, u16* __restrict__ dst,
    int K, int Kp, int R, int Rp, const int* __restrict__ flag)
{
  const int bf = *flag;
  int total = Rp*Kp;
  int idx = blockIdx.x*256 + threadIdx.x;
  if (idx >= total) return;
  int r = idx / Kp, k = idx - r*Kp;
  u16 v = 0;
  if (k < K && r < R){
    size_t si = (size_t)r*K + k;
    v = bf ? ((const u16*)src)[si] : f2bu(((const float*)src)[si]);
  }
  dst[idx] = v;
}

// ---------------------------------------------------------------------------
// Kernel Pe: emb table -> bf16, 4 elems/thread. total4 = 70001*100/4.
// ---------------------------------------------------------------------------
__global__ __launch_bounds__(256) void k_packe(
    const void* __restrict__ emb, u16* __restrict__ Eb,
    int total4, const int* __restrict__ flag)
{
  const int bf = *flag;
  int idx = blockIdx.x*256 + threadIdx.x;
  if (idx >= total4) return;
  size_t i = (size_t)idx*4;
  union { u16 q[4]; uint2 d; } o;
  if (bf){
    o.d = *(const uint2*)((const u16*)emb + i);
  } else {
    float4 t = *(const float4*)((const float*)emb + i);
    o.q[0] = f2bu(t.x); o.q[1] = f2bu(t.y);
    o.q[2] = f2bu(t.z); o.q[3] = f2bu(t.w);
  }
  *(uint2*)(Eb + i) = o.d;
}

// ---------------------------------------------------------------------------
// Kernel Pg: gate-interleaved LSTM weight pack, 4 elems/thread along K.
// src [2][1800=gate*450+k][K] -> dst [2][1920][Kp],
// row' = (k/16)*64 + gate*16 + (k%16). Zero pad. Kp % 4 == 0.
// ---------------------------------------------------------------------------
__global__ __launch_bounds__(256) void k_packg(
    const void* __restrict__ src, u16* __restrict__ dst,
    int K, int Kp, const int* __restrict__ flag)
{
  const int bf = *flag;
  const int Kq = Kp >> 2;
  const int per = 1920*Kq;
  int idx = blockIdx.x*256 + threadIdx.x;
  if (idx >= 2*per) return;
  int z = idx / per, r = idx - z*per;
  int rp = r / Kq, cq = r - rp*Kq;
  int c0 = cq*4;
  int kblk = rp >> 6, rem = rp & 63, gate = rem >> 4, klo = rem & 15;
  int k = kblk*16 + klo;
  union { u16 q[4]; uint2 d; } o;
  o.q[0] = 0; o.q[1] = 0; o.q[2] = 0; o.q[3] = 0;
  if (k < 450){
    size_t base = ((size_t)z*1800 + (size_t)gate*450 + k)*K;
    #pragma unroll
    for (int e = 0; e < 4; ++e){
      int c = c0 + e;
      if (c < K)
        o.q[e] = bf ? ((const u16*)src)[base+c] : f2bu(((const float*)src)[base+c]);
    }
  }
  *(uint2*)(dst + (size_t)idx*4) = o.d;
}

// ---------------------------------------------------------------------------
// Kernel Pb: permuted bias pack: Bp[z][1920] f32 = bih+bhh at (gate,k).
// ---------------------------------------------------------------------------
__global__ __launch_bounds__(256) void k_packb(
    const void* __restrict__ bih, const void* __restrict__ bhh,
    float* __restrict__ Bp, const int* __restrict__ flag)
{
  const int bf = *flag;
  int idx = blockIdx.x*256 + threadIdx.x;
  if (idx >= 2*1920) return;
  int z = idx / 1920, rp = idx - z*1920;
  int kblk = rp >> 6, rem = rp & 63, gate = rem >> 4, klo = rem & 15;
  int k = kblk*16 + klo;
  float v = 0.0f;
  if (k < 450){
    size_t si = (size_t)z*1800 + (size_t)gate*450 + k;
    v = ldf(bih, si, bf) + ldf(bhh, si, bf);
  }
  Bp[idx] = v;
}

// ---------------------------------------------------------------------------
// Kernel 1: neighbor encoder (round-7 verified, unchanged). Gathers read
// pre-packed bf16 emb (Eb); register prefetch; accumulator shfl tail.
// ---------------------------------------------------------------------------
__global__ __launch_bounds__(512, 4) void k_gcn(
    const int* __restrict__ left, const int* __restrict__ right,
    const void* __restrict__ emb, const u16* __restrict__ Eb,
    const u16* __restrict__ Wg,
    const void* __restrict__ gcnwb, const void* __restrict__ gcnb,
    const void* __restrict__ attnw, const void* __restrict__ attnwb,
    const void* __restrict__ gatew, const void* __restrict__ gatewb,
    const void* __restrict__ gateb,
    const int* __restrict__ flag,
    u16* __restrict__ X0bf)
{
  __shared__ __align__(16) u16 As[208*40];    // 16640 B
  __shared__ __align__(16) u16 Bs[112*232];   // 51968 B
  __shared__ int c1_s[200], c2_s[200];
  __shared__ float logit_s[208];
  __shared__ float red_s[512];
  __shared__ float attnw_s[112], bias_s[112], gatew_s[112], oa_s[112];

  const int bf  = *flag;
  const int tid = threadIdx.x;
  const int n   = blockIdx.x;
  const int b   = n & 255;
  const int fs  = n >> 8;
  const int s   = fs & 1;
  const int f   = fs >> 1;
  const int* conn = (s == 0 ? left : right) + (size_t)(f*256 + b)*600;

  if (tid < 200){ c1_s[tid] = conn[tid*3+1]; c2_s[tid] = conn[tid*3+2]; }
  if (tid < 112){
    attnw_s[tid] = (tid < 100) ? ldf(attnw, tid, bf) : 0.0f;
    bias_s[tid]  = (tid < 100) ? (ldf(gcnwb, tid, bf) + ldf(gcnb, tid, bf)) : 0.0f;
    gatew_s[tid] = (tid < 100) ? ldf(gatew, tid, bf) : 0.0f;
    oa_s[tid] = 0.0f;
  }
  for (int g = tid; g < 112*28; g += 512){
    int r = g / 28, cc = g - r*28;
    *(short8*)(Bs + r*232 + cc*8) = *(const short8*)(Wg + (size_t)r*224 + cc*8);
  }
  __syncthreads();

  const int wid  = tid >> 6, lane = tid & 63, ln = lane & 15, quad = lane >> 4;
  const int mt0 = (wid < 5) ? 2*wid : (10 + (wid - 5));
  const int nmt = (wid < 5) ? 2 : 1;

  // gather kc's A-slots (bf16 table, 8 B/slot) into registers
  auto loadA = [&](int kc, uint2* pv){
    #pragma unroll
    for (int it = 0; it < 4; ++it){
      int g = tid + it*512;
      uint2 v; v.x = 0u; v.y = 0u;
      if (g < 1664){
        int r = g >> 3, gi = g & 7, k = kc*32 + gi*4;
        if (r < 200 && k < 200){
          int c  = (k < 100) ? c1_s[r] : c2_s[r];
          int kk = (k < 100) ? k : (k - 100);
          v = *(const uint2*)(Eb + (size_t)c*100 + kk);
        }
      }
      pv[it] = v;
    }
  };

  f32x4 acc[2][7];
  #pragma unroll
  for (int i = 0; i < 2; ++i)
    #pragma unroll
    for (int j = 0; j < 7; ++j) acc[i][j] = (f32x4)0.0f;

  uint2 pv[4];
  loadA(0, pv);

  for (int kc = 0; kc < 7; ++kc){
    const int k0 = kc*32;
    #pragma unroll
    for (int it = 0; it < 4; ++it){
      int g = tid + it*512;
      if (g < 1664){
        int r = g >> 3, gi = g & 7;
        *(uint2*)(As + r*40 + gi*4) = pv[it];
      }
    }
    __syncthreads();
    if (kc < 6) loadA(kc+1, pv);   // in flight under MFMA phase

    #pragma unroll
    for (int mi = 0; mi < 2; ++mi){
      if (mi < nmt){
        short8 afr = *(const short8*)(As + ((mt0+mi)*16 + ln)*40 + quad*8);
        #pragma unroll
        for (int nt = 0; nt < 7; ++nt){
          short8 bfr = *(const short8*)(Bs + (size_t)(nt*16 + ln)*232 + k0 + quad*8);
          acc[mi][nt] = __builtin_amdgcn_mfma_f32_16x16x32_bf16(afr, bfr, acc[mi][nt], 0, 0, 0);
        }
      }
    }
    __syncthreads();
  }

  const float awb = ldf(attnwb, 0, bf);
  #pragma unroll
  for (int mi = 0; mi < 2; ++mi){
    if (mi < nmt){
      #pragma unroll
      for (int rg = 0; rg < 4; ++rg){
        float p = 0.0f;
        #pragma unroll
        for (int nt = 0; nt < 7; ++nt){
          float x = acc[mi][nt][rg] + bias_s[nt*16 + ln];
          x = x > 0.0f ? x : 0.01f*x;
          p += x * attnw_s[nt*16 + ln];
        }
        p += __shfl_xor(p, 1, 64); p += __shfl_xor(p, 2, 64);
        p += __shfl_xor(p, 4, 64); p += __shfl_xor(p, 8, 64);
        int m = (mt0+mi)*16 + quad*4 + rg;
        if (ln == 0 && m < 200) logit_s[m] = p + awb;
      }
    }
  }
  __syncthreads();

  red_s[tid] = (tid < 200) ? logit_s[tid] : -3.0e38f;
  __syncthreads();
  for (int off = 256; off > 0; off >>= 1){
    if (tid < off) red_s[tid] = fmaxf(red_s[tid], red_s[tid+off]);
    __syncthreads();
  }
  float mx = red_s[0];
  __syncthreads();
  float ev = 0.0f;
  if (tid < 200) ev = expf(logit_s[tid] - mx);
  red_s[tid] = ev;
  __syncthreads();
  for (int off = 256; off > 0; off >>= 1){
    if (tid < off) red_s[tid] += red_s[tid+off];
    __syncthreads();
  }
  float S = red_s[0];
  __syncthreads();
  if (tid < 208) logit_s[tid] = (tid < 200) ? ev*(1.0f/S) : 0.0f;
  __syncthreads();

  float at[2][4];
  #pragma unroll
  for (int mi = 0; mi < 2; ++mi)
    #pragma unroll
    for (int rg = 0; rg < 4; ++rg)
      at[mi][rg] = (mi < nmt) ? logit_s[(mt0+mi)*16 + quad*4 + rg] : 0.0f;

  #pragma unroll
  for (int nt = 0; nt < 7; ++nt){
    float p = 0.0f;
    #pragma unroll
    for (int mi = 0; mi < 2; ++mi){
      if (mi < nmt){
        #pragma unroll
        for (int rg = 0; rg < 4; ++rg){
          float x = acc[mi][nt][rg] + bias_s[nt*16 + ln];
          x = x > 0.0f ? x : 0.01f*x;
          p += x * at[mi][rg];
        }
      }
    }
    p += __shfl_xor(p, 16, 64); p += __shfl_xor(p, 32, 64);
    if (quad == 0) atomicAdd(&oa_s[nt*16 + ln], p);
  }
  __syncthreads();

  red_s[tid] = (tid < 100) ? oa_s[tid]*gatew_s[tid] : 0.0f;
  __syncthreads();
  for (int off = 256; off > 0; off >>= 1){
    if (tid < off) red_s[tid] += red_s[tid+off];
    __syncthreads();
  }
  float gate = sigm(red_s[0] + ldf(gatewb, 0, bf) + ldf(gateb, 0, bf));
  if (tid < 100){
    int c0 = conn[0];
    float self = ldf(emb, (size_t)c0*100 + tid, bf);
    X0bf[((size_t)f*256 + b)*224 + s*100 + tid] = f2bu(oa_s[tid]*gate + self*(1.0f - gate));
  }
}

// ---------------------------------------------------------------------------
// Kernel M: MFMA GEMM (input projections only). out[z][row][col'] bf16 =
// A[row]·B'[col'] + Bp[z][col']. N=1920 exact (15x128 tiles), M mult of 128.
// ---------------------------------------------------------------------------
__global__ __launch_bounds__(256) void k_mgemm(
    const u16* __restrict__ A, int lda, size_t Astride,
    const u16* __restrict__ B, int ldb, size_t Bstride,
    const float* __restrict__ bsum,
    u16* __restrict__ out, size_t Ostride,
    int N, int KC)
{
  __shared__ __align__(16) u16 As[128*40];
  __shared__ __align__(16) u16 Bs[128*40];
  const int tid = threadIdx.x;
  const int z  = blockIdx.z;
  const int nb = blockIdx.x, mb = blockIdx.y;
  const u16* Az = A + (size_t)z*Astride;
  const u16* Bz = B + (size_t)z*Bstride;

  const int wid = tid >> 6, lane = tid & 63, ln = lane & 15, quad = lane >> 4;
  const int wm = wid >> 1, wn = wid & 1;

  f32x4 acc[4][4];
  #pragma unroll
  for (int i = 0; i < 4; ++i)
    #pragma unroll
    for (int j = 0; j < 4; ++j) acc[i][j] = (f32x4)0.0f;

  const int srow = tid >> 1;
  const int koff = (tid & 1)*16;
  const int rowA = mb*128 + srow;
  const int rowB = nb*128 + srow;

  for (int kc = 0; kc < KC; ++kc){
    const int k0 = kc*32 + koff;
    const u16* ap = Az + (size_t)rowA*lda + k0;
    const u16* bp = Bz + (size_t)rowB*ldb + k0;
    short8 av0 = *(const short8*)(ap);
    short8 av1 = *(const short8*)(ap + 8);
    short8 bv0 = *(const short8*)(bp);
    short8 bv1 = *(const short8*)(bp + 8);
    *(short8*)(As + srow*40 + koff)     = av0;
    *(short8*)(As + srow*40 + koff + 8) = av1;
    *(short8*)(Bs + srow*40 + koff)     = bv0;
    *(short8*)(Bs + srow*40 + koff + 8) = bv1;
    __syncthreads();
    short8 af[4], bfr[4];
    #pragma unroll
    for (int i = 0; i < 4; ++i)
      af[i] = *(const short8*)(As + (wm*64 + i*16 + ln)*40 + quad*8);
    #pragma unroll
    for (int j = 0; j < 4; ++j)
      bfr[j] = *(const short8*)(Bs + (wn*64 + j*16 + ln)*40 + quad*8);
    #pragma unroll
    for (int i = 0; i < 4; ++i)
      #pragma unroll
      for (int j = 0; j < 4; ++j)
        acc[i][j] = __builtin_amdgcn_mfma_f32_16x16x32_bf16(af[i], bfr[j], acc[i][j], 0, 0, 0);
    __syncthreads();
  }

  #pragma unroll
  for (int j = 0; j < 4; ++j){
    int col = nb*128 + wn*64 + j*16 + ln;
    float bias = bsum ? bsum[(size_t)z*1920 + col] : 0.0f;
    #pragma unroll
    for (int i = 0; i < 4; ++i){
      #pragma unroll
      for (int rg = 0; rg < 4; ++rg){
        int row = mb*128 + wm*64 + i*16 + quad*4 + rg;
        out[(size_t)z*Ostride + (size_t)row*N + col] = f2bu(acc[i][j][rg] + bias);
      }
    }
  }
}

// ---------------------------------------------------------------------------
// Kernel H: fused hidden GEMM + LSTM cell (round-5 verified, unchanged).
// ---------------------------------------------------------------------------
__global__ __launch_bounds__(256) void k_hstep(
    const u16* __restrict__ Hin, const u16* __restrict__ Whp,
    const u16* __restrict__ Gb, float* __restrict__ HC,
    u16* __restrict__ Hout, u16* __restrict__ Ybf, float* __restrict__ Yf,
    float* __restrict__ HF, int s, int layer)
{
  __shared__ __align__(16) u16 As[32*40];
  __shared__ __align__(16) u16 Bs[128*40];
  const int tid = threadIdx.x;
  const int nb = blockIdx.x, mb = blockIdx.y, z = blockIdx.z;
  const int wid = tid >> 6, lane = tid & 63, ln = lane & 15, quad = lane >> 4;
  const int wm = wid >> 1, wn = wid & 1;

  const u16* Az = Hin + ((size_t)z*256 + mb*32)*480;
  const u16* Bz = Whp + (size_t)z*1920*480 + (size_t)nb*128*480;

  f32x4 acc[4];
  #pragma unroll
  for (int j = 0; j < 4; ++j) acc[j] = (f32x4)0.0f;

  const int ar = tid >> 2, ap = tid & 3;   // A: first 128 threads
  const int br = tid >> 1, bp = tid & 1;   // B: all 256 threads
  for (int kc = 0; kc < 15; ++kc){
    const int k0 = kc*32;
    if (tid < 128)
      *(short8*)(As + ar*40 + ap*8) = *(const short8*)(Az + (size_t)ar*480 + k0 + ap*8);
    *(short8*)(Bs + br*40 + bp*16)     = *(const short8*)(Bz + (size_t)br*480 + k0 + bp*16);
    *(short8*)(Bs + br*40 + bp*16 + 8) = *(const short8*)(Bz + (size_t)br*480 + k0 + bp*16 + 8);
    __syncthreads();
    short8 afr = *(const short8*)(As + (wm*16 + ln)*40 + quad*8);
    #pragma unroll
    for (int j = 0; j < 4; ++j){
      short8 bfr = *(const short8*)(Bs + (wn*64 + j*16 + ln)*40 + quad*8);
      acc[j] = __builtin_amdgcn_mfma_f32_16x16x32_bf16(afr, bfr, acc[j], 0, 0, 0);
    }
    __syncthreads();
  }

  const int kblk = nb*2 + wn;
  const int k = kblk*16 + ln;
  const int t = z ? (4 - s) : s;
  if (k < 450){
    const u16* Gz = Gb + (size_t)z*2457600 + (size_t)t*256*1920;
    #pragma unroll
    for (int rg = 0; rg < 4; ++rg){
      int b = mb*32 + wm*16 + quad*4 + rg;
      const u16* grow = Gz + (size_t)b*1920 + nb*128 + wn*64 + ln;
      float gi = acc[0][rg] + u2f(grow[0]);
      float gf = acc[1][rg] + u2f(grow[16]);
      float gg = acc[2][rg] + u2f(grow[32]);
      float go = acc[3][rg] + u2f(grow[48]);
      float* cp = HC + ((size_t)(2+z)*256 + b)*450 + k;
      float c = sigm(gf)*(*cp) + sigm(gi)*tanhf(gg);
      float h = sigm(go)*tanhf(c);
      *cp = c;
      Hout[((size_t)z*256 + b)*480 + k] = f2bu(h);
      if (Ybf) Ybf[((size_t)t*256 + b)*928 + z*450 + k] = f2bu(h);
      else     Yf [((size_t)t*256 + b)*900 + z*450 + k] = h;
      HF[((size_t)(layer*2+z)*256 + b)*450 + k] = h;
    }
  }
}

// ---------------------------------------------------------------------------
// Kernel 5: attention over timesteps + context. Wave-level reductions:
// per (p, wave) partial -> wsum -> LDS slot; ONE barrier, then tid<2 combine.
// hidden[b][h][l] = HF_flat[b*1800 + h*2 + l]  (reference reshape quirk)
// ---------------------------------------------------------------------------
__global__ __launch_bounds__(256) void k_attn(
    const float* __restrict__ Y1, const float* __restrict__ HF,
    float* __restrict__ CTX)
{
  __shared__ float red2[40];
  __shared__ float aw[10];
  int b = blockIdx.x, tid = threadIdx.x;
  int wid = tid >> 6, lane = tid & 63;
  for (int p = 0; p < 10; ++p){
    int t = p >> 1, l = p & 1;
    float a = 0.0f;
    for (int h = tid; h < 900; h += 256)
      a += Y1[((size_t)t*256 + b)*900 + h] * HF[(size_t)b*1800 + h*2 + l];
    a = wsum(a);
    if (lane == 0) red2[p*4 + wid] = a;
  }
  __syncthreads();
  if (tid < 2){
    int l = tid;
    float sc[5];
    float mxv = -3.0e38f;
    for (int t = 0; t < 5; ++t){
      int p = t*2 + l;
      sc[t] = red2[p*4] + red2[p*4+1] + red2[p*4+2] + red2[p*4+3];
      mxv = fmaxf(mxv, sc[t]);
    }
    float e[5], sum = 0.0f;
    for (int t = 0; t < 5; ++t){ e[t] = expf(sc[t]-mxv); sum += e[t]; }
    for (int t = 0; t < 5; ++t) aw[t*2+l] = e[t]/sum;
  }
  __syncthreads();
  for (int h = tid; h < 900; h += 256){
    float v0 = 0.0f, v1 = 0.0f;
    for (int t = 0; t < 5; ++t){
      float y = Y1[((size_t)t*256 + b)*900 + h];
      v0 += y*aw[t*2+0]; v1 += y*aw[t*2+1];
    }
    CTX[(size_t)b*1800 + h*2 + 0] = v0;
    CTX[(size_t)b*1800 + h*2 + 1] = v1;
  }
}

// ---------------------------------------------------------------------------
// Kernel 2s: scalar GEMM (kept only for CTX @ out_w, C=100).
// ---------------------------------------------------------------------------
__global__ __launch_bounds__(256) void k_gemm(
    const float* __restrict__ A, const void* __restrict__ W, size_t wEl,
    const void* __restrict__ b1, const void* __restrict__ b2, size_t bEl,
    const int* __restrict__ flag,
    float* __restrict__ out, int K, int C)
{
  extern __shared__ float a_s[];
  const int bf = *flag;
  const int tid = threadIdx.x;
  const int r = blockIdx.y;
  const float* a = A + (size_t)r*K;
  for (int k = tid; k < K; k += 256) a_s[k] = a[k];
  __syncthreads();
  const int j = blockIdx.x*256 + tid;
  if (j >= C) return;
  float acc = 0.0f;
  if (b1) acc += ldf(b1, bEl + j, bf);
  if (b2) acc += ldf(b2, bEl + j, bf);
  if (bf){
    const u16* w = (const u16*)W + wEl + (size_t)j*K;
    for (int k = 0; k < K; k += 4){
      uint2 wv = *(const uint2*)(w + k);
      acc += a_s[k]   * u2f(wv.x & 0xffffu);
      acc += a_s[k+1] * u2f(wv.x >> 16);
      acc += a_s[k+2] * u2f(wv.y & 0xffffu);
      acc += a_s[k+3] * u2f(wv.y >> 16);
    }
  } else {
    const float* w = (const float*)W + wEl + (size_t)j*K;
    for (int k = 0; k < K; k += 4){
      float4 wv = *(const float4*)(w + k);
      acc += a_s[k]*wv.x + a_s[k+1]*wv.y + a_s[k+2]*wv.z + a_s[k+3]*wv.w;
    }
  }
  out[(size_t)r*C + j] = acc;
}

// ---------------------------------------------------------------------------
// Kernel 6: analytic meta-gradient. ONE WAVE per b; lane owns dims
// {lane, lane+64}; every reduction is a 6-shfl wsum. Zero barriers.
// ---------------------------------------------------------------------------
__global__ __launch_bounds__(64) void k_grad(
    const void* __restrict__ sup, const void* __restrict__ supn,
    const void* __restrict__ normv, const float* __restrict__ REL,
    const int* __restrict__ flag,
    float* __restrict__ RELQ, float* __restrict__ NORMQ)
{
  const int bf = *flag;
  const int b = blockIdx.x, lane = threadIdx.x;
  const int d0 = lane, d1 = lane + 64;
  const bool a1 = (d1 < 100);
  float nv0 = ldf(normv, (size_t)b*100 + d0, bf);
  float nv1 = a1 ? ldf(normv, (size_t)b*100 + d1, bf) : 0.0f;
  float rl0 = REL[(size_t)b*100 + d0];
  float rl1 = a1 ? REL[(size_t)b*100 + d1] : 0.0f;
  float acc0 = 0.0f, acc1 = 0.0f;
  for (int j = 0; j < 5; ++j){
    size_t base = (size_t)(b*5+j)*200;
    float h10 = ldf(sup,  base + d0, bf);
    float t10 = ldf(sup,  base + 100 + d0, bf);
    float h20 = ldf(supn, base + d0, bf);
    float t20 = ldf(supn, base + 100 + d0, bf);
    float h11 = a1 ? ldf(sup,  base + d1, bf) : 0.0f;
    float t11 = a1 ? ldf(sup,  base + 100 + d1, bf) : 0.0f;
    float h21 = a1 ? ldf(supn, base + d1, bf) : 0.0f;
    float t21 = a1 ? ldf(supn, base + 100 + d1, bf) : 0.0f;
    float hd1 = wsum(h10*nv0 + h11*nv1);
    float td1 = wsum(t10*nv0 + t11*nv1);
    float hd2 = wsum(h20*nv0 + h21*nv1);
    float td2 = wsum(t20*nv0 + t21*nv1);
    float upd0 = (h10 - hd1*nv0) + rl0 - (t10 - td1*nv0);
    float upd1 = (h11 - hd1*nv1) + rl1 - (t11 - td1*nv1);
    float und0 = (h20 - hd2*nv0) + rl0 - (t20 - td2*nv0);
    float und1 = (h21 - hd2*nv1) + rl1 - (t21 - td2*nv1);
    if (!a1){ upd1 = 0.0f; und1 = 0.0f; }
    float np2 = wsum(upd0*upd0 + upd1*upd1);
    float nn2 = wsum(und0*und0 + und1*und1);
    float p = -sqrtf(np2), nsc = -sqrtf(nn2);
    if (1.0f - (p - nsc) > 0.0f){
      float ip = 1.0f/sqrtf(np2), in = 1.0f/sqrtf(nn2);
      acc0 += upd0*ip - und0*in;
      acc1 += upd1*ip - und1*in;
    }
  }
  float g0 = acc0 * (1.0f/1280.0f);
  RELQ [(size_t)b*100 + d0] = rl0 - 5.0f*g0;
  NORMQ[(size_t)b*100 + d0] = nv0 - 5.0f*g0;
  if (a1){
    float g1 = acc1 * (1.0f/1280.0f);
    RELQ [(size_t)b*100 + d1] = rl1 - 5.0f*g1;
    NORMQ[(size_t)b*100 + d1] = nv1 - 5.0f*g1;
  }
}

// ---------------------------------------------------------------------------
// Kernel 7: final scores. Wave per row; h-part in lanes 0-24, t-part in
// lanes 32-56 so hd AND td reduce in ONE width-32 xor butterfly (5 shfl);
// td crosses halves with 1 shfl; s2 is a second width-32 butterfly.
// 15 cross-lane ops/row (was 22).
// ---------------------------------------------------------------------------
__global__ __launch_bounds__(256) void k_score(
    const void* __restrict__ query, const void* __restrict__ neg,
    const float* __restrict__ RELQ, const float* __restrict__ NORMQ,
    const int* __restrict__ flag, void* __restrict__ out)
{
  __shared__ __align__(16) float nq[104], rq[104];
  const int bf = *flag;
  const int b = blockIdx.x, tid = threadIdx.x;
  if (tid < 100){ nq[tid] = NORMQ[b*100+tid]; rq[tid] = RELQ[b*100+tid]; }
  __syncthreads();
  const int wid = tid >> 6, lane = tid & 63;
  const bool lo = (lane < 25);
  const bool hi = (lane >= 32 && lane < 57);
  const int d0 = lo ? lane*4 : (hi ? (lane-32)*4 : 0);
  float4 w4 = make_float4(0.0f,0.0f,0.0f,0.0f);
  float4 r4 = make_float4(0.0f,0.0f,0.0f,0.0f);
  if (lo || hi) w4 = *(const float4*)(nq + d0);
  if (lo)       r4 = *(const float4*)(rq + d0);

  for (int qi = blockIdx.y*4 + wid; qi < 522; qi += 32){
    const void* src = (qi < 10) ? query : neg;
    size_t row = (qi < 10) ? ((size_t)b*10 + qi) : ((size_t)b*512 + qi - 10);
    size_t base = row*200 + (hi ? 100 : 0) + d0;
    float4 v = make_float4(0.0f,0.0f,0.0f,0.0f);
    if (lo || hi){
      if (bf){
        uint2 u = *(const uint2*)((const u16*)src + base);
        v.x = u2f(u.x & 0xffffu); v.y = u2f(u.x >> 16);
        v.z = u2f(u.y & 0xffffu); v.w = u2f(u.y >> 16);
      } else {
        v = *(const float4*)((const float*)src + base);
      }
    }
    float pr = v.x*w4.x + v.y*w4.y + v.z*w4.z + v.w*w4.w;
    #pragma unroll
    for (int off = 16; off > 0; off >>= 1) pr += __shfl_xor(pr, off, 32);
    // lanes 0-31: pr = hd ; lanes 32-63: pr = td
    float tdv = __shfl(pr, lane + 32, 64);   // valid for lane < 32
    float4 t4;
    t4.x = __shfl(v.x, lane + 32, 64);
    t4.y = __shfl(v.y, lane + 32, 64);
    t4.z = __shfl(v.z, lane + 32, 64);
    t4.w = __shfl(v.w, lane + 32, 64);
    float s2 = 0.0f;
    if (lo){
      float ux = (v.x - pr*w4.x) + r4.x - (t4.x - tdv*w4.x);
      float uy = (v.y - pr*w4.y) + r4.y - (t4.y - tdv*w4.y);
      float uz = (v.z - pr*w4.z) + r4.z - (t4.z - tdv*w4.z);
      float uw = (v.w - pr*w4.w) + r4.w - (t4.w - tdv*w4.w);
      s2 = ux*ux + uy*uy + uz*uz + uw*uw;
    }
    #pragma unroll
    for (int off = 16; off > 0; off >>= 1) s2 += __shfl_xor(s2, off, 32);
    if (lane == 0){
      float sc = -sqrtf(s2);
      size_t oi = (qi < 10) ? ((size_t)b*10 + qi) : (2560 + (size_t)b*512 + (qi - 10));
      if (bf) ((u16*)out)[oi] = f2bu(sc);
      else    ((float*)out)[oi] = sc;
    }
  }
}

// ---------------------------------------------------------------------------
extern "C" void kernel_launch(void* const* d_in, const int* in_sizes, int n_in,
                              void* d_out, int out_size, void* d_ws, size_t ws_size,
                              hipStream_t stream)
{
  const void* support = d_in[0];
  const void* supneg  = d_in[1];
  const void* query   = d_in[2];
  const void* negat   = d_in[3];
  const void* normv   = d_in[4];
  const int* left     = (const int*)d_in[5];
  const int* right    = (const int*)d_in[6];
  const void* emb     = d_in[7];
  const void* gcnw    = d_in[8];
  const void* gcnwb   = d_in[9];
  const void* gcnb    = d_in[10];
  const void* attnw   = d_in[11];
  const void* attnwb  = d_in[12];
  const void* gatew   = d_in[13];
  const void* gatewb  = d_in[14];
  const void* gateb   = d_in[15];
  const void* Wih0    = d_in[16];
  const void* Whh0    = d_in[17];
  const void* bih0    = d_in[18];
  const void* bhh0    = d_in[19];
  const void* Wih1    = d_in[20];
  const void* Whh1    = d_in[21];
  const void* bih1    = d_in[22];
  const void* bhh1    = d_in[23];
  const void* outw    = d_in[24];
  const void* outb    = d_in[25];

  int*   dflag = (int*)d_ws;
  float* fws   = (float*)d_ws + 16;
  // f32 region
  float* Y1   = fws;                 // 5*256*900  = 1,152,000
  float* HF   = Y1 + 1152000;        // 4*256*450  =   460,800
  float* HC   = HF + 460800;         //               460,800 (c in slots 2,3)
  float* CTX  = HC + 460800;         //               460,800
  float* RELb = CTX + 460800;        //    25,600
  float* RELQ = RELb + 25600;        //    25,600
  float* NORMQ= RELQ + 25600;        //    25,600
  float* Bp   = NORMQ + 25600;       //     3,840  (2x1920 permuted bias)
  float* fend = Bp + 3840;           // total f32 = 2,615,040 (16B aligned)
  // u16 region
  u16* Gb   = (u16*)fend;            // 2*1280*1920 = 4,915,200
  u16* X0bf = Gb + 4915200;          // 1280*224    =   286,720
  u16* Y0bf = X0bf + 286720;         // 1280*928    = 1,187,840
  u16* Hbf  = Y0bf + 1187840;        // 2 par * 2*256*480 = 491,520
  u16* Wg   = Hbf + 491520;          // 112*224     =    25,088
  u16* Eb   = Wg + 25088;            // 70001*100   = 7,000,100 (bf16 emb)
  // Wp/Whp ALIAS Eb: Eb dead after k_gcn; packs run after (stream-serial).
  u16* Wp   = Eb;                    // 2*1920*928 max = 3,563,520
  u16* Whp  = Eb + 3563520;          // 2*1920*480  = 1,843,200 (sum 5.4M < 7.0M)
  // total ~= 38.3 MB

  k_detect<<<1, 64, 0, stream>>>((const u32*)normv, dflag);

  // neighbor encoder -> X0bf
  hipMemsetAsync(X0bf, 0, 286720*sizeof(u16), stream);
  k_pack<<<(112*224+255)/256, 256, 0, stream>>>(gcnw, Wg, 200, 224, 100, 112, dflag);
  k_packe<<<(1750025+255)/256, 256, 0, stream>>>(emb, Eb, 1750025, dflag);
  k_gcn<<<2560, 512, 0, stream>>>(left, right, emb, Eb, Wg, gcnwb, gcnb,
                                  attnw, attnwb, gatew, gatewb, gateb,
                                  dflag, X0bf);

  u16* Hpar0 = Hbf;
  u16* Hpar1 = Hbf + 245760;

  // ---- layer 0 ----
  hipMemsetAsync(Y0bf, 0, 1187840*sizeof(u16), stream);
  hipMemsetAsync(Hbf, 0, 491520*sizeof(u16), stream);
  hipMemsetAsync(HC, 0, 460800*sizeof(float), stream);
  k_packg<<<(2*1920*224/4+255)/256, 256, 0, stream>>>(Wih0, Wp, 200, 224, dflag);
  k_packg<<<(2*1920*480/4+255)/256, 256, 0, stream>>>(Whh0, Whp, 450, 480, dflag);
  k_packb<<<15, 256, 0, stream>>>(bih0, bhh0, Bp, dflag);
  k_mgemm<<<dim3(15,10,2), 256, 0, stream>>>(
      X0bf, 224, 0, Wp, 224, (size_t)1920*224,
      Bp, Gb, 2457600, 1920, 7);
  {
    u16* hc = Hpar0; u16* hn = Hpar1;
    for (int s = 0; s < 5; ++s){
      k_hstep<<<dim3(15,8,2), 256, 0, stream>>>(hc, Whp, Gb, HC, hn,
                                                Y0bf, nullptr, HF, s, 0);
      u16* tmp = hc; hc = hn; hn = tmp;
    }
  }

  // ---- layer 1 ----
  hipMemsetAsync(Hbf, 0, 491520*sizeof(u16), stream);
  hipMemsetAsync(HC, 0, 460800*sizeof(float), stream);
  k_packg<<<(2*1920*928/4+255)/256, 256, 0, stream>>>(Wih1, Wp, 900, 928, dflag);
  k_packg<<<(2*1920*480/4+255)/256, 256, 0, stream>>>(Whh1, Whp, 450, 480, dflag);
  k_packb<<<15, 256, 0, stream>>>(bih1, bhh1, Bp, dflag);
  k_mgemm<<<dim3(15,10,2), 256, 0, stream>>>(
      Y0bf, 928, 0, Wp, 928, (size_t)1920*928,
      Bp, Gb, 2457600, 1920, 29);
  {
    u16* hc = Hpar0; u16* hn = Hpar1;
    for (int s = 0; s < 5; ++s){
      k_hstep<<<dim3(15,8,2), 256, 0, stream>>>(hc, Whp, Gb, HC, hn,
                                                nullptr, Y1, HF, s, 1);
      u16* tmp = hc; hc = hn; hn = tmp;
    }
  }

  k_attn<<<256, 256, 0, stream>>>(Y1, HF, CTX);
  k_gemm<<<dim3(1,256), 256, 1800*4, stream>>>(CTX, outw, 0, outb, nullptr, 0,
                                               dflag, RELb, 1800, 100);
  k_grad<<<256, 64, 0, stream>>>(support, supneg, normv, RELb, dflag, RELQ, NORMQ);
  k_score<<<dim3(256,8), 256, 0, stream>>>(query, negat, RELQ, NORMQ, dflag, d_out);
}